// Round 7
// baseline (250.174 us; speedup 1.0000x reference)
//
#include <hip/hip_runtime.h>
#include <math.h>

#define G_   32
#define NPG_ 512
#define N_   16384
#define E_   262144
#define D_   256
#define H_   8
#define FF_  1024
#define BCAP 128   // per (g, qt16, key-quarter) bucket: avg 64, cap = 8 sigma

typedef unsigned int u32;
typedef unsigned short u16;
typedef __attribute__((ext_vector_type(8))) short s16x8;   // 8 x bf16
typedef __attribute__((ext_vector_type(4))) float f32x4;

__device__ inline u16 f2bf(float f) {
  u32 u = __float_as_uint(f);
  u += 0x7fffu + ((u >> 16) & 1u);
  return (u16)(u >> 16);
}

// ---------------------------------------------------------------- LayerNorm (bf16 out)
__global__ __launch_bounds__(256) void ln_kernel(const float* __restrict__ in,
                                                 const float* __restrict__ gw,
                                                 const float* __restrict__ bw,
                                                 u16* __restrict__ out) {
  const int wave = threadIdx.x >> 6, lane = threadIdx.x & 63;
  const int row = (blockIdx.x << 2) + wave;
  const float4 v = reinterpret_cast<const float4*>(in + (size_t)row * D_)[lane];
  float s = v.x + v.y + v.z + v.w;
#pragma unroll
  for (int off = 32; off > 0; off >>= 1) s += __shfl_xor(s, off);
  const float m = s * (1.0f / D_);
  const float dx = v.x - m, dy = v.y - m, dz = v.z - m, dw = v.w - m;
  float s2 = dx * dx + dy * dy + dz * dz + dw * dw;
#pragma unroll
  for (int off = 32; off > 0; off >>= 1) s2 += __shfl_xor(s2, off);
  const float inv = rsqrtf(s2 * (1.0f / D_) + 1e-5f);
  const float4 g4 = reinterpret_cast<const float4*>(gw)[lane];
  const float4 b4 = reinterpret_cast<const float4*>(bw)[lane];
  ushort4 o;
  o.x = f2bf(dx * inv * g4.x + b4.x);
  o.y = f2bf(dy * inv * g4.y + b4.y);
  o.z = f2bf(dz * inv * g4.z + b4.z);
  o.w = f2bf(dw * inv * g4.w + b4.w);
  *reinterpret_cast<ushort4*>(out + (size_t)row * D_ + (lane << 2)) = o;
}

// ---------------------------------------------------------------- fused weight prep
__global__ void wt_conv_all(const float* __restrict__ wq, const float* __restrict__ wk,
                            const float* __restrict__ wv, const float* __restrict__ w1,
                            const float* __restrict__ w2,
                            u16* __restrict__ wqkvt, u16* __restrict__ w1t,
                            u16* __restrict__ w2t,
                            const float* __restrict__ bq, const float* __restrict__ bk,
                            const float* __restrict__ bv, float* __restrict__ bqkv,
                            u32* __restrict__ cnt, u32* __restrict__ amask) {
  const int bid = blockIdx.x;
  const int tx = threadIdx.x, ty = threadIdx.y;
  if (bid == 704) {
    const int t = ty * 32 + tx;
    for (int i = t; i < 768; i += 256)
      bqkv[i] = (i < 256) ? bq[i] : (i < 512 ? bk[i - 256] : bv[i - 512]);
    for (int i = t; i < 4096; i += 256) cnt[i] = 0u;
    for (int i = t; i < 8192; i += 256) amask[i] = 0u;
    return;
  }
  const float* W; u16* Wt; int K, Nc, ro, local;
  if (bid < 64)       { W = wq; Wt = wqkvt; K = 256;  Nc = 256;  ro = 0;   local = bid; }
  else if (bid < 128) { W = wk; Wt = wqkvt; K = 256;  Nc = 256;  ro = 256; local = bid - 64; }
  else if (bid < 192) { W = wv; Wt = wqkvt; K = 256;  Nc = 256;  ro = 512; local = bid - 128; }
  else if (bid < 448) { W = w1; Wt = w1t;   K = 256;  Nc = 1024; ro = 0;   local = bid - 192; }
  else                { W = w2; Wt = w2t;   K = 1024; Nc = 256;  ro = 0;   local = bid - 448; }
  const int tn = Nc >> 5;
  const int n0 = (local % tn) << 5, k0 = (local / tn) << 5;
  __shared__ float tl[32][33];
#pragma unroll
  for (int i = 0; i < 4; ++i)
    tl[ty + (i << 3)][tx] = W[(size_t)(k0 + ty + (i << 3)) * Nc + n0 + tx];
  __syncthreads();
#pragma unroll
  for (int i = 0; i < 4; ++i)
    Wt[(size_t)(ro + n0 + ty + (i << 3)) * K + k0 + tx] = f2bf(tl[tx][ty + (i << 3)]);
}

// ---------------------------------------------------------------- edge prep
// gated weights for all 8 heads (bf16x8); bucket by (g, ls>>4, ld>>7) -> 4096 buckets
// + graph-0 adjacency bitmask (dedup for rel_pos)
__global__ __launch_bounds__(256) void edge_prep(const int* __restrict__ ei,
                                                 const float* __restrict__ ea,
                                                 const float* __restrict__ wep,
                                                 const float* __restrict__ bep,
                                                 const float* __restrict__ weg,
                                                 const float* __restrict__ beg,
                                                 u32* __restrict__ cnt,
                                                 u32* __restrict__ rec_id,
                                                 uint4* __restrict__ rec_ew,
                                                 u32* __restrict__ amask) {
  const int e = blockIdx.x * 256 + threadIdx.x;
  const int ls = ei[e] & 511;
  const int ld = ei[E_ + e] & 511;
  if (e < 8192)  // graph 0 adjacency (deduped by OR)
    atomicOr(&amask[(ls << 4) + (ld >> 5)], 1u << (ld & 31));
  const int bk = ((e >> 13) << 7) | ((ls >> 4) << 2) | (ld >> 7);
  const u32 pos = atomicAdd(&cnt[bk], 1u);
  if (pos < (u32)BCAP) {
    const float2 a2 = reinterpret_cast<const float2*>(ea)[e];
    u32 wds[4];
#pragma unroll
    for (int hp = 0; hp < 4; ++hp) {
      u32 wd = 0;
#pragma unroll
      for (int s = 0; s < 2; ++s) {
        const int h = hp * 2 + s;
        const float pre = a2.x * wep[h] + a2.y * wep[H_ + h] + bep[h];
        const float gat = a2.x * weg[h] + a2.y * weg[H_ + h] + beg[h];
        const float ew = pre / (1.0f + __expf(-gat));
        wd |= ((u32)f2bf(ew)) << (s * 16);
      }
      wds[hp] = wd;
    }
    rec_id[(bk << 7) + pos] = (u32)((ls & 15) | ((ld & 127) << 4));
    rec_ew[((size_t)bk << 7) + pos] = make_uint4(wds[0], wds[1], wds[2], wds[3]);
  }
}

// ---------------------------------------------------------------- MFMA GEMM (unchanged)
template <int ACT, int OUTM>
__global__ __launch_bounds__(256) void mgemm(const u16* __restrict__ A,
                                             const u16* __restrict__ Bt,
                                             const float* __restrict__ bias,
                                             const float* __restrict__ res,
                                             float* __restrict__ Cf,
                                             u16* __restrict__ Cb,
                                             u16* __restrict__ Vt,
                                             int K, int Nc) {
  __shared__ u16 s_all[17408];
  u16* sA = s_all;
  u16* sB = s_all + 8192;
  const int t = threadIdx.x;
  const int row0 = blockIdx.x << 7;
  const int col0 = blockIdx.y << 7;
  const int lane = t & 63, w = t >> 6;
  const int ql = lane & 15, u = lane >> 4;
  const int wr = w >> 1, wc = w & 1;

  f32x4 acc[4][4];
#pragma unroll
  for (int i = 0; i < 4; ++i)
#pragma unroll
    for (int j = 0; j < 4; ++j) acc[i][j] = (f32x4){0.f, 0.f, 0.f, 0.f};

  const u16* Ab = A + (size_t)row0 * K;
  const u16* Bb = Bt + (size_t)col0 * K;

  for (int k0 = 0; k0 < K; k0 += 64) {
    __syncthreads();
#pragma unroll
    for (int it = 0; it < 4; ++it) {
      const int idx = (it << 8) + t;
      const int row = idx >> 3, gc = idx & 7;
      const int sw = ((gc ^ (row & 7)) << 3);
      *reinterpret_cast<s16x8*>(sA + row * 64 + sw) =
          *reinterpret_cast<const s16x8*>(Ab + (size_t)row * K + k0 + (gc << 3));
    }
#pragma unroll
    for (int it = 0; it < 4; ++it) {
      const int idx = (it << 8) + t;
      const int row = idx >> 3, gc = idx & 7;
      const int sw = ((gc ^ (row & 7)) << 3);
      *reinterpret_cast<s16x8*>(sB + row * 64 + sw) =
          *reinterpret_cast<const s16x8*>(Bb + (size_t)row * K + k0 + (gc << 3));
    }
    __syncthreads();
#pragma unroll
    for (int ks = 0; ks < 2; ++ks) {
      const int gk = (ks << 2) + u;
      s16x8 aF[4], bF[4];
#pragma unroll
      for (int i = 0; i < 4; ++i) {
        const int ra = (wr << 6) + (i << 4) + ql;
        aF[i] = *reinterpret_cast<const s16x8*>(sA + ra * 64 + ((gk ^ (ra & 7)) << 3));
        const int rb = (wc << 6) + (i << 4) + ql;
        bF[i] = *reinterpret_cast<const s16x8*>(sB + rb * 64 + ((gk ^ (rb & 7)) << 3));
      }
#pragma unroll
      for (int i = 0; i < 4; ++i)
#pragma unroll
        for (int j = 0; j < 4; ++j)
          acc[i][j] = __builtin_amdgcn_mfma_f32_16x16x32_bf16(aF[i], bF[j], acc[i][j], 0, 0, 0);
    }
  }

  float b_[4];
#pragma unroll
  for (int j = 0; j < 4; ++j) b_[j] = bias[col0 + (wc << 6) + (j << 4) + ql];

  if (OUTM == 1) {
#pragma unroll
    for (int i = 0; i < 4; ++i)
#pragma unroll
      for (int j = 0; j < 4; ++j)
#pragma unroll
        for (int r = 0; r < 4; ++r) {
          const int row = row0 + (wr << 6) + (i << 4) + (u << 2) + r;
          const int col = col0 + (wc << 6) + (j << 4) + ql;
          Cf[(size_t)row * Nc + col] = acc[i][j][r] + b_[j] + res[(size_t)row * Nc + col];
        }
    return;
  }

  bool rowmajor = (OUTM == 0);
  if (OUTM == 2) {
    if (col0 < 512) rowmajor = true;
    else {
      const int g = row0 >> 9;
      const int key0 = (row0 & 511) + (wr << 6);
#pragma unroll
      for (int i = 0; i < 4; ++i)
#pragma unroll
        for (int j = 0; j < 4; ++j) {
          const int c = (col0 - 512) + (wc << 6) + (j << 4) + ql;
          const int hh = c >> 5, d = c & 31;
          ushort4 pk;
          pk.x = f2bf(acc[i][j][0] + b_[j]);
          pk.y = f2bf(acc[i][j][1] + b_[j]);
          pk.z = f2bf(acc[i][j][2] + b_[j]);
          pk.w = f2bf(acc[i][j][3] + b_[j]);
          *reinterpret_cast<ushort4*>(Vt + ((((size_t)g << 3) + hh) << 14) + d * 512 +
                                      key0 + (i << 4) + (u << 2)) = pk;
        }
      return;
    }
  }

  if (rowmajor) {
    __syncthreads();
    u16* sC = s_all;  // [128][136]
#pragma unroll
    for (int i = 0; i < 4; ++i)
#pragma unroll
      for (int j = 0; j < 4; ++j)
#pragma unroll
        for (int r = 0; r < 4; ++r) {
          float v = acc[i][j][r] + b_[j];
          if (ACT) v = fmaxf(v, 0.f);
          const int row = (wr << 6) + (i << 4) + (u << 2) + r;
          const int col = (wc << 6) + (j << 4) + ql;
          sC[row * 136 + col] = f2bf(v);
        }
    __syncthreads();
    const int ncb = (OUTM == 2) ? 512 : Nc;
#pragma unroll
    for (int it = 0; it < 8; ++it) {
      const int idx = (it << 8) + t;
      const int row = idx >> 4, gc = idx & 15;
      *reinterpret_cast<s16x8*>(Cb + (size_t)(row0 + row) * ncb + col0 + (gc << 3)) =
          *reinterpret_cast<const s16x8*>(sC + row * 136 + (gc << 3));
    }
  }
}

// ---------------------------------------------------------------- Attention v7 (wave-autonomous)
// WG = (g, h, qt16); grid 8192 x 256 (4 waves). Wave w owns keys [w*128, w*128+128):
// private strip [128][17] f32 (zero, scatter, rel_pos, apply -- NO barriers).
// Only 3 __syncthreads: row-max, P+sums, output tile.
// LDS dwords: strips 4*2176=8704 | P[16][512]bf16 = 4096 | statM 64 | statS 64
//   = 12928 dw = 51,712 B -> 3 WG/CU.  s_ot[16][36] aliases strip0 (re-zeroed post-A).
__global__ __launch_bounds__(256, 3) void attn_kernel(
    const u16* __restrict__ qk, const u16* __restrict__ vt,
    const u32* __restrict__ rec_id, const u32* __restrict__ rec_ew32,
    const u32* __restrict__ cnt, const u32* __restrict__ amask,
    const float* __restrict__ relpos,
    const float* __restrict__ x, float* __restrict__ x1) {
  extern __shared__ u32 smem_u[];
  const int braw = blockIdx.x;
  const int b = ((braw & 7) << 10) | (braw >> 3);  // XCD swizzle (8192 % 8 == 0)
  const int qt = b & 31, h = (b >> 5) & 7, g = b >> 8;
  const int t = threadIdx.x;
  const int lane = t & 63, w = t >> 6;
  const int ql = lane & 15, u = lane >> 4;
  const int n0 = (g << 9) + (qt << 4);
  const float scale = 0.17677669529663687f;  // 1/sqrt(32)
  const float rpv = relpos[h];

  float* strip = (float*)smem_u + w * 2176;        // wave-private [128][17]
  u16* s_p = (u16*)(smem_u + 8704);                // [16][512] bf16
  float* s_statM = (float*)(smem_u + 12800);       // [16][4]
  float* s_statS = (float*)(smem_u + 12864);       // [16][4]
  float* s_ot = (float*)smem_u;                    // [16][36] alias strip0

  // ---- bucket + prefetch records into registers (<= 2 per lane)
  const int bkt = (g << 7) | (qt << 2) | w;
  const u32 cn = cnt[bkt];
  const int nrec = cn > (u32)BCAP ? BCAP : (int)cn;
  u32 id0 = 0, wd0 = 0, id1 = 0, wd1 = 0;
  if (lane < nrec) {
    id0 = rec_id[(bkt << 7) + lane];
    wd0 = rec_ew32[(((size_t)bkt << 7) + lane) * 4 + (h >> 1)];
  }
  if (lane + 64 < nrec) {
    id1 = rec_id[(bkt << 7) + lane + 64];
    wd1 = rec_ew32[(((size_t)bkt << 7) + lane + 64) * 4 + (h >> 1)];
  }

  // ---- prefetch Q (1 frag) + K (8 frags)
  const s16x8 qf8 = *reinterpret_cast<const s16x8*>(
      qk + (size_t)(n0 + ql) * 512 + (h << 5) + (u << 3));
  s16x8 kf8[8];
#pragma unroll
  for (int kf = 0; kf < 8; ++kf)
    kf8[kf] = *reinterpret_cast<const s16x8*>(
        qk + (size_t)((g << 9) + (w << 7) + (kf << 4) + ql) * 512 + 256 + (h << 5) + (u << 3));

  {  // zero wave-private strip (no barrier)
    f32x4* zs = (f32x4*)strip;
    const f32x4 zv = {0.f, 0.f, 0.f, 0.f};
#pragma unroll
    for (int i = 0; i < 9; ++i) {
      const int idx = lane + (i << 6);
      if (idx < 544) zs[idx] = zv;
    }
  }

  // ---- QK^T (swapped): S^T[key][q], 8 MFMAs register-only
  f32x4 acc[8];
#pragma unroll
  for (int kf = 0; kf < 8; ++kf) acc[kf] = (f32x4){0.f, 0.f, 0.f, 0.f};
  __builtin_amdgcn_s_setprio(1);
#pragma unroll
  for (int kf = 0; kf < 8; ++kf)
    acc[kf] = __builtin_amdgcn_mfma_f32_16x16x32_bf16(kf8[kf], qf8, acc[kf], 0, 0, 0);
  __builtin_amdgcn_s_setprio(0);

  // ---- scatter (wave-local LDS atomics)
  if (lane < nrec) {
    const u32 bits = (h & 1) ? (wd0 & 0xffff0000u) : (wd0 << 16);
    atomicAdd(&strip[((id0 >> 4) & 127) * 17 + (id0 & 15)], __uint_as_float(bits));
  }
  if (lane + 64 < nrec) {
    const u32 bits = (h & 1) ? (wd1 & 0xffff0000u) : (wd1 << 16);
    atomicAdd(&strip[((id1 >> 4) & 127) * 17 + (id1 & 15)], __uint_as_float(bits));
  }
  __threadfence_block();  // drain wave's LDS atomics (wave-internal order)

  if (g == 0) {  // fold rel_pos * A (deduped) into the strip; wave-local
    u32 m = amask[(((qt << 4) + ql) << 4) + (w << 2) + u];
    while (m) {
      const int bit = __ffs(m) - 1;
      m &= m - 1;
      strip[((u << 5) + bit) * 17 + ql] += rpv;
    }
    __threadfence_block();
  }

  // ---- apply bias + row max (strip reads, wave-local)
  float mx = -1e30f;
#pragma unroll
  for (int kf = 0; kf < 8; ++kf)
#pragma unroll
    for (int r = 0; r < 4; ++r) {
      const float v = fmaf(acc[kf][r], scale, strip[((kf << 4) + (u << 2) + r) * 17 + ql]);
      acc[kf][r] = v;
      mx = fmaxf(mx, v);
    }
  mx = fmaxf(mx, __shfl_xor(mx, 16));
  mx = fmaxf(mx, __shfl_xor(mx, 32));
  if (lane < 16) s_statM[(ql << 2) + w] = mx;
  __syncthreads();  // A: strips dead; statM visible

  // re-zero ot region (aliases strip0 dwords [0,576))
  for (int i = t; i < 576; i += 256) ((float*)smem_u)[i] = 0.0f;

  {  // ---- exp + P (bf16, swizzled) + sums
    const f32x4 m4 = *reinterpret_cast<const f32x4*>(s_statM + (ql << 2));
    const float M = fmaxf(fmaxf(m4[0], m4[1]), fmaxf(m4[2], m4[3]));
    float sum = 0.0f;
#pragma unroll
    for (int kf = 0; kf < 8; ++kf) {
      float e[4];
#pragma unroll
      for (int r = 0; r < 4; ++r) {
        e[r] = __expf(acc[kf][r] - M);
        sum += e[r];
      }
      const int kl0 = (w << 7) + (kf << 4) + (u << 2);
      const int gran = kl0 >> 3;
      uint2 pw;
      pw.x = (u32)f2bf(e[0]) | ((u32)f2bf(e[1]) << 16);
      pw.y = (u32)f2bf(e[2]) | ((u32)f2bf(e[3]) << 16);
      *reinterpret_cast<uint2*>(s_p + (ql << 9) + ((gran ^ (ql & 7)) << 3) + (kl0 & 7)) = pw;
    }
    sum += __shfl_xor(sum, 16);
    sum += __shfl_xor(sum, 32);
    if (lane < 16) s_statS[(ql << 2) + w] = sum;
  }
  __syncthreads();  // B: P + sums + ot-zero visible

  {  // ---- PV: wave w covers its own key quarter, both 16-dim halves
    const u16* vtb = vt + ((((size_t)g << 3) + h) << 14);
    f32x4 o0 = (f32x4){0.f, 0.f, 0.f, 0.f}, o1 = (f32x4){0.f, 0.f, 0.f, 0.f};
    __builtin_amdgcn_s_setprio(1);
#pragma unroll
    for (int ks = 0; ks < 4; ++ks) {
      const int k0 = (w << 7) + (ks << 5) + (u << 3);
      const s16x8 pb = *reinterpret_cast<const s16x8*>(
          s_p + (ql << 9) + (((k0 >> 3) ^ (ql & 7)) << 3));
      const s16x8 va0 = *reinterpret_cast<const s16x8*>(vtb + (size_t)ql * 512 + k0);
      const s16x8 va1 = *reinterpret_cast<const s16x8*>(vtb + (size_t)(16 + ql) * 512 + k0);
      o0 = __builtin_amdgcn_mfma_f32_16x16x32_bf16(va0, pb, o0, 0, 0, 0);
      o1 = __builtin_amdgcn_mfma_f32_16x16x32_bf16(va1, pb, o1, 0, 0, 0);
    }
    __builtin_amdgcn_s_setprio(0);
#pragma unroll
    for (int r = 0; r < 4; ++r) {
      atomicAdd(&s_ot[ql * 36 + (u << 2) + r], o0[r]);
      atomicAdd(&s_ot[ql * 36 + 16 + (u << 2) + r], o1[r]);
    }
  }
  __syncthreads();  // C: ot complete

  if (t < 128) {  // ---- epilogue: 1/S + x residual
    const int q = t >> 3, d4 = (t & 7) << 2;
    const f32x4 s4 = *reinterpret_cast<const f32x4*>(s_statS + (q << 2));
    const float invS = 1.0f / (s4[0] + s4[1] + s4[2] + s4[3]);
    const f32x4 ov = *reinterpret_cast<const f32x4*>(s_ot + q * 36 + d4);
    const size_t oi = (size_t)(n0 + q) * D_ + (h << 5) + d4;
    const f32x4 xv = *reinterpret_cast<const f32x4*>(x + oi);
    f32x4 o;
#pragma unroll
    for (int j = 0; j < 4; ++j) o[j] = ov[j] * invS + xv[j];
    *reinterpret_cast<f32x4*>(x1 + oi) = o;
  }
}

// ---------------------------------------------------------------- launch
extern "C" void kernel_launch(void* const* d_in, const int* in_sizes, int n_in,
                              void* d_out, int out_size, void* d_ws, size_t ws_size,
                              hipStream_t stream) {
  const float* x    = (const float*)d_in[0];
  const int*   ei   = (const int*)d_in[1];
  const float* ea   = (const float*)d_in[2];
  const float* ln1g = (const float*)d_in[3];
  const float* ln1b = (const float*)d_in[4];
  const float* wq   = (const float*)d_in[5];
  const float* bq   = (const float*)d_in[6];
  const float* wk   = (const float*)d_in[7];
  const float* bk   = (const float*)d_in[8];
  const float* wv   = (const float*)d_in[9];
  const float* bv   = (const float*)d_in[10];
  const float* wep  = (const float*)d_in[11];
  const float* bep  = (const float*)d_in[12];
  const float* weg  = (const float*)d_in[13];
  const float* beg  = (const float*)d_in[14];
  const float* rp   = (const float*)d_in[15];
  const float* w1   = (const float*)d_in[16];
  const float* b1   = (const float*)d_in[17];
  const float* w2   = (const float*)d_in[18];
  const float* b2   = (const float*)d_in[19];
  const float* ln2g = (const float*)d_in[20];
  const float* ln2b = (const float*)d_in[21];
  float* out = (float*)d_out;

  float* ws = (float*)d_ws;
  const size_t M1 = 1048576;
  u16* xn   = (u16*)ws;                       // [16384][256] bf16
  u16* qk   = (u16*)(ws + 2 * M1);            // [16384][512] bf16 (Q|K)
  u16* vt   = (u16*)(ws + 6 * M1);            // [256][32][512] bf16
  u16* f1   = (u16*)ws;                       // [16384][1024] bf16 (alias, post-attn)
  float* x1 = ws + 8 * M1;                    // f32
  u16* h2   = (u16*)(ws + 12 * M1);           // bf16
  u16* wqkvt = (u16*)(ws + 14 * M1);          // [768][256] bf16
  u16* w1t  = (u16*)(ws + 14 * M1 + 262144);  // [1024][256] bf16
  u16* w2t  = (u16*)(ws + 14 * M1 + 524288);  // [256][1024] bf16
  float* bqkv = ws + 14 * M1 + 786432;        // [768] f32
  u32* cnt  = (u32*)(ws + 14 * M1 + 787456);  // [4096] u32
  u32* amask = (u32*)(ws + 14 * M1 + 791552); // [512][16] u32 (32KB)
  u32* rec_id = (u32*)(ws + 15 * M1);         // [4096*128] u32 (2MB)
  uint4* rec_ew = (uint4*)(ws + 16 * M1);     // [4096*128] uint4 (8MB)

  // 0. fused weight prep (packs bqkv, zeros cnt + amask), then edge prep
  wt_conv_all<<<dim3(705), dim3(32, 8), 0, stream>>>(wq, wk, wv, w1, w2, wqkvt, w1t, w2t,
                                                     bq, bk, bv, bqkv, cnt, amask);
  edge_prep<<<dim3(E_ / 256), dim3(256), 0, stream>>>(ei, ea, wep, bep, weg, beg,
                                                      cnt, rec_id, rec_ew, amask);
  // 1. LN1 -> bf16
  ln_kernel<<<dim3(N_ / 4), dim3(256), 0, stream>>>(x, ln1g, ln1b, xn);
  // 2. fused QKV GEMM: Q,K -> qk row-major; V -> vt transposed
  mgemm<0, 2><<<dim3(128, 6), 256, 0, stream>>>(xn, wqkvt, bqkv, nullptr, nullptr, qk, vt, 256, 768);
  // 3. attention (+x residual) -> x1 f32
  const int smem_attn = 12928 * 4;  // 51,712 B -> 3 WG/CU
  (void)hipFuncSetAttribute(reinterpret_cast<const void*>(attn_kernel),
                            hipFuncAttributeMaxDynamicSharedMemorySize, smem_attn);
  attn_kernel<<<dim3(G_ * H_ * 32), 256, smem_attn, stream>>>(
      qk, vt, rec_id, (const u32*)rec_ew, cnt, amask, rp, x, x1);
  // 4. LN2 -> bf16
  ln_kernel<<<dim3(N_ / 4), dim3(256), 0, stream>>>(x1, ln2g, ln2b, h2);
  // 5. FF1 (relu) -> f1 bf16
  mgemm<1, 0><<<dim3(128, 8), 256, 0, stream>>>(h2, w1t, b1, nullptr, nullptr, f1, nullptr, 256, 1024);
  // 6. FF2 (+bias +x1 residual) -> out f32
  mgemm<0, 1><<<dim3(128, 2), 256, 0, stream>>>(f1, w2t, b2, x1, out, nullptr, nullptr, 1024, 256);
}

// Round 8
// 209.244 us; speedup vs baseline: 1.1956x; 1.1956x over previous
//
#include <hip/hip_runtime.h>
#include <math.h>

#define G_   32
#define NPG_ 512
#define N_   16384
#define E_   262144
#define D_   256
#define H_   8
#define FF_  1024
#define BCAP 512   // per (g, qt16, key-half) bucket: avg 256, cap = 16 sigma

typedef unsigned int u32;
typedef unsigned short u16;
typedef __attribute__((ext_vector_type(8))) short s16x8;   // 8 x bf16
typedef __attribute__((ext_vector_type(4))) float f32x4;

__device__ inline u16 f2bf(float f) {
  u32 u = __float_as_uint(f);
  u += 0x7fffu + ((u >> 16) & 1u);
  return (u16)(u >> 16);
}

// ---------------------------------------------------------------- LayerNorm (bf16 out)
__global__ __launch_bounds__(256) void ln_kernel(const float* __restrict__ in,
                                                 const float* __restrict__ gw,
                                                 const float* __restrict__ bw,
                                                 u16* __restrict__ out) {
  const int wave = threadIdx.x >> 6, lane = threadIdx.x & 63;
  const int row = (blockIdx.x << 2) + wave;
  const float4 v = reinterpret_cast<const float4*>(in + (size_t)row * D_)[lane];
  float s = v.x + v.y + v.z + v.w;
#pragma unroll
  for (int off = 32; off > 0; off >>= 1) s += __shfl_xor(s, off);
  const float m = s * (1.0f / D_);
  const float dx = v.x - m, dy = v.y - m, dz = v.z - m, dw = v.w - m;
  float s2 = dx * dx + dy * dy + dz * dz + dw * dw;
#pragma unroll
  for (int off = 32; off > 0; off >>= 1) s2 += __shfl_xor(s2, off);
  const float inv = rsqrtf(s2 * (1.0f / D_) + 1e-5f);
  const float4 g4 = reinterpret_cast<const float4*>(gw)[lane];
  const float4 b4 = reinterpret_cast<const float4*>(bw)[lane];
  ushort4 o;
  o.x = f2bf(dx * inv * g4.x + b4.x);
  o.y = f2bf(dy * inv * g4.y + b4.y);
  o.z = f2bf(dz * inv * g4.z + b4.z);
  o.w = f2bf(dw * inv * g4.w + b4.w);
  *reinterpret_cast<ushort4*>(out + (size_t)row * D_ + (lane << 2)) = o;
}

// ---------------------------------------------------------------- fused weight prep
__global__ void wt_conv_all(const float* __restrict__ wq, const float* __restrict__ wk,
                            const float* __restrict__ wv, const float* __restrict__ w1,
                            const float* __restrict__ w2,
                            u16* __restrict__ wqkvt, u16* __restrict__ w1t,
                            u16* __restrict__ w2t,
                            const float* __restrict__ bq, const float* __restrict__ bk,
                            const float* __restrict__ bv, float* __restrict__ bqkv,
                            u32* __restrict__ cnt) {
  const int bid = blockIdx.x;
  const int tx = threadIdx.x, ty = threadIdx.y;
  if (bid == 704) {
    const int t = ty * 32 + tx;
    for (int i = t; i < 768; i += 256)
      bqkv[i] = (i < 256) ? bq[i] : (i < 512 ? bk[i - 256] : bv[i - 512]);
    for (int i = t; i < 1024; i += 256) cnt[i] = 0u;
    return;
  }
  const float* W; u16* Wt; int K, Nc, ro, local;
  if (bid < 64)       { W = wq; Wt = wqkvt; K = 256;  Nc = 256;  ro = 0;   local = bid; }
  else if (bid < 128) { W = wk; Wt = wqkvt; K = 256;  Nc = 256;  ro = 256; local = bid - 64; }
  else if (bid < 192) { W = wv; Wt = wqkvt; K = 256;  Nc = 256;  ro = 512; local = bid - 128; }
  else if (bid < 448) { W = w1; Wt = w1t;   K = 256;  Nc = 1024; ro = 0;   local = bid - 192; }
  else                { W = w2; Wt = w2t;   K = 1024; Nc = 256;  ro = 0;   local = bid - 448; }
  const int tn = Nc >> 5;
  const int n0 = (local % tn) << 5, k0 = (local / tn) << 5;
  __shared__ float tl[32][33];
#pragma unroll
  for (int i = 0; i < 4; ++i)
    tl[ty + (i << 3)][tx] = W[(size_t)(k0 + ty + (i << 3)) * Nc + n0 + tx];
  __syncthreads();
#pragma unroll
  for (int i = 0; i < 4; ++i)
    Wt[(size_t)(ro + n0 + ty + (i << 3)) * K + k0 + tx] = f2bf(tl[tx][ty + (i << 3)]);
}

// ---------------------------------------------------------------- edge prep
// gated weights for all 8 heads (bf16x8); bucket by (g, ls>>5, ld>>8) -> 1024 buckets
__global__ __launch_bounds__(256) void edge_prep(const int* __restrict__ ei,
                                                 const float* __restrict__ ea,
                                                 const float* __restrict__ wep,
                                                 const float* __restrict__ bep,
                                                 const float* __restrict__ weg,
                                                 const float* __restrict__ beg,
                                                 u32* __restrict__ cnt,
                                                 u32* __restrict__ rec_id,
                                                 uint4* __restrict__ rec_ew) {
  const int e = blockIdx.x * 256 + threadIdx.x;
  const int ls = ei[e] & 511;
  const int ld = ei[E_ + e] & 511;
  const int bk = ((e >> 13) << 5) | ((ls >> 5) << 1) | (ld >> 8);
  const u32 pos = atomicAdd(&cnt[bk], 1u);
  if (pos < (u32)BCAP) {
    const float2 a2 = reinterpret_cast<const float2*>(ea)[e];
    u32 wds[4];
#pragma unroll
    for (int hp = 0; hp < 4; ++hp) {
      u32 wd = 0;
#pragma unroll
      for (int s = 0; s < 2; ++s) {
        const int h = hp * 2 + s;
        const float pre = a2.x * wep[h] + a2.y * wep[H_ + h] + bep[h];
        const float gat = a2.x * weg[h] + a2.y * weg[H_ + h] + beg[h];
        const float ew = pre / (1.0f + __expf(-gat));
        wd |= ((u32)f2bf(ew)) << (s * 16);
      }
      wds[hp] = wd;
    }
    rec_id[bk * BCAP + pos] = (u32)((ls & 31) | ((ld & 255) << 5));
    rec_ew[(size_t)bk * BCAP + pos] = make_uint4(wds[0], wds[1], wds[2], wds[3]);
  }
}

// ---------------------------------------------------------------- MFMA GEMM
// Staging now via global_load_lds width=16 with PRE-SWIZZLED global source:
// LDS dest stays lane-linear (HW requirement); the XOR swizzle is applied to the
// source granule index, so the MFMA-side swizzled ds_reads are unchanged.
template <int ACT, int OUTM>
__global__ __launch_bounds__(256) void mgemm(const u16* __restrict__ A,
                                             const u16* __restrict__ Bt,
                                             const float* __restrict__ bias,
                                             const float* __restrict__ res,
                                             float* __restrict__ Cf,
                                             u16* __restrict__ Cb,
                                             u16* __restrict__ Vt,
                                             int K, int Nc) {
  __shared__ u16 s_all[17408];
  u16* sA = s_all;
  u16* sB = s_all + 8192;
  const int t = threadIdx.x;
  const int row0 = blockIdx.x << 7;
  const int col0 = blockIdx.y << 7;
  const int lane = t & 63, w = t >> 6;
  const int ql = lane & 15, u = lane >> 4;
  const int wr = w >> 1, wc = w & 1;
  const int wbase = (t >> 6) << 6;  // wave-uniform lane base

  f32x4 acc[4][4];
#pragma unroll
  for (int i = 0; i < 4; ++i)
#pragma unroll
    for (int j = 0; j < 4; ++j) acc[i][j] = (f32x4){0.f, 0.f, 0.f, 0.f};

  const u16* Ab = A + (size_t)row0 * K;
  const u16* Bb = Bt + (size_t)col0 * K;

  for (int k0 = 0; k0 < K; k0 += 64) {
    __syncthreads();
#pragma unroll
    for (int it = 0; it < 4; ++it) {
      const int idx = (it << 8) + t;
      const int row = idx >> 3;
      const int gcs = (idx & 7) ^ (row & 7);  // pre-swizzled source granule
      __builtin_amdgcn_global_load_lds(
          (const __attribute__((address_space(1))) u32*)(Ab + (size_t)row * K + k0 + (gcs << 3)),
          (__attribute__((address_space(3))) u32*)(sA + (((it << 8) + wbase) << 3)),
          16, 0, 0);
    }
#pragma unroll
    for (int it = 0; it < 4; ++it) {
      const int idx = (it << 8) + t;
      const int row = idx >> 3;
      const int gcs = (idx & 7) ^ (row & 7);
      __builtin_amdgcn_global_load_lds(
          (const __attribute__((address_space(1))) u32*)(Bb + (size_t)row * K + k0 + (gcs << 3)),
          (__attribute__((address_space(3))) u32*)(sB + (((it << 8) + wbase) << 3)),
          16, 0, 0);
    }
    __syncthreads();
#pragma unroll
    for (int ks = 0; ks < 2; ++ks) {
      const int gk = (ks << 2) + u;
      s16x8 aF[4], bF[4];
#pragma unroll
      for (int i = 0; i < 4; ++i) {
        const int ra = (wr << 6) + (i << 4) + ql;
        aF[i] = *reinterpret_cast<const s16x8*>(sA + ra * 64 + ((gk ^ (ra & 7)) << 3));
        const int rb = (wc << 6) + (i << 4) + ql;
        bF[i] = *reinterpret_cast<const s16x8*>(sB + rb * 64 + ((gk ^ (rb & 7)) << 3));
      }
#pragma unroll
      for (int i = 0; i < 4; ++i)
#pragma unroll
        for (int j = 0; j < 4; ++j)
          acc[i][j] = __builtin_amdgcn_mfma_f32_16x16x32_bf16(aF[i], bF[j], acc[i][j], 0, 0, 0);
    }
  }

  float b_[4];
#pragma unroll
  for (int j = 0; j < 4; ++j) b_[j] = bias[col0 + (wc << 6) + (j << 4) + ql];

  if (OUTM == 1) {
#pragma unroll
    for (int i = 0; i < 4; ++i)
#pragma unroll
      for (int j = 0; j < 4; ++j)
#pragma unroll
        for (int r = 0; r < 4; ++r) {
          const int row = row0 + (wr << 6) + (i << 4) + (u << 2) + r;
          const int col = col0 + (wc << 6) + (j << 4) + ql;
          Cf[(size_t)row * Nc + col] = acc[i][j][r] + b_[j] + res[(size_t)row * Nc + col];
        }
    return;
  }

  bool rowmajor = (OUTM == 0);
  if (OUTM == 2) {
    if (col0 < 512) rowmajor = true;
    else {
      const int g = row0 >> 9;
      const int key0 = (row0 & 511) + (wr << 6);
#pragma unroll
      for (int i = 0; i < 4; ++i)
#pragma unroll
        for (int j = 0; j < 4; ++j) {
          const int c = (col0 - 512) + (wc << 6) + (j << 4) + ql;
          const int hh = c >> 5, d = c & 31;
          ushort4 pk;
          pk.x = f2bf(acc[i][j][0] + b_[j]);
          pk.y = f2bf(acc[i][j][1] + b_[j]);
          pk.z = f2bf(acc[i][j][2] + b_[j]);
          pk.w = f2bf(acc[i][j][3] + b_[j]);
          *reinterpret_cast<ushort4*>(Vt + ((((size_t)g << 3) + hh) << 14) + d * 512 +
                                      key0 + (i << 4) + (u << 2)) = pk;
        }
      return;
    }
  }

  if (rowmajor) {
    __syncthreads();
    u16* sC = s_all;  // [128][136]
#pragma unroll
    for (int i = 0; i < 4; ++i)
#pragma unroll
      for (int j = 0; j < 4; ++j)
#pragma unroll
        for (int r = 0; r < 4; ++r) {
          float v = acc[i][j][r] + b_[j];
          if (ACT) v = fmaxf(v, 0.f);
          const int row = (wr << 6) + (i << 4) + (u << 2) + r;
          const int col = (wc << 6) + (j << 4) + ql;
          sC[row * 136 + col] = f2bf(v);
        }
    __syncthreads();
    const int ncb = (OUTM == 2) ? 512 : Nc;
#pragma unroll
    for (int it = 0; it < 8; ++it) {
      const int idx = (it << 8) + t;
      const int row = idx >> 4, gc = idx & 15;
      *reinterpret_cast<s16x8*>(Cb + (size_t)(row0 + row) * ncb + col0 + (gc << 3)) =
          *reinterpret_cast<const s16x8*>(sC + row * 136 + (gc << 3));
    }
  }
}

// ---------------------------------------------------------------- Attention v5 (round-5 revert)
// Two-pass key halves over a [256][36] bias slab -> LDS 40,448 B -> 4 WG/CU.
__global__ __launch_bounds__(256) void attn_kernel(
    const u16* __restrict__ qk, const u16* __restrict__ vt,
    const u32* __restrict__ rec_id, const uint4* __restrict__ rec_ew,
    const u32* __restrict__ cnt, const float* __restrict__ relpos,
    const float* __restrict__ x, float* __restrict__ x1) {
  extern __shared__ u32 smem_u[];
  float* s_bias = (float*)smem_u;             // [256][36] f32
  u16* s_p = (u16*)smem_u;                    // [32][512] bf16 (alias)
  float* s_ot = (float*)(smem_u + 8192);      // [32][36] f32 (alias)
  u32* s_mask = smem_u + 9344;                // [32][16]
  float* s_statM = (float*)(smem_u + 9856);   // [2][64]
  float* s_statS = (float*)(smem_u + 9984);   // [2][64]

  const int braw = blockIdx.x;
  const int b = ((braw & 7) << 9) + (braw >> 3);  // XCD swizzle (4096 % 8 == 0)
  const int qt = b & 15, h = (b >> 4) & 7, g = b >> 7;
  const int t = threadIdx.x;
  const int n0 = (g << 9) + (qt << 5);
  const int lane = t & 63, w = t >> 6;
  const int ql = lane & 15, u = lane >> 4;

  // ---- prefetch Q (2) + K (2x2) fragments
  s16x8 qf8[2], kf8[8];
#pragma unroll
  for (int qf = 0; qf < 2; ++qf)
    qf8[qf] = *reinterpret_cast<const s16x8*>(
        qk + (size_t)(n0 + (qf << 4) + ql) * 512 + (h << 5) + (u << 3));
#pragma unroll
  for (int kf = 0; kf < 8; ++kf) {
    const int half = kf >> 2, kf2 = kf & 3;
    kf8[kf] = *reinterpret_cast<const s16x8*>(
        qk + (size_t)((g << 9) + (half << 8) + (w << 6) + (kf2 << 4) + ql) * 512 + 256 +
        (h << 5) + (u << 3));
  }

  {  // zero bias + ot-slack + mask (dwords [0, 9856))
    f32x4* z = (f32x4*)smem_u;
    const f32x4 zv = {0.f, 0.f, 0.f, 0.f};
    for (int i = t; i < 2464; i += 256) z[i] = zv;
  }

  // ---- QK^T in registers (all 16 MFMAs up front)
  f32x4 acc[8][2];
#pragma unroll
  for (int kf = 0; kf < 8; ++kf)
#pragma unroll
    for (int qf = 0; qf < 2; ++qf) acc[kf][qf] = (f32x4){0.f, 0.f, 0.f, 0.f};
#pragma unroll
  for (int kf = 0; kf < 8; ++kf)
#pragma unroll
    for (int qf = 0; qf < 2; ++qf)
      acc[kf][qf] = __builtin_amdgcn_mfma_f32_16x16x32_bf16(kf8[kf], qf8[qf], acc[kf][qf], 0, 0, 0);

  const float scale = 0.17677669529663687f;  // 1/sqrt(32)
  const float rpv = relpos[h];
  float mx[2] = {-1e30f, -1e30f};

#pragma unroll
  for (int half = 0; half < 2; ++half) {
    if (half) {
      __syncthreads();  // apply(0) bias reads complete
      f32x4* z = (f32x4*)smem_u;
      const f32x4 zv = {0.f, 0.f, 0.f, 0.f};
      for (int i = t; i < 2304; i += 256) z[i] = zv;
    }
    __syncthreads();  // zero complete

    {  // scatter this half's records
      const int bkt = (g << 5) | (qt << 1) | half;
      const u32 cn = cnt[bkt];
      const int n = cn > (u32)BCAP ? BCAP : (int)cn;
      const u32* ridb = rec_id + bkt * BCAP;
      const u32* rewb = (const u32*)(rec_ew + (size_t)bkt * BCAP) + (h >> 1);
      for (int i = t; i < n; i += 256) {
        const u32 id = ridb[i];
        const u32 wrd = rewb[(size_t)i << 2];
        const u32 bits = (h & 1) ? (wrd & 0xffff0000u) : (wrd << 16);
        const int lsq = id & 31, ld8 = (int)(id >> 5);
        atomicAdd(&s_bias[ld8 * 36 + lsq], __uint_as_float(bits));
        if (g == 0) atomicOr(&s_mask[(lsq << 4) + (half << 3) + (ld8 >> 5)], 1u << (ld8 & 31));
      }
    }
    __syncthreads();  // scatter complete

    {  // apply bias + rel_pos mask, track row max
      u32 m4[2][2] = {{0u, 0u}, {0u, 0u}};
      if (g == 0) {
#pragma unroll
        for (int qf = 0; qf < 2; ++qf)
#pragma unroll
          for (int i = 0; i < 2; ++i)
            m4[qf][i] = s_mask[(((qf << 4) + ql) << 4) + (half << 3) + (w << 1) + i];
      }
#pragma unroll
      for (int kf2 = 0; kf2 < 4; ++kf2) {
        const int kf = (half << 2) + kf2;
#pragma unroll
        for (int qf = 0; qf < 2; ++qf) {
#pragma unroll
          for (int r = 0; r < 4; ++r) {
            const int kidx = (w << 6) + (kf2 << 4) + (u << 2) + r;  // kl & 255
            float v = acc[kf][qf][r] * scale + s_bias[kidx * 36 + (qf << 4) + ql];
            const int bit = ((kf2 & 1) << 4) + (u << 2) + r;
            if ((m4[qf][kf2 >> 1] >> bit) & 1u) v += rpv;
            acc[kf][qf][r] = v;
            mx[qf] = fmaxf(mx[qf], v);
          }
        }
      }
    }
  }

#pragma unroll
  for (int qf = 0; qf < 2; ++qf) {
    mx[qf] = fmaxf(mx[qf], __shfl_xor(mx[qf], 16));
    mx[qf] = fmaxf(mx[qf], __shfl_xor(mx[qf], 32));
  }
  if (lane < 16) {
    s_statM[(ql << 2) + w] = mx[0];
    s_statM[64 + (ql << 2) + w] = mx[1];
  }
  __syncthreads();  // apply(1) bias reads done; statM visible; P region writable

  {  // ---- exp + P (bf16, swizzled) + sums
    float M[2], sum[2] = {0.f, 0.f};
#pragma unroll
    for (int qf = 0; qf < 2; ++qf) {
      const f32x4 m4v = *reinterpret_cast<const f32x4*>(s_statM + (qf << 6) + (ql << 2));
      M[qf] = fmaxf(fmaxf(m4v.x, m4v.y), fmaxf(m4v.z, m4v.w));
    }
#pragma unroll
    for (int kf = 0; kf < 8; ++kf) {
      const int half = kf >> 2, kf2 = kf & 3;
#pragma unroll
      for (int qf = 0; qf < 2; ++qf) {
        const int q = (qf << 4) + ql;
        float e[4];
#pragma unroll
        for (int r = 0; r < 4; ++r) {
          e[r] = __expf(acc[kf][qf][r] - M[qf]);
          sum[qf] += e[r];
        }
        const int kl0 = (half << 8) + (w << 6) + (kf2 << 4) + (u << 2);
        const int gran = kl0 >> 3;
        uint2 pw;
        pw.x = (u32)f2bf(e[0]) | ((u32)f2bf(e[1]) << 16);
        pw.y = (u32)f2bf(e[2]) | ((u32)f2bf(e[3]) << 16);
        *reinterpret_cast<uint2*>(s_p + (q << 9) + ((gran ^ (q & 7)) << 3) + (kl0 & 7)) = pw;
      }
    }
#pragma unroll
    for (int qf = 0; qf < 2; ++qf) {
      sum[qf] += __shfl_xor(sum[qf], 16);
      sum[qf] += __shfl_xor(sum[qf], 32);
    }
    if (lane < 16) {
      s_statS[(ql << 2) + w] = sum[0];
      s_statS[64 + (ql << 2) + w] = sum[1];
    }
  }
  __syncthreads();  // P + sums visible

  {  // ---- PV: wave -> (wd dim-frag, wq q-frag); full 512 keys
    const int wq = w & 1, wd = w >> 1;
    const u16* vtb = vt + ((((size_t)g << 3) + h) << 14) + (size_t)((wd << 4) + ql) * 512;
    const int q = (wq << 4) + ql;
    f32x4 o = (f32x4){0.f, 0.f, 0.f, 0.f};
#pragma unroll
    for (int ks = 0; ks < 16; ++ks) {
      const s16x8 va = *reinterpret_cast<const s16x8*>(vtb + (ks << 5) + (u << 3));
      const int gran = (ks << 2) + u;
      const s16x8 pb = *reinterpret_cast<const s16x8*>(s_p + (q << 9) + ((gran ^ (q & 7)) << 3));
      o = __builtin_amdgcn_mfma_f32_16x16x32_bf16(va, pb, o, 0, 0, 0);
    }
    const f32x4 s4 = *reinterpret_cast<const f32x4*>(s_statS + (wq << 6) + (ql << 2));
    const float invS = 1.0f / (s4.x + s4.y + s4.z + s4.w);
#pragma unroll
    for (int r = 0; r < 4; ++r)
      s_ot[q * 36 + (wd << 4) + (u << 2) + r] = o[r] * invS;
  }
  __syncthreads();

  {  // ---- epilogue: + x residual
    const int q = t >> 3, d4 = (t & 7) << 2;
    const f32x4 ov = *reinterpret_cast<const f32x4*>(s_ot + q * 36 + d4);
    const size_t oi = (size_t)(n0 + q) * D_ + (h << 5) + d4;
    const f32x4 xv = *reinterpret_cast<const f32x4*>(x + oi);
    f32x4 o;
#pragma unroll
    for (int j = 0; j < 4; ++j) o[j] = ov[j] + xv[j];
    *reinterpret_cast<f32x4*>(x1 + oi) = o;
  }
}

// ---------------------------------------------------------------- launch
extern "C" void kernel_launch(void* const* d_in, const int* in_sizes, int n_in,
                              void* d_out, int out_size, void* d_ws, size_t ws_size,
                              hipStream_t stream) {
  const float* x    = (const float*)d_in[0];
  const int*   ei   = (const int*)d_in[1];
  const float* ea   = (const float*)d_in[2];
  const float* ln1g = (const float*)d_in[3];
  const float* ln1b = (const float*)d_in[4];
  const float* wq   = (const float*)d_in[5];
  const float* bq   = (const float*)d_in[6];
  const float* wk   = (const float*)d_in[7];
  const float* bk   = (const float*)d_in[8];
  const float* wv   = (const float*)d_in[9];
  const float* bv   = (const float*)d_in[10];
  const float* wep  = (const float*)d_in[11];
  const float* bep  = (const float*)d_in[12];
  const float* weg  = (const float*)d_in[13];
  const float* beg  = (const float*)d_in[14];
  const float* rp   = (const float*)d_in[15];
  const float* w1   = (const float*)d_in[16];
  const float* b1   = (const float*)d_in[17];
  const float* w2   = (const float*)d_in[18];
  const float* b2   = (const float*)d_in[19];
  const float* ln2g = (const float*)d_in[20];
  const float* ln2b = (const float*)d_in[21];
  float* out = (float*)d_out;

  float* ws = (float*)d_ws;
  const size_t M1 = 1048576;
  u16* xn   = (u16*)ws;                       // [16384][256] bf16
  u16* qk   = (u16*)(ws + 2 * M1);            // [16384][512] bf16 (Q|K)
  u16* vt   = (u16*)(ws + 6 * M1);            // [256][32][512] bf16
  u16* f1   = (u16*)ws;                       // [16384][1024] bf16 (alias, post-attn)
  float* x1 = ws + 8 * M1;                    // f32
  u16* h2   = (u16*)(ws + 12 * M1);           // bf16
  u16* wqkvt = (u16*)(ws + 14 * M1);          // [768][256] bf16
  u16* w1t  = (u16*)(ws + 14 * M1 + 262144);  // [1024][256] bf16
  u16* w2t  = (u16*)(ws + 14 * M1 + 524288);  // [256][1024] bf16
  float* bqkv = ws + 14 * M1 + 786432;        // [768] f32
  u32* cnt  = (u32*)(ws + 14 * M1 + 787456);  // [1024] u32
  u32* rec_id = (u32*)(ws + 15 * M1);         // [1024*512] u32 (2MB)
  uint4* rec_ew = (uint4*)(ws + 16 * M1);     // [1024*512] uint4 (8MB)

  // 0. fused weight prep (packs bqkv + zeros cnt), then edge prep
  wt_conv_all<<<dim3(705), dim3(32, 8), 0, stream>>>(wq, wk, wv, w1, w2, wqkvt, w1t, w2t,
                                                     bq, bk, bv, bqkv, cnt);
  edge_prep<<<dim3(E_ / 256), dim3(256), 0, stream>>>(ei, ea, wep, bep, weg, beg,
                                                      cnt, rec_id, rec_ew);
  // 1. LN1 -> bf16
  ln_kernel<<<dim3(N_ / 4), dim3(256), 0, stream>>>(x, ln1g, ln1b, xn);
  // 2. fused QKV GEMM: Q,K -> qk row-major; V -> vt transposed
  mgemm<0, 2><<<dim3(128, 6), 256, 0, stream>>>(xn, wqkvt, bqkv, nullptr, nullptr, qk, vt, 256, 768);
  // 3. attention (+x residual) -> x1 f32
  const int smem_attn = 10112 * 4;  // 40,448 B -> 4 WG/CU
  (void)hipFuncSetAttribute(reinterpret_cast<const void*>(attn_kernel),
                            hipFuncAttributeMaxDynamicSharedMemorySize, smem_attn);
  attn_kernel<<<dim3(G_ * H_ * 16), 256, smem_attn, stream>>>(qk, vt, rec_id, rec_ew, cnt,
                                                              rp, x, x1);
  // 4. LN2 -> bf16
  ln_kernel<<<dim3(N_ / 4), dim3(256), 0, stream>>>(x1, ln2g, ln2b, h2);
  // 5. FF1 (relu) -> f1 bf16
  mgemm<1, 0><<<dim3(128, 8), 256, 0, stream>>>(h2, w1t, b1, nullptr, nullptr, f1, nullptr, 256, 1024);
  // 6. FF2 (+bias +x1 residual) -> out f32
  mgemm<0, 1><<<dim3(128, 2), 256, 0, stream>>>(f1, w2t, b2, x1, out, nullptr, nullptr, 1024, 256);
}

// Round 9
// 191.678 us; speedup vs baseline: 1.3052x; 1.0916x over previous
//
#include <hip/hip_runtime.h>
#include <math.h>

#define G_   32
#define NPG_ 512
#define N_   16384
#define E_   262144
#define D_   256
#define H_   8
#define FF_  1024
#define BCAP 512   // per (g, qt16, key-half) bucket, 4 shards x 128

typedef unsigned int u32;
typedef unsigned short u16;
typedef __attribute__((ext_vector_type(8))) short s16x8;   // 8 x bf16
typedef __attribute__((ext_vector_type(4))) float f32x4;

__device__ inline u16 f2bf(float f) {
  u32 u = __float_as_uint(f);
  u += 0x7fffu + ((u >> 16) & 1u);
  return (u16)(u >> 16);
}

// ---------------------------------------------------------------- LayerNorm (bf16 out)
__global__ __launch_bounds__(256) void ln_kernel(const float* __restrict__ in,
                                                 const float* __restrict__ gw,
                                                 const float* __restrict__ bw,
                                                 u16* __restrict__ out) {
  const int wave = threadIdx.x >> 6, lane = threadIdx.x & 63;
  const int row = (blockIdx.x << 2) + wave;
  const float4 v = reinterpret_cast<const float4*>(in + (size_t)row * D_)[lane];
  float s = v.x + v.y + v.z + v.w;
#pragma unroll
  for (int off = 32; off > 0; off >>= 1) s += __shfl_xor(s, off);
  const float m = s * (1.0f / D_);
  const float dx = v.x - m, dy = v.y - m, dz = v.z - m, dw = v.w - m;
  float s2 = dx * dx + dy * dy + dz * dz + dw * dw;
#pragma unroll
  for (int off = 32; off > 0; off >>= 1) s2 += __shfl_xor(s2, off);
  const float inv = rsqrtf(s2 * (1.0f / D_) + 1e-5f);
  const float4 g4 = reinterpret_cast<const float4*>(gw)[lane];
  const float4 b4 = reinterpret_cast<const float4*>(bw)[lane];
  ushort4 o;
  o.x = f2bf(dx * inv * g4.x + b4.x);
  o.y = f2bf(dy * inv * g4.y + b4.y);
  o.z = f2bf(dz * inv * g4.z + b4.z);
  o.w = f2bf(dw * inv * g4.w + b4.w);
  *reinterpret_cast<ushort4*>(out + (size_t)row * D_ + (lane << 2)) = o;
}

// ---------------------------------------------------------------- fused weight prep
__global__ void wt_conv_all(const float* __restrict__ wq, const float* __restrict__ wk,
                            const float* __restrict__ wv, const float* __restrict__ w1,
                            const float* __restrict__ w2,
                            u16* __restrict__ wqkvt, u16* __restrict__ w1t,
                            u16* __restrict__ w2t,
                            const float* __restrict__ bq, const float* __restrict__ bk,
                            const float* __restrict__ bv, float* __restrict__ bqkv,
                            u32* __restrict__ cnt) {
  const int bid = blockIdx.x;
  const int tx = threadIdx.x, ty = threadIdx.y;
  if (bid == 704) {
    const int t = ty * 32 + tx;
    for (int i = t; i < 768; i += 256)
      bqkv[i] = (i < 256) ? bq[i] : (i < 512 ? bk[i - 256] : bv[i - 512]);
    for (int i = t; i < 4096; i += 256) cnt[i] = 0u;
    return;
  }
  const float* W; u16* Wt; int K, Nc, ro, local;
  if (bid < 64)       { W = wq; Wt = wqkvt; K = 256;  Nc = 256;  ro = 0;   local = bid; }
  else if (bid < 128) { W = wk; Wt = wqkvt; K = 256;  Nc = 256;  ro = 256; local = bid - 64; }
  else if (bid < 192) { W = wv; Wt = wqkvt; K = 256;  Nc = 256;  ro = 512; local = bid - 128; }
  else if (bid < 448) { W = w1; Wt = w1t;   K = 256;  Nc = 1024; ro = 0;   local = bid - 192; }
  else                { W = w2; Wt = w2t;   K = 1024; Nc = 256;  ro = 0;   local = bid - 448; }
  const int tn = Nc >> 5;
  const int n0 = (local % tn) << 5, k0 = (local / tn) << 5;
  __shared__ float tl[32][33];
#pragma unroll
  for (int i = 0; i < 4; ++i)
    tl[ty + (i << 3)][tx] = W[(size_t)(k0 + ty + (i << 3)) * Nc + n0 + tx];
  __syncthreads();
#pragma unroll
  for (int i = 0; i < 4; ++i)
    Wt[(size_t)(ro + n0 + ty + (i << 3)) * K + k0 + tx] = f2bf(tl[tx][ty + (i << 3)]);
}

// ---------------------------------------------------------------- edge prep
// gated weights all 8 heads (bf16x8); buckets (g, ls>>5, ld>>8) x 4 shards
__global__ __launch_bounds__(256) void edge_prep(const int* __restrict__ ei,
                                                 const float* __restrict__ ea,
                                                 const float* __restrict__ wep,
                                                 const float* __restrict__ bep,
                                                 const float* __restrict__ weg,
                                                 const float* __restrict__ beg,
                                                 u32* __restrict__ cnt,
                                                 u32* __restrict__ rec_id,
                                                 uint4* __restrict__ rec_ew) {
  const int e = blockIdx.x * 256 + threadIdx.x;
  const int ls = ei[e] & 511;
  const int ld = ei[E_ + e] & 511;
  const int bk = ((e >> 13) << 5) | ((ls >> 5) << 1) | (ld >> 8);
  const int sh = threadIdx.x & 3;
  const u32 pos = atomicAdd(&cnt[(bk << 2) + sh], 1u);
  if (pos < 128u) {
    const float2 a2 = reinterpret_cast<const float2*>(ea)[e];
    u32 wds[4];
#pragma unroll
    for (int hp = 0; hp < 4; ++hp) {
      u32 wd = 0;
#pragma unroll
      for (int s = 0; s < 2; ++s) {
        const int h = hp * 2 + s;
        const float pre = a2.x * wep[h] + a2.y * wep[H_ + h] + bep[h];
        const float gat = a2.x * weg[h] + a2.y * weg[H_ + h] + beg[h];
        const float ew = pre / (1.0f + __expf(-gat));
        wd |= ((u32)f2bf(ew)) << (s * 16);
      }
      wds[hp] = wd;
    }
    rec_id[bk * BCAP + (sh << 7) + pos] = (u32)((ls & 31) | ((ld & 255) << 5));
    rec_ew[(size_t)bk * BCAP + (sh << 7) + pos] = make_uint4(wds[0], wds[1], wds[2], wds[3]);
  }
}

// ---------------------------------------------------------------- MFMA GEMM narrow (FF2)
// BM=BN=128, 256 threads; gload_lds staging with pre-swizzled source.
__global__ __launch_bounds__(256) void mgemm_res(const u16* __restrict__ A,
                                                 const u16* __restrict__ Bt,
                                                 const float* __restrict__ bias,
                                                 const float* __restrict__ res,
                                                 float* __restrict__ Cf,
                                                 int K, int Nc) {
  __shared__ u16 s_all[16384];
  u16* sA = s_all;
  u16* sB = s_all + 8192;
  const int t = threadIdx.x;
  const int row0 = blockIdx.x << 7;
  const int col0 = blockIdx.y << 7;
  const int lane = t & 63, w = t >> 6;
  const int ql = lane & 15, u = lane >> 4;
  const int wr = w >> 1, wc = w & 1;

  f32x4 acc[4][4];
#pragma unroll
  for (int i = 0; i < 4; ++i)
#pragma unroll
    for (int j = 0; j < 4; ++j) acc[i][j] = (f32x4){0.f, 0.f, 0.f, 0.f};

  const u16* Ab = A + (size_t)row0 * K;
  const u16* Bb = Bt + (size_t)col0 * K;

  for (int k0 = 0; k0 < K; k0 += 64) {
    __syncthreads();
#pragma unroll
    for (int it = 0; it < 4; ++it) {
      const int idx = (it << 8) + t;
      const int row = idx >> 3;
      const int gcs = (idx & 7) ^ (row & 7);
      __builtin_amdgcn_global_load_lds(
          (const __attribute__((address_space(1))) u32*)(Ab + (size_t)row * K + k0 + (gcs << 3)),
          (__attribute__((address_space(3))) u32*)(sA + (idx << 3)), 16, 0, 0);
    }
#pragma unroll
    for (int it = 0; it < 4; ++it) {
      const int idx = (it << 8) + t;
      const int row = idx >> 3;
      const int gcs = (idx & 7) ^ (row & 7);
      __builtin_amdgcn_global_load_lds(
          (const __attribute__((address_space(1))) u32*)(Bb + (size_t)row * K + k0 + (gcs << 3)),
          (__attribute__((address_space(3))) u32*)(sB + (idx << 3)), 16, 0, 0);
    }
    __syncthreads();
#pragma unroll
    for (int ks = 0; ks < 2; ++ks) {
      const int gk = (ks << 2) + u;
      s16x8 aF[4], bF[4];
#pragma unroll
      for (int i = 0; i < 4; ++i) {
        const int ra = (wr << 6) + (i << 4) + ql;
        aF[i] = *reinterpret_cast<const s16x8*>(sA + ra * 64 + ((gk ^ (ra & 7)) << 3));
        const int rb = (wc << 6) + (i << 4) + ql;
        bF[i] = *reinterpret_cast<const s16x8*>(sB + rb * 64 + ((gk ^ (rb & 7)) << 3));
      }
#pragma unroll
      for (int i = 0; i < 4; ++i)
#pragma unroll
        for (int j = 0; j < 4; ++j)
          acc[i][j] = __builtin_amdgcn_mfma_f32_16x16x32_bf16(aF[i], bF[j], acc[i][j], 0, 0, 0);
    }
  }

  float b_[4];
#pragma unroll
  for (int j = 0; j < 4; ++j) b_[j] = bias[col0 + (wc << 6) + (j << 4) + ql];
#pragma unroll
  for (int i = 0; i < 4; ++i)
#pragma unroll
    for (int j = 0; j < 4; ++j)
#pragma unroll
      for (int r = 0; r < 4; ++r) {
        const int row = row0 + (wr << 6) + (i << 4) + (u << 2) + r;
        const int col = col0 + (wc << 6) + (j << 4) + ql;
        Cf[(size_t)row * Nc + col] = acc[i][j][r] + b_[j] + res[(size_t)row * Nc + col];
      }
}

// ---------------------------------------------------------------- MFMA GEMM wide (QKV, FF1)
// BM=128, BN=256, 512 threads (8 waves: wr=w>>2, wc=w&3).
// OUTM: 0 = bf16 row-major (2-half LDS repack, optional ACT), 2 = QKV routing.
template <int ACT, int OUTM>
__global__ __launch_bounds__(512) void mgemm_w(const u16* __restrict__ A,
                                               const u16* __restrict__ Bt,
                                               const float* __restrict__ bias,
                                               u16* __restrict__ Cb,
                                               u16* __restrict__ Vt,
                                               int K, int Nc) {
  __shared__ u16 s_all[24576];  // sA[128][64] | sB[256][64]; sC[128][136] alias
  u16* sA = s_all;
  u16* sB = s_all + 8192;
  const int t = threadIdx.x;
  const int row0 = blockIdx.x << 7;
  const int col0 = blockIdx.y << 8;
  const int lane = t & 63, w = t >> 6;
  const int ql = lane & 15, u = lane >> 4;
  const int wr = w >> 2, wc = w & 3;

  f32x4 acc[4][4];
#pragma unroll
  for (int i = 0; i < 4; ++i)
#pragma unroll
    for (int j = 0; j < 4; ++j) acc[i][j] = (f32x4){0.f, 0.f, 0.f, 0.f};

  const u16* Ab = A + (size_t)row0 * K;
  const u16* Bb = Bt + (size_t)col0 * K;

  for (int k0 = 0; k0 < K; k0 += 64) {
    __syncthreads();
#pragma unroll
    for (int it = 0; it < 2; ++it) {
      const int idx = (it << 9) + t;
      const int row = idx >> 3;
      const int gcs = (idx & 7) ^ (row & 7);
      __builtin_amdgcn_global_load_lds(
          (const __attribute__((address_space(1))) u32*)(Ab + (size_t)row * K + k0 + (gcs << 3)),
          (__attribute__((address_space(3))) u32*)(sA + (idx << 3)), 16, 0, 0);
    }
#pragma unroll
    for (int it = 0; it < 4; ++it) {
      const int idx = (it << 9) + t;
      const int row = idx >> 3;
      const int gcs = (idx & 7) ^ (row & 7);
      __builtin_amdgcn_global_load_lds(
          (const __attribute__((address_space(1))) u32*)(Bb + (size_t)row * K + k0 + (gcs << 3)),
          (__attribute__((address_space(3))) u32*)(sB + (idx << 3)), 16, 0, 0);
    }
    __syncthreads();
#pragma unroll
    for (int ks = 0; ks < 2; ++ks) {
      const int gk = (ks << 2) + u;
      s16x8 aF[4], bF[4];
#pragma unroll
      for (int i = 0; i < 4; ++i) {
        const int ra = (wr << 6) + (i << 4) + ql;
        aF[i] = *reinterpret_cast<const s16x8*>(sA + ra * 64 + ((gk ^ (ra & 7)) << 3));
        const int rb = (wc << 6) + (i << 4) + ql;
        bF[i] = *reinterpret_cast<const s16x8*>(sB + rb * 64 + ((gk ^ (rb & 7)) << 3));
      }
#pragma unroll
      for (int i = 0; i < 4; ++i)
#pragma unroll
        for (int j = 0; j < 4; ++j)
          acc[i][j] = __builtin_amdgcn_mfma_f32_16x16x32_bf16(aF[i], bF[j], acc[i][j], 0, 0, 0);
    }
  }

  float b_[4];
#pragma unroll
  for (int j = 0; j < 4; ++j) b_[j] = bias[col0 + (wc << 6) + (j << 4) + ql];

  if (OUTM == 2 && col0 >= 512) {  // V -> transposed vt[(g*8+h)][d][node]
    const int g = row0 >> 9;
    const int key0 = (row0 & 511) + (wr << 6);
#pragma unroll
    for (int i = 0; i < 4; ++i)
#pragma unroll
      for (int j = 0; j < 4; ++j) {
        const int c = (wc << 6) + (j << 4) + ql;  // col0==512 exactly
        const int hh = c >> 5, d = c & 31;
        ushort4 pk;
        pk.x = f2bf(acc[i][j][0] + b_[j]);
        pk.y = f2bf(acc[i][j][1] + b_[j]);
        pk.z = f2bf(acc[i][j][2] + b_[j]);
        pk.w = f2bf(acc[i][j][3] + b_[j]);
        *reinterpret_cast<ushort4*>(Vt + ((((size_t)g << 3) + hh) << 14) + d * 512 +
                                    key0 + (i << 4) + (u << 2)) = pk;
      }
    return;
  }

  // bf16 row-major via 2-half LDS repack (sC[128][136] aliases sA/sB)
  const int ncb = (OUTM == 2) ? 512 : Nc;
  u16* sC = s_all;
#pragma unroll
  for (int halfc = 0; halfc < 2; ++halfc) {
    __syncthreads();
    if ((wc >> 1) == halfc) {
      const int wcl = wc & 1;
#pragma unroll
      for (int i = 0; i < 4; ++i)
#pragma unroll
        for (int j = 0; j < 4; ++j)
#pragma unroll
          for (int r = 0; r < 4; ++r) {
            float v = acc[i][j][r] + b_[j];
            if (ACT) v = fmaxf(v, 0.f);
            const int row = (wr << 6) + (i << 4) + (u << 2) + r;
            const int col = (wcl << 6) + (j << 4) + ql;
            sC[row * 136 + col] = f2bf(v);
          }
    }
    __syncthreads();
#pragma unroll
    for (int it = 0; it < 4; ++it) {
      const int idx = (it << 9) + t;
      const int row = idx >> 4, gc = idx & 15;
      *reinterpret_cast<s16x8*>(Cb + (size_t)(row0 + row) * ncb + col0 + (halfc << 7) + (gc << 3)) =
          *reinterpret_cast<const s16x8*>(sC + row * 136 + (gc << 3));
    }
  }
}

// ---------------------------------------------------------------- Attention (r5 + V-prefetch + shards)
__global__ __launch_bounds__(256) void attn_kernel(
    const u16* __restrict__ qk, const u16* __restrict__ vt,
    const u32* __restrict__ rec_id, const uint4* __restrict__ rec_ew,
    const u32* __restrict__ cnt, const float* __restrict__ relpos,
    const float* __restrict__ x, float* __restrict__ x1) {
  extern __shared__ u32 smem_u[];
  float* s_bias = (float*)smem_u;             // [256][36] f32
  u16* s_p = (u16*)smem_u;                    // [32][512] bf16 (alias)
  float* s_ot = (float*)(smem_u + 8192);      // [32][36] f32 (alias)
  u32* s_mask = smem_u + 9344;                // [32][16]
  float* s_statM = (float*)(smem_u + 9856);   // [2][64]
  float* s_statS = (float*)(smem_u + 9984);   // [2][64]

  const int braw = blockIdx.x;
  const int b = ((braw & 7) << 9) + (braw >> 3);  // XCD swizzle (4096 % 8 == 0)
  const int qt = b & 15, h = (b >> 4) & 7, g = b >> 7;
  const int t = threadIdx.x;
  const int n0 = (g << 9) + (qt << 5);
  const int lane = t & 63, w = t >> 6;
  const int ql = lane & 15, u = lane >> 4;

  // ---- prefetch Q (2) + K (8) fragments
  s16x8 qf8[2], kf8[8];
#pragma unroll
  for (int qf = 0; qf < 2; ++qf)
    qf8[qf] = *reinterpret_cast<const s16x8*>(
        qk + (size_t)(n0 + (qf << 4) + ql) * 512 + (h << 5) + (u << 3));
#pragma unroll
  for (int kf = 0; kf < 8; ++kf) {
    const int half = kf >> 2, kf2 = kf & 3;
    kf8[kf] = *reinterpret_cast<const s16x8*>(
        qk + (size_t)((g << 9) + (half << 8) + (w << 6) + (kf2 << 4) + ql) * 512 + 256 +
        (h << 5) + (u << 3));
  }
  // ---- V prefetch (T14): first 8 of 16 PV fragments, hidden under score phases
  const int wqv = w & 1, wdv = w >> 1;
  const u16* vtb = vt + ((((size_t)g << 3) + h) << 14) + (size_t)((wdv << 4) + ql) * 512;
  s16x8 vf[8];
#pragma unroll
  for (int ks = 0; ks < 8; ++ks)
    vf[ks] = *reinterpret_cast<const s16x8*>(vtb + (ks << 5) + (u << 3));

  {  // zero bias + ot-slack + mask (dwords [0, 9856))
    f32x4* z = (f32x4*)smem_u;
    const f32x4 zv = {0.f, 0.f, 0.f, 0.f};
    for (int i = t; i < 2464; i += 256) z[i] = zv;
  }

  // ---- QK^T in registers (all 16 MFMAs up front)
  f32x4 acc[8][2];
#pragma unroll
  for (int kf = 0; kf < 8; ++kf)
#pragma unroll
    for (int qf = 0; qf < 2; ++qf) acc[kf][qf] = (f32x4){0.f, 0.f, 0.f, 0.f};
#pragma unroll
  for (int kf = 0; kf < 8; ++kf)
#pragma unroll
    for (int qf = 0; qf < 2; ++qf)
      acc[kf][qf] = __builtin_amdgcn_mfma_f32_16x16x32_bf16(kf8[kf], qf8[qf], acc[kf][qf], 0, 0, 0);

  const float scale = 0.17677669529663687f;  // 1/sqrt(32)
  const float rpv = relpos[h];
  float mx[2] = {-1e30f, -1e30f};

#pragma unroll
  for (int half = 0; half < 2; ++half) {
    if (half) {
      __syncthreads();  // apply(0) bias reads complete
      f32x4* z = (f32x4*)smem_u;
      const f32x4 zv = {0.f, 0.f, 0.f, 0.f};
      for (int i = t; i < 2304; i += 256) z[i] = zv;
    }
    __syncthreads();  // zero complete

    {  // scatter this half's records: wave w owns shard w
      const int bkt = (g << 5) | (qt << 1) | half;
      const u32 cn = cnt[(bkt << 2) + w];
      const int n = cn > 128u ? 128 : (int)cn;
      const u32* ridb = rec_id + bkt * BCAP + (w << 7);
      const u32* rewb = (const u32*)(rec_ew + (size_t)bkt * BCAP + (w << 7)) + (h >> 1);
      for (int i = lane; i < n; i += 64) {
        const u32 id = ridb[i];
        const u32 wrd = rewb[(size_t)i << 2];
        const u32 bits = (h & 1) ? (wrd & 0xffff0000u) : (wrd << 16);
        const int lsq = id & 31, ld8 = (int)(id >> 5);
        atomicAdd(&s_bias[ld8 * 36 + lsq], __uint_as_float(bits));
        if (g == 0) atomicOr(&s_mask[(lsq << 4) + (half << 3) + (ld8 >> 5)], 1u << (ld8 & 31));
      }
    }
    __syncthreads();  // scatter complete

    {  // apply bias + rel_pos mask, track row max
      u32 m4[2][2] = {{0u, 0u}, {0u, 0u}};
      if (g == 0) {
#pragma unroll
        for (int qf = 0; qf < 2; ++qf)
#pragma unroll
          for (int i = 0; i < 2; ++i)
            m4[qf][i] = s_mask[(((qf << 4) + ql) << 4) + (half << 3) + (w << 1) + i];
      }
#pragma unroll
      for (int kf2 = 0; kf2 < 4; ++kf2) {
        const int kf = (half << 2) + kf2;
#pragma unroll
        for (int qf = 0; qf < 2; ++qf) {
#pragma unroll
          for (int r = 0; r < 4; ++r) {
            const int kidx = (w << 6) + (kf2 << 4) + (u << 2) + r;  // kl & 255
            float v = acc[kf][qf][r] * scale + s_bias[kidx * 36 + (qf << 4) + ql];
            const int bit = ((kf2 & 1) << 4) + (u << 2) + r;
            if ((m4[qf][kf2 >> 1] >> bit) & 1u) v += rpv;
            acc[kf][qf][r] = v;
            mx[qf] = fmaxf(mx[qf], v);
          }
        }
      }
    }
  }

#pragma unroll
  for (int qf = 0; qf < 2; ++qf) {
    mx[qf] = fmaxf(mx[qf], __shfl_xor(mx[qf], 16));
    mx[qf] = fmaxf(mx[qf], __shfl_xor(mx[qf], 32));
  }
  if (lane < 16) {
    s_statM[(ql << 2) + w] = mx[0];
    s_statM[64 + (ql << 2) + w] = mx[1];
  }
  __syncthreads();  // apply(1) bias reads done; statM visible; P region writable

  {  // ---- exp + P (bf16, swizzled) + sums
    float M[2], sum[2] = {0.f, 0.f};
#pragma unroll
    for (int qf = 0; qf < 2; ++qf) {
      const f32x4 m4v = *reinterpret_cast<const f32x4*>(s_statM + (qf << 6) + (ql << 2));
      M[qf] = fmaxf(fmaxf(m4v.x, m4v.y), fmaxf(m4v.z, m4v.w));
    }
#pragma unroll
    for (int kf = 0; kf < 8; ++kf) {
      const int half = kf >> 2, kf2 = kf & 3;
#pragma unroll
      for (int qf = 0; qf < 2; ++qf) {
        const int q = (qf << 4) + ql;
        float e[4];
#pragma unroll
        for (int r = 0; r < 4; ++r) {
          e[r] = __expf(acc[kf][qf][r] - M[qf]);
          sum[qf] += e[r];
        }
        const int kl0 = (half << 8) + (w << 6) + (kf2 << 4) + (u << 2);
        const int gran = kl0 >> 3;
        uint2 pw;
        pw.x = (u32)f2bf(e[0]) | ((u32)f2bf(e[1]) << 16);
        pw.y = (u32)f2bf(e[2]) | ((u32)f2bf(e[3]) << 16);
        *reinterpret_cast<uint2*>(s_p + (q << 9) + ((gran ^ (q & 7)) << 3) + (kl0 & 7)) = pw;
      }
    }
#pragma unroll
    for (int qf = 0; qf < 2; ++qf) {
      sum[qf] += __shfl_xor(sum[qf], 16);
      sum[qf] += __shfl_xor(sum[qf], 32);
    }
    if (lane < 16) {
      s_statS[(ql << 2) + w] = sum[0];
      s_statS[64 + (ql << 2) + w] = sum[1];
    }
  }
  __syncthreads();  // P + sums visible

  {  // ---- PV: wave -> (wd dim-frag, wq q-frag); full 512 keys; first 8 V frags prefetched
    const int q = (wqv << 4) + ql;
    f32x4 o = (f32x4){0.f, 0.f, 0.f, 0.f};
#pragma unroll
    for (int ks = 0; ks < 16; ++ks) {
      const s16x8 va = (ks < 8) ? vf[ks]
                                : *reinterpret_cast<const s16x8*>(vtb + (ks << 5) + (u << 3));
      const int gran = (ks << 2) + u;
      const s16x8 pb = *reinterpret_cast<const s16x8*>(s_p + (q << 9) + ((gran ^ (q & 7)) << 3));
      o = __builtin_amdgcn_mfma_f32_16x16x32_bf16(va, pb, o, 0, 0, 0);
    }
    const f32x4 s4 = *reinterpret_cast<const f32x4*>(s_statS + (wqv << 6) + (ql << 2));
    const float invS = 1.0f / (s4.x + s4.y + s4.z + s4.w);
#pragma unroll
    for (int r = 0; r < 4; ++r)
      s_ot[q * 36 + (wdv << 4) + (u << 2) + r] = o[r] * invS;
  }
  __syncthreads();

  {  // ---- epilogue: + x residual
    const int q = t >> 3, d4 = (t & 7) << 2;
    const f32x4 ov = *reinterpret_cast<const f32x4*>(s_ot + q * 36 + d4);
    const size_t oi = (size_t)(n0 + q) * D_ + (h << 5) + d4;
    const f32x4 xv = *reinterpret_cast<const f32x4*>(x + oi);
    f32x4 o;
#pragma unroll
    for (int j = 0; j < 4; ++j) o[j] = ov[j] + xv[j];
    *reinterpret_cast<f32x4*>(x1 + oi) = o;
  }
}

// ---------------------------------------------------------------- launch
extern "C" void kernel_launch(void* const* d_in, const int* in_sizes, int n_in,
                              void* d_out, int out_size, void* d_ws, size_t ws_size,
                              hipStream_t stream) {
  const float* x    = (const float*)d_in[0];
  const int*   ei   = (const int*)d_in[1];
  const float* ea   = (const float*)d_in[2];
  const float* ln1g = (const float*)d_in[3];
  const float* ln1b = (const float*)d_in[4];
  const float* wq   = (const float*)d_in[5];
  const float* bq   = (const float*)d_in[6];
  const float* wk   = (const float*)d_in[7];
  const float* bk   = (const float*)d_in[8];
  const float* wv   = (const float*)d_in[9];
  const float* bv   = (const float*)d_in[10];
  const float* wep  = (const float*)d_in[11];
  const float* bep  = (const float*)d_in[12];
  const float* weg  = (const float*)d_in[13];
  const float* beg  = (const float*)d_in[14];
  const float* rp   = (const float*)d_in[15];
  const float* w1   = (const float*)d_in[16];
  const float* b1   = (const float*)d_in[17];
  const float* w2   = (const float*)d_in[18];
  const float* b2   = (const float*)d_in[19];
  const float* ln2g = (const float*)d_in[20];
  const float* ln2b = (const float*)d_in[21];
  float* out = (float*)d_out;

  float* ws = (float*)d_ws;
  const size_t M1 = 1048576;
  u16* xn   = (u16*)ws;                       // [16384][256] bf16
  u16* qk   = (u16*)(ws + 2 * M1);            // [16384][512] bf16 (Q|K)
  u16* vt   = (u16*)(ws + 6 * M1);            // [256][32][512] bf16
  u16* f1   = (u16*)ws;                       // [16384][1024] bf16 (alias, post-attn)
  float* x1 = ws + 8 * M1;                    // f32
  u16* h2   = (u16*)(ws + 12 * M1);           // bf16
  u16* wqkvt = (u16*)(ws + 14 * M1);          // [768][256] bf16
  u16* w1t  = (u16*)(ws + 14 * M1 + 262144);  // [1024][256] bf16
  u16* w2t  = (u16*)(ws + 14 * M1 + 524288);  // [256][1024] bf16
  float* bqkv = ws + 14 * M1 + 786432;        // [768] f32
  u32* cnt  = (u32*)(ws + 14 * M1 + 787456);  // [4096] u32
  u32* rec_id = (u32*)(ws + 15 * M1);         // [1024*512] u32 (2MB)
  uint4* rec_ew = (uint4*)(ws + 16 * M1);     // [1024*512] uint4 (8MB)

  // 0. fused weight prep (packs bqkv + zeros cnt), then edge prep
  wt_conv_all<<<dim3(705), dim3(32, 8), 0, stream>>>(wq, wk, wv, w1, w2, wqkvt, w1t, w2t,
                                                     bq, bk, bv, bqkv, cnt);
  edge_prep<<<dim3(E_ / 256), dim3(256), 0, stream>>>(ei, ea, wep, bep, weg, beg,
                                                      cnt, rec_id, rec_ew);
  // 1. LN1 -> bf16
  ln_kernel<<<dim3(N_ / 4), dim3(256), 0, stream>>>(x, ln1g, ln1b, xn);
  // 2. fused QKV GEMM (wide): Q,K -> qk row-major; V -> vt transposed
  mgemm_w<0, 2><<<dim3(128, 3), 512, 0, stream>>>(xn, wqkvt, bqkv, qk, vt, 256, 768);
  // 3. attention (+x residual) -> x1 f32
  const int smem_attn = 10112 * 4;  // 40,448 B -> 4 WG/CU
  (void)hipFuncSetAttribute(reinterpret_cast<const void*>(attn_kernel),
                            hipFuncAttributeMaxDynamicSharedMemorySize, smem_attn);
  attn_kernel<<<dim3(G_ * H_ * 16), 256, smem_attn, stream>>>(qk, vt, rec_id, rec_ew, cnt,
                                                              rp, x, x1);
  // 4. LN2 -> bf16
  ln_kernel<<<dim3(N_ / 4), dim3(256), 0, stream>>>(x1, ln2g, ln2b, h2);
  // 5. FF1 (relu, wide) -> f1 bf16
  mgemm_w<1, 0><<<dim3(128, 4), 512, 0, stream>>>(h2, w1t, b1, f1, nullptr, 256, 1024);
  // 6. FF2 (+bias +x1 residual, narrow) -> out f32
  mgemm_res<<<dim3(128, 2), 256, 0, stream>>>(f1, w2t, b2, x1, out, 1024, 256);
}

// Round 10
// 180.348 us; speedup vs baseline: 1.3872x; 1.0628x over previous
//
#include <hip/hip_runtime.h>
#include <math.h>

#define G_   32
#define NPG_ 512
#define N_   16384
#define E_   262144
#define D_   256
#define H_   8
#define FF_  1024

typedef unsigned int u32;
typedef unsigned short u16;
typedef __attribute__((ext_vector_type(8))) short s16x8;   // 8 x bf16
typedef __attribute__((ext_vector_type(4))) float f32x4;

__device__ inline u16 f2bf(float f) {
  u32 u = __float_as_uint(f);
  u += 0x7fffu + ((u >> 16) & 1u);
  return (u16)(u >> 16);
}
__device__ inline float bf2f(u32 hi16) { return __uint_as_float(hi16 << 16); }
__device__ inline u16 f2h(float f) {
  union { _Float16 h; u16 u; } c; c.h = (_Float16)f; return c.u;
}
__device__ inline float h2f(u32 bits) {
  union { u16 u; _Float16 h; } c; c.u = (u16)bits; return (float)c.h;
}

// ---------------------------------------------------------------- LayerNorm (bf16 out)
__device__ inline void ln_row(const float* __restrict__ in, const float* __restrict__ gw,
                              const float* __restrict__ bw, u16* __restrict__ out,
                              int row, int lane) {
  const float4 v = reinterpret_cast<const float4*>(in + (size_t)row * D_)[lane];
  float s = v.x + v.y + v.z + v.w;
#pragma unroll
  for (int off = 32; off > 0; off >>= 1) s += __shfl_xor(s, off);
  const float m = s * (1.0f / D_);
  const float dx = v.x - m, dy = v.y - m, dz = v.z - m, dw = v.w - m;
  float s2 = dx * dx + dy * dy + dz * dz + dw * dw;
#pragma unroll
  for (int off = 32; off > 0; off >>= 1) s2 += __shfl_xor(s2, off);
  const float inv = rsqrtf(s2 * (1.0f / D_) + 1e-5f);
  const float4 g4 = reinterpret_cast<const float4*>(gw)[lane];
  const float4 b4 = reinterpret_cast<const float4*>(bw)[lane];
  ushort4 o;
  o.x = f2bf(dx * inv * g4.x + b4.x);
  o.y = f2bf(dy * inv * g4.y + b4.y);
  o.z = f2bf(dz * inv * g4.z + b4.z);
  o.w = f2bf(dw * inv * g4.w + b4.w);
  *reinterpret_cast<ushort4*>(out + (size_t)row * D_ + (lane << 2)) = o;
}

__global__ __launch_bounds__(256) void ln_kernel(const float* __restrict__ in,
                                                 const float* __restrict__ gw,
                                                 const float* __restrict__ bw,
                                                 u16* __restrict__ out) {
  ln_row(in, gw, bw, out, (blockIdx.x << 2) + (threadIdx.x >> 6), threadIdx.x & 63);
}

// ---------------------------------------------------------------- fused prep
// blocks [0,704): weight transpose+convert; 704: bqkv pack;
// [705,1729): edge prep (exp'd f16 gate weights, 4-shard buckets, amask);
// [1729,5825): LN1.
__global__ __launch_bounds__(256) void prep_all(
    const float* __restrict__ wq, const float* __restrict__ wk,
    const float* __restrict__ wv, const float* __restrict__ w1,
    const float* __restrict__ w2,
    u16* __restrict__ wqkvt, u16* __restrict__ w1t, u16* __restrict__ w2t,
    const float* __restrict__ bq, const float* __restrict__ bk,
    const float* __restrict__ bv, float* __restrict__ bqkv,
    const int* __restrict__ ei, const float* __restrict__ ea,
    const float* __restrict__ wep, const float* __restrict__ bep,
    const float* __restrict__ weg, const float* __restrict__ beg,
    u32* __restrict__ cnt, u32* __restrict__ rec_id, uint4* __restrict__ rec_ew,
    u32* __restrict__ amask,
    const float* __restrict__ x, const float* __restrict__ ln1g,
    const float* __restrict__ ln1b, u16* __restrict__ xn) {
  const int bid = blockIdx.x;
  const int t = threadIdx.x;
  if (bid >= 1729) {  // LN1
    ln_row(x, ln1g, ln1b, xn, ((bid - 1729) << 2) + (t >> 6), t & 63);
    return;
  }
  if (bid >= 705) {  // edge prep
    const int e = (bid - 705) * 256 + t;
    const int ls = ei[e] & 511;
    const int ld = ei[E_ + e] & 511;
    if (e < 8192)  // graph 0 adjacency (deduped by OR)
      atomicOr(&amask[(ls << 4) + (ld >> 5)], 1u << (ld & 31));
    const int bk = ((e >> 13) << 4) | (ls >> 5);
    const int sh = t & 3;
    const u32 pos = atomicAdd(&cnt[(bk << 2) + sh], 1u);
    if (pos < 256u) {
      const float2 a2 = reinterpret_cast<const float2*>(ea)[e];
      u32 wds[4];
#pragma unroll
      for (int hp = 0; hp < 4; ++hp) {
        float f2[2];
#pragma unroll
        for (int s = 0; s < 2; ++s) {
          const int h = hp * 2 + s;
          const float pre = a2.x * wep[h] + a2.y * wep[H_ + h] + bep[h];
          const float gat = a2.x * weg[h] + a2.y * weg[H_ + h] + beg[h];
          f2[s] = __expf(pre / (1.0f + __expf(-gat)));  // exp(ew): multiplicative factor
        }
        wds[hp] = (u32)f2h(f2[0]) | ((u32)f2h(f2[1]) << 16);
      }
      const int slot = (bk << 10) + (sh << 8) + (int)pos;
      rec_id[slot] = (u32)((ls & 31) | (ld << 5));
      rec_ew[slot] = make_uint4(wds[0], wds[1], wds[2], wds[3]);
    }
    return;
  }
  if (bid == 704) {  // bias pack
    for (int i = t; i < 768; i += 256)
      bqkv[i] = (i < 256) ? bq[i] : (i < 512 ? bk[i - 256] : bv[i - 512]);
    return;
  }
  // weight transpose
  const float* W; u16* Wt; int K, Nc, ro, local;
  if (bid < 64)       { W = wq; Wt = wqkvt; K = 256;  Nc = 256;  ro = 0;   local = bid; }
  else if (bid < 128) { W = wk; Wt = wqkvt; K = 256;  Nc = 256;  ro = 256; local = bid - 64; }
  else if (bid < 192) { W = wv; Wt = wqkvt; K = 256;  Nc = 256;  ro = 512; local = bid - 128; }
  else if (bid < 448) { W = w1; Wt = w1t;   K = 256;  Nc = 1024; ro = 0;   local = bid - 192; }
  else                { W = w2; Wt = w2t;   K = 1024; Nc = 256;  ro = 0;   local = bid - 448; }
  const int tx = t & 31, ty = t >> 5;
  const int tn = Nc >> 5;
  const int n0 = (local % tn) << 5, k0 = (local / tn) << 5;
  __shared__ float tl[32][33];
#pragma unroll
  for (int i = 0; i < 4; ++i)
    tl[ty + (i << 3)][tx] = W[(size_t)(k0 + ty + (i << 3)) * Nc + n0 + tx];
  __syncthreads();
#pragma unroll
  for (int i = 0; i < 4; ++i)
    Wt[(size_t)(ro + n0 + ty + (i << 3)) * K + k0 + tx] = f2bf(tl[tx][ty + (i << 3)]);
}

// ---------------------------------------------------------------- MFMA GEMM narrow (FF2)
__global__ __launch_bounds__(256) void mgemm_res(const u16* __restrict__ A,
                                                 const u16* __restrict__ Bt,
                                                 const float* __restrict__ bias,
                                                 const float* __restrict__ res,
                                                 float* __restrict__ Cf,
                                                 int K, int Nc) {
  __shared__ u16 s_all[16384];
  u16* sA = s_all;
  u16* sB = s_all + 8192;
  const int t = threadIdx.x;
  const int row0 = blockIdx.x << 7;
  const int col0 = blockIdx.y << 7;
  const int lane = t & 63, w = t >> 6;
  const int ql = lane & 15, u = lane >> 4;
  const int wr = w >> 1, wc = w & 1;

  f32x4 acc[4][4];
#pragma unroll
  for (int i = 0; i < 4; ++i)
#pragma unroll
    for (int j = 0; j < 4; ++j) acc[i][j] = (f32x4){0.f, 0.f, 0.f, 0.f};

  const u16* Ab = A + (size_t)row0 * K;
  const u16* Bb = Bt + (size_t)col0 * K;

  for (int k0 = 0; k0 < K; k0 += 64) {
    __syncthreads();
#pragma unroll
    for (int it = 0; it < 4; ++it) {
      const int idx = (it << 8) + t;
      const int row = idx >> 3;
      const int gcs = (idx & 7) ^ (row & 7);
      __builtin_amdgcn_global_load_lds(
          (const __attribute__((address_space(1))) u32*)(Ab + (size_t)row * K + k0 + (gcs << 3)),
          (__attribute__((address_space(3))) u32*)(sA + (idx << 3)), 16, 0, 0);
    }
#pragma unroll
    for (int it = 0; it < 4; ++it) {
      const int idx = (it << 8) + t;
      const int row = idx >> 3;
      const int gcs = (idx & 7) ^ (row & 7);
      __builtin_amdgcn_global_load_lds(
          (const __attribute__((address_space(1))) u32*)(Bb + (size_t)row * K + k0 + (gcs << 3)),
          (__attribute__((address_space(3))) u32*)(sB + (idx << 3)), 16, 0, 0);
    }
    __syncthreads();
#pragma unroll
    for (int ks = 0; ks < 2; ++ks) {
      const int gk = (ks << 2) + u;
      s16x8 aF[4], bF[4];
#pragma unroll
      for (int i = 0; i < 4; ++i) {
        const int ra = (wr << 6) + (i << 4) + ql;
        aF[i] = *reinterpret_cast<const s16x8*>(sA + ra * 64 + ((gk ^ (ra & 7)) << 3));
        const int rb = (wc << 6) + (i << 4) + ql;
        bF[i] = *reinterpret_cast<const s16x8*>(sB + rb * 64 + ((gk ^ (rb & 7)) << 3));
      }
#pragma unroll
      for (int i = 0; i < 4; ++i)
#pragma unroll
        for (int j = 0; j < 4; ++j)
          acc[i][j] = __builtin_amdgcn_mfma_f32_16x16x32_bf16(aF[i], bF[j], acc[i][j], 0, 0, 0);
    }
  }

  float b_[4];
#pragma unroll
  for (int j = 0; j < 4; ++j) b_[j] = bias[col0 + (wc << 6) + (j << 4) + ql];
#pragma unroll
  for (int i = 0; i < 4; ++i)
#pragma unroll
    for (int j = 0; j < 4; ++j)
#pragma unroll
      for (int r = 0; r < 4; ++r) {
        const int row = row0 + (wr << 6) + (i << 4) + (u << 2) + r;
        const int col = col0 + (wc << 6) + (j << 4) + ql;
        Cf[(size_t)row * Nc + col] = acc[i][j][r] + b_[j] + res[(size_t)row * Nc + col];
      }
}

// ---------------------------------------------------------------- MFMA GEMM wide (QKV, FF1)
template <int ACT, int OUTM>
__global__ __launch_bounds__(512) void mgemm_w(const u16* __restrict__ A,
                                               const u16* __restrict__ Bt,
                                               const float* __restrict__ bias,
                                               u16* __restrict__ Cb,
                                               u16* __restrict__ Vt,
                                               int K, int Nc) {
  __shared__ u16 s_all[24576];  // sA[128][64] | sB[256][64]; sC[128][136] alias
  u16* sA = s_all;
  u16* sB = s_all + 8192;
  const int t = threadIdx.x;
  const int row0 = blockIdx.x << 7;
  const int col0 = blockIdx.y << 8;
  const int lane = t & 63, w = t >> 6;
  const int ql = lane & 15, u = lane >> 4;
  const int wr = w >> 2, wc = w & 3;

  f32x4 acc[4][4];
#pragma unroll
  for (int i = 0; i < 4; ++i)
#pragma unroll
    for (int j = 0; j < 4; ++j) acc[i][j] = (f32x4){0.f, 0.f, 0.f, 0.f};

  const u16* Ab = A + (size_t)row0 * K;
  const u16* Bb = Bt + (size_t)col0 * K;

  for (int k0 = 0; k0 < K; k0 += 64) {
    __syncthreads();
#pragma unroll
    for (int it = 0; it < 2; ++it) {
      const int idx = (it << 9) + t;
      const int row = idx >> 3;
      const int gcs = (idx & 7) ^ (row & 7);
      __builtin_amdgcn_global_load_lds(
          (const __attribute__((address_space(1))) u32*)(Ab + (size_t)row * K + k0 + (gcs << 3)),
          (__attribute__((address_space(3))) u32*)(sA + (idx << 3)), 16, 0, 0);
    }
#pragma unroll
    for (int it = 0; it < 4; ++it) {
      const int idx = (it << 9) + t;
      const int row = idx >> 3;
      const int gcs = (idx & 7) ^ (row & 7);
      __builtin_amdgcn_global_load_lds(
          (const __attribute__((address_space(1))) u32*)(Bb + (size_t)row * K + k0 + (gcs << 3)),
          (__attribute__((address_space(3))) u32*)(sB + (idx << 3)), 16, 0, 0);
    }
    __syncthreads();
#pragma unroll
    for (int ks = 0; ks < 2; ++ks) {
      const int gk = (ks << 2) + u;
      s16x8 aF[4], bF[4];
#pragma unroll
      for (int i = 0; i < 4; ++i) {
        const int ra = (wr << 6) + (i << 4) + ql;
        aF[i] = *reinterpret_cast<const s16x8*>(sA + ra * 64 + ((gk ^ (ra & 7)) << 3));
        const int rb = (wc << 6) + (i << 4) + ql;
        bF[i] = *reinterpret_cast<const s16x8*>(sB + rb * 64 + ((gk ^ (rb & 7)) << 3));
      }
#pragma unroll
      for (int i = 0; i < 4; ++i)
#pragma unroll
        for (int j = 0; j < 4; ++j)
          acc[i][j] = __builtin_amdgcn_mfma_f32_16x16x32_bf16(aF[i], bF[j], acc[i][j], 0, 0, 0);
    }
  }

  float b_[4];
#pragma unroll
  for (int j = 0; j < 4; ++j) b_[j] = bias[col0 + (wc << 6) + (j << 4) + ql];

  if (OUTM == 2 && col0 >= 512) {  // V -> transposed vt[(g*8+h)][d][node]
    const int g = row0 >> 9;
    const int key0 = (row0 & 511) + (wr << 6);
#pragma unroll
    for (int i = 0; i < 4; ++i)
#pragma unroll
      for (int j = 0; j < 4; ++j) {
        const int c = (wc << 6) + (j << 4) + ql;
        const int hh = c >> 5, d = c & 31;
        ushort4 pk;
        pk.x = f2bf(acc[i][j][0] + b_[j]);
        pk.y = f2bf(acc[i][j][1] + b_[j]);
        pk.z = f2bf(acc[i][j][2] + b_[j]);
        pk.w = f2bf(acc[i][j][3] + b_[j]);
        *reinterpret_cast<ushort4*>(Vt + ((((size_t)g << 3) + hh) << 14) + d * 512 +
                                    key0 + (i << 4) + (u << 2)) = pk;
      }
    return;
  }

  const int ncb = (OUTM == 2) ? 512 : Nc;
  u16* sC = s_all;
#pragma unroll
  for (int halfc = 0; halfc < 2; ++halfc) {
    __syncthreads();
    if ((wc >> 1) == halfc) {
      const int wcl = wc & 1;
#pragma unroll
      for (int i = 0; i < 4; ++i)
#pragma unroll
        for (int j = 0; j < 4; ++j)
#pragma unroll
          for (int r = 0; r < 4; ++r) {
            float v = acc[i][j][r] + b_[j];
            if (ACT) v = fmaxf(v, 0.f);
            const int row = (wr << 6) + (i << 4) + (u << 2) + r;
            const int col = (wcl << 6) + (j << 4) + ql;
            sC[row * 136 + col] = f2bf(v);
          }
    }
    __syncthreads();
#pragma unroll
    for (int it = 0; it < 4; ++it) {
      const int idx = (it << 9) + t;
      const int row = idx >> 4, gc = idx & 15;
      *reinterpret_cast<s16x8*>(Cb + (size_t)(row0 + row) * ncb + col0 + (halfc << 7) + (gc << 3)) =
          *reinterpret_cast<const s16x8*>(sC + row * 136 + (gc << 3));
    }
  }
}

// ---------------------------------------------------------------- Attention v8 (multiplicative bias)
// P = exp(QK/sqrt(d)) (no max needed: |s| < ~4 by construction); edge bias applied as
// P[q][k] *= exp(ew) via LDS CAS (composes exactly for duplicate edges); rel_pos as
// P *= exp(rp) over deduped adjacency bits; row sums tracked incrementally in srow[32].
// LDS: P[32][512]bf16 (32KB) | srow[32] | ot[32][36] = 37,504 B -> 4 WG/CU. 4 barriers.
__global__ __launch_bounds__(256) void attn_kernel(
    const u16* __restrict__ qk, const u16* __restrict__ vt,
    const u32* __restrict__ rec_id, const uint4* __restrict__ rec_ew,
    const u32* __restrict__ cnt, const u32* __restrict__ amask,
    const float* __restrict__ relpos,
    const float* __restrict__ x, float* __restrict__ x1) {
  extern __shared__ u32 smem_u[];
  u16* s_p = (u16*)smem_u;                    // [32][512] bf16 (swizzled)
  float* srow = (float*)(smem_u + 8192);      // [32]
  float* s_ot = (float*)(smem_u + 8224);      // [32][36]

  const int braw = blockIdx.x;
  const int b = ((braw & 7) << 9) + (braw >> 3);  // XCD swizzle (4096 % 8 == 0)
  const int qt = b & 15, h = (b >> 4) & 7, g = b >> 7;
  const int t = threadIdx.x;
  const int n0 = (g << 9) + (qt << 5);
  const int lane = t & 63, w = t >> 6;
  const int ql = lane & 15, u = lane >> 4;

  if (t < 32) srow[t] = 0.0f;

  // ---- prefetch Q (2) + K (8) fragments
  s16x8 qf8[2], kf8[8];
#pragma unroll
  for (int qf = 0; qf < 2; ++qf)
    qf8[qf] = *reinterpret_cast<const s16x8*>(
        qk + (size_t)(n0 + (qf << 4) + ql) * 512 + (h << 5) + (u << 3));
#pragma unroll
  for (int kf = 0; kf < 8; ++kf)
    kf8[kf] = *reinterpret_cast<const s16x8*>(
        qk + (size_t)((g << 9) + (w << 7) + (kf << 4) + ql) * 512 + 256 + (h << 5) + (u << 3));

  // ---- QK^T (swapped): S^T[key][q]; 16 MFMAs register-only
  f32x4 acc[8][2];
#pragma unroll
  for (int kf = 0; kf < 8; ++kf)
#pragma unroll
    for (int qf = 0; qf < 2; ++qf) acc[kf][qf] = (f32x4){0.f, 0.f, 0.f, 0.f};
#pragma unroll
  for (int kf = 0; kf < 8; ++kf)
#pragma unroll
    for (int qf = 0; qf < 2; ++qf)
      acc[kf][qf] = __builtin_amdgcn_mfma_f32_16x16x32_bf16(kf8[kf], qf8[qf], acc[kf][qf], 0, 0, 0);
  __syncthreads();  // #1: srow zero visible

  {  // ---- exp (no max) + P write (bf16, swizzled) + base row sums
    const float scale = 0.17677669529663687f;  // 1/sqrt(32)
    float sum[2] = {0.f, 0.f};
#pragma unroll
    for (int kf = 0; kf < 8; ++kf) {
#pragma unroll
      for (int qf = 0; qf < 2; ++qf) {
        const int q = (qf << 4) + ql;
        float e[4];
#pragma unroll
        for (int r = 0; r < 4; ++r) {
          e[r] = __expf(acc[kf][qf][r] * scale);
          sum[qf] += e[r];
        }
        const int kl0 = (w << 7) + (kf << 4) + (u << 2);
        const int gran = kl0 >> 3;
        uint2 pw;
        pw.x = (u32)f2bf(e[0]) | ((u32)f2bf(e[1]) << 16);
        pw.y = (u32)f2bf(e[2]) | ((u32)f2bf(e[3]) << 16);
        *reinterpret_cast<uint2*>(s_p + (q << 9) + ((gran ^ (q & 7)) << 3) + (kl0 & 7)) = pw;
      }
    }
#pragma unroll
    for (int qf = 0; qf < 2; ++qf) {
      sum[qf] += __shfl_xor(sum[qf], 16);
      sum[qf] += __shfl_xor(sum[qf], 32);
      if (lane < 16) atomicAdd(&srow[(qf << 4) + ql], sum[qf]);
    }
  }
  __syncthreads();  // #2: P fully written

  {  // ---- sparse edge pass: P[q][k] *= f, srow[q] += P_old*(f-1). Wave w = shard w.
    const int bkt = (g << 4) | qt;
    const u32 cn = cnt[(bkt << 2) + w];
    const int n = cn > 256u ? 256 : (int)cn;
    const u32* ridb = rec_id + (bkt << 10) + (w << 8);
    const u32* rewb = (const u32*)(rec_ew + ((size_t)bkt << 10) + (w << 8)) + (h >> 1);
    for (int i = lane; i < n; i += 64) {
      const u32 id = ridb[i];
      const u32 wrd = rewb[(size_t)i << 2];
      const float f = h2f((h & 1) ? (wrd >> 16) : (wrd & 0xffffu));
      const int q = id & 31, k = (int)(id >> 5);
      const int idx16 = (q << 9) + ((((k >> 3)) ^ (q & 7)) << 3) + (k & 7);
      u32* addr = smem_u + (idx16 >> 1);
      const int sh = (idx16 & 1) << 4;
      u32 old = *addr;
      float pv;
      while (true) {
        pv = bf2f((old >> sh) & 0xffffu);
        const u32 nw = (old & ~(0xffffu << sh)) | ((u32)f2bf(pv * f) << sh);
        const u32 got = atomicCAS(addr, old, nw);
        if (got == old) break;
        old = got;
      }
      atomicAdd(&srow[q], pv * (f - 1.0f));
    }
    if (g == 0) {  // rel_pos: P *= exp(rp) over deduped adjacency bits
      const float frp = __expf(relpos[h]);
      const float fm1 = frp - 1.0f;
#pragma unroll
      for (int wi = 0; wi < 2; ++wi) {
        const int widx = t + (wi << 8);
        const int q = widx >> 4, w16 = widx & 15;
        u32 m = amask[(((qt << 5) + q) << 4) + w16];
        while (m) {
          const int bit = __ffs(m) - 1;
          m &= m - 1;
          const int k = (w16 << 5) + bit;
          const int idx16 = (q << 9) + ((((k >> 3)) ^ (q & 7)) << 3) + (k & 7);
          u32* addr = smem_u + (idx16 >> 1);
          const int sh = (idx16 & 1) << 4;
          u32 old = *addr;
          float pv;
          while (true) {
            pv = bf2f((old >> sh) & 0xffffu);
            const u32 nw = (old & ~(0xffffu << sh)) | ((u32)f2bf(pv * frp) << sh);
            const u32 got = atomicCAS(addr, old, nw);
            if (got == old) break;
            old = got;
          }
          atomicAdd(&srow[q], pv * fm1);
        }
      }
    }
  }
  __syncthreads();  // #3: corrected P + sums visible

  {  // ---- PV: wave -> (wd dim-frag, wq q-frag); full 512 keys
    const int wq = w & 1, wd = w >> 1;
    const u16* vtb = vt + ((((size_t)g << 3) + h) << 14) + (size_t)((wd << 4) + ql) * 512;
    const int q = (wq << 4) + ql;
    f32x4 o = (f32x4){0.f, 0.f, 0.f, 0.f};
#pragma unroll
    for (int ks = 0; ks < 16; ++ks) {
      const s16x8 va = *reinterpret_cast<const s16x8*>(vtb + (ks << 5) + (u << 3));
      const int gran = (ks << 2) + u;
      const s16x8 pb = *reinterpret_cast<const s16x8*>(s_p + (q << 9) + ((gran ^ (q & 7)) << 3));
      o = __builtin_amdgcn_mfma_f32_16x16x32_bf16(va, pb, o, 0, 0, 0);
    }
    const float invS = 1.0f / srow[q];
#pragma unroll
    for (int r = 0; r < 4; ++r)
      s_ot[q * 36 + (wd << 4) + (u << 2) + r] = o[r] * invS;
  }
  __syncthreads();  // #4

  {  // ---- epilogue: + x residual
    const int q = t >> 3, d4 = (t & 7) << 2;
    const f32x4 ov = *reinterpret_cast<const f32x4*>(s_ot + q * 36 + d4);
    const size_t oi = (size_t)(n0 + q) * D_ + (h << 5) + d4;
    const f32x4 xv = *reinterpret_cast<const f32x4*>(x + oi);
    f32x4 o;
#pragma unroll
    for (int j = 0; j < 4; ++j) o[j] = ov[j] + xv[j];
    *reinterpret_cast<f32x4*>(x1 + oi) = o;
  }
}

// ---------------------------------------------------------------- launch
extern "C" void kernel_launch(void* const* d_in, const int* in_sizes, int n_in,
                              void* d_out, int out_size, void* d_ws, size_t ws_size,
                              hipStream_t stream) {
  const float* x    = (const float*)d_in[0];
  const int*   ei   = (const int*)d_in[1];
  const float* ea   = (const float*)d_in[2];
  const float* ln1g = (const float*)d_in[3];
  const float* ln1b = (const float*)d_in[4];
  const float* wq   = (const float*)d_in[5];
  const float* bq   = (const float*)d_in[6];
  const float* wk   = (const float*)d_in[7];
  const float* bk   = (const float*)d_in[8];
  const float* wv   = (const float*)d_in[9];
  const float* bv   = (const float*)d_in[10];
  const float* wep  = (const float*)d_in[11];
  const float* bep  = (const float*)d_in[12];
  const float* weg  = (const float*)d_in[13];
  const float* beg  = (const float*)d_in[14];
  const float* rp   = (const float*)d_in[15];
  const float* w1   = (const float*)d_in[16];
  const float* b1   = (const float*)d_in[17];
  const float* w2   = (const float*)d_in[18];
  const float* b2   = (const float*)d_in[19];
  const float* ln2g = (const float*)d_in[20];
  const float* ln2b = (const float*)d_in[21];
  float* out = (float*)d_out;

  float* ws = (float*)d_ws;
  const size_t M1 = 1048576;
  u16* xn   = (u16*)ws;                       // [16384][256] bf16
  u16* qk   = (u16*)(ws + 2 * M1);            // [16384][512] bf16 (Q|K)
  u16* vt   = (u16*)(ws + 6 * M1);            // [256][32][512] bf16
  u16* f1   = (u16*)ws;                       // [16384][1024] bf16 (alias, post-attn)
  float* x1 = ws + 8 * M1;                    // f32
  u16* h2   = (u16*)(ws + 12 * M1);           // bf16
  u16* wqkvt = (u16*)(ws + 14 * M1);          // [768][256] bf16
  u16* w1t  = (u16*)(ws + 14 * M1 + 262144);  // [1024][256] bf16
  u16* w2t  = (u16*)(ws + 14 * M1 + 524288);  // [256][1024] bf16
  float* bqkv = ws + 14 * M1 + 786432;        // [768] f32
  u32* cnt  = (u32*)(ws + 14 * M1 + 787456);  // [2048] u32
  u32* amask = cnt + 2048;                    // [512][16] u32 (32KB)
  u32* rec_id = (u32*)(ws + 15 * M1);         // [512*1024] u32 (2MB)
  uint4* rec_ew = (uint4*)(ws + 16 * M1);     // [512*1024] uint4 (8MB)

  // 0. zero cnt+amask, then fused prep (weights | bqkv | edge prep | LN1)
  hipMemsetAsync(cnt, 0, (2048 + 8192) * sizeof(u32), stream);
  prep_all<<<dim3(5825), dim3(256), 0, stream>>>(
      wq, wk, wv, w1, w2, wqkvt, w1t, w2t, bq, bk, bv, bqkv,
      ei, ea, wep, bep, weg, beg, cnt, rec_id, rec_ew, amask, x, ln1g, ln1b, xn);
  // 1. fused QKV GEMM (wide): Q,K -> qk row-major; V -> vt transposed
  mgemm_w<0, 2><<<dim3(128, 3), 512, 0, stream>>>(xn, wqkvt, bqkv, qk, vt, 256, 768);
  // 2. attention (+x residual) -> x1 f32
  const int smem_attn = 9376 * 4;  // 37,504 B -> 4 WG/CU
  (void)hipFuncSetAttribute(reinterpret_cast<const void*>(attn_kernel),
                            hipFuncAttributeMaxDynamicSharedMemorySize, smem_attn);
  attn_kernel<<<dim3(G_ * H_ * 16), 256, smem_attn, stream>>>(qk, vt, rec_id, rec_ew, cnt,
                                                              amask, rp, x, x1);
  // 3. LN2 -> bf16
  ln_kernel<<<dim3(N_ / 4), dim3(256), 0, stream>>>(x1, ln2g, ln2b, h2);
  // 4. FF1 (relu, wide) -> f1 bf16
  mgemm_w<1, 0><<<dim3(128, 4), 512, 0, stream>>>(h2, w1t, b1, f1, nullptr, 256, 1024);
  // 5. FF2 (+bias +x1 residual, narrow) -> out f32
  mgemm_res<<<dim3(128, 2), 256, 0, stream>>>(f1, w2t, b2, x1, out, 1024, 256);
}

// Round 11
// 175.292 us; speedup vs baseline: 1.4272x; 1.0288x over previous
//
#include <hip/hip_runtime.h>
#include <math.h>

#define G_   32
#define NPG_ 512
#define N_   16384
#define E_   262144
#define D_   256
#define H_   8
#define FF_  1024

typedef unsigned int u32;
typedef unsigned short u16;
typedef __attribute__((ext_vector_type(8))) short s16x8;   // 8 x bf16
typedef __attribute__((ext_vector_type(4))) float f32x4;

__device__ inline u16 f2bf(float f) {
  u32 u = __float_as_uint(f);
  u += 0x7fffu + ((u >> 16) & 1u);
  return (u16)(u >> 16);
}
__device__ inline float bf2f(u32 hi16) { return __uint_as_float(hi16 << 16); }
__device__ inline u16 f2h(float f) {
  union { _Float16 h; u16 u; } c; c.h = (_Float16)f; return c.u;
}
__device__ inline float h2f(u32 bits) {
  union { u16 u; _Float16 h; } c; c.u = (u16)bits; return (float)c.h;
}

// ---------------------------------------------------------------- LayerNorm (bf16 out)
__device__ inline void ln_row(const float* __restrict__ in, const float* __restrict__ gw,
                              const float* __restrict__ bw, u16* __restrict__ out,
                              int row, int lane) {
  const float4 v = reinterpret_cast<const float4*>(in + (size_t)row * D_)[lane];
  float s = v.x + v.y + v.z + v.w;
#pragma unroll
  for (int off = 32; off > 0; off >>= 1) s += __shfl_xor(s, off);
  const float m = s * (1.0f / D_);
  const float dx = v.x - m, dy = v.y - m, dz = v.z - m, dw = v.w - m;
  float s2 = dx * dx + dy * dy + dz * dz + dw * dw;
#pragma unroll
  for (int off = 32; off > 0; off >>= 1) s2 += __shfl_xor(s2, off);
  const float inv = rsqrtf(s2 * (1.0f / D_) + 1e-5f);
  const float4 g4 = reinterpret_cast<const float4*>(gw)[lane];
  const float4 b4 = reinterpret_cast<const float4*>(bw)[lane];
  ushort4 o;
  o.x = f2bf(dx * inv * g4.x + b4.x);
  o.y = f2bf(dy * inv * g4.y + b4.y);
  o.z = f2bf(dz * inv * g4.z + b4.z);
  o.w = f2bf(dw * inv * g4.w + b4.w);
  *reinterpret_cast<ushort4*>(out + (size_t)row * D_ + (lane << 2)) = o;
}

__global__ __launch_bounds__(256) void ln_kernel(const float* __restrict__ in,
                                                 const float* __restrict__ gw,
                                                 const float* __restrict__ bw,
                                                 u16* __restrict__ out) {
  ln_row(in, gw, bw, out, (blockIdx.x << 2) + (threadIdx.x >> 6), threadIdx.x & 63);
}

// ---------------------------------------------------------------- fused prep
__global__ __launch_bounds__(256) void prep_all(
    const float* __restrict__ wq, const float* __restrict__ wk,
    const float* __restrict__ wv, const float* __restrict__ w1,
    const float* __restrict__ w2,
    u16* __restrict__ wqkvt, u16* __restrict__ w1t, u16* __restrict__ w2t,
    const float* __restrict__ bq, const float* __restrict__ bk,
    const float* __restrict__ bv, float* __restrict__ bqkv,
    const int* __restrict__ ei, const float* __restrict__ ea,
    const float* __restrict__ wep, const float* __restrict__ bep,
    const float* __restrict__ weg, const float* __restrict__ beg,
    u32* __restrict__ cnt, u32* __restrict__ rec_id, uint4* __restrict__ rec_ew,
    u32* __restrict__ amask,
    const float* __restrict__ x, const float* __restrict__ ln1g,
    const float* __restrict__ ln1b, u16* __restrict__ xn) {
  const int bid = blockIdx.x;
  const int t = threadIdx.x;
  if (bid >= 1729) {  // LN1
    ln_row(x, ln1g, ln1b, xn, ((bid - 1729) << 2) + (t >> 6), t & 63);
    return;
  }
  if (bid >= 705) {  // edge prep
    const int e = (bid - 705) * 256 + t;
    const int ls = ei[e] & 511;
    const int ld = ei[E_ + e] & 511;
    if (e < 8192)  // graph 0 adjacency (deduped by OR)
      atomicOr(&amask[(ls << 4) + (ld >> 5)], 1u << (ld & 31));
    const int bk = ((e >> 13) << 4) | (ls >> 5);
    const int sh = t & 3;
    const u32 pos = atomicAdd(&cnt[(bk << 2) + sh], 1u);
    if (pos < 256u) {
      const float2 a2 = reinterpret_cast<const float2*>(ea)[e];
      u32 wds[4];
#pragma unroll
      for (int hp = 0; hp < 4; ++hp) {
        float f2[2];
#pragma unroll
        for (int s = 0; s < 2; ++s) {
          const int h = hp * 2 + s;
          const float pre = a2.x * wep[h] + a2.y * wep[H_ + h] + bep[h];
          const float gat = a2.x * weg[h] + a2.y * weg[H_ + h] + beg[h];
          f2[s] = __expf(pre / (1.0f + __expf(-gat)));  // exp(ew): multiplicative factor
        }
        wds[hp] = (u32)f2h(f2[0]) | ((u32)f2h(f2[1]) << 16);
      }
      const int slot = (bk << 10) + (sh << 8) + (int)pos;
      rec_id[slot] = (u32)((ls & 31) | (ld << 5));
      rec_ew[slot] = make_uint4(wds[0], wds[1], wds[2], wds[3]);
    }
    return;
  }
  if (bid == 704) {  // bias pack
    for (int i = t; i < 768; i += 256)
      bqkv[i] = (i < 256) ? bq[i] : (i < 512 ? bk[i - 256] : bv[i - 512]);
    return;
  }
  // weight transpose
  const float* W; u16* Wt; int K, Nc, ro, local;
  if (bid < 64)       { W = wq; Wt = wqkvt; K = 256;  Nc = 256;  ro = 0;   local = bid; }
  else if (bid < 128) { W = wk; Wt = wqkvt; K = 256;  Nc = 256;  ro = 256; local = bid - 64; }
  else if (bid < 192) { W = wv; Wt = wqkvt; K = 256;  Nc = 256;  ro = 512; local = bid - 128; }
  else if (bid < 448) { W = w1; Wt = w1t;   K = 256;  Nc = 1024; ro = 0;   local = bid - 192; }
  else                { W = w2; Wt = w2t;   K = 1024; Nc = 256;  ro = 0;   local = bid - 448; }
  const int tx = t & 31, ty = t >> 5;
  const int tn = Nc >> 5;
  const int n0 = (local % tn) << 5, k0 = (local / tn) << 5;
  __shared__ float tl[32][33];
#pragma unroll
  for (int i = 0; i < 4; ++i)
    tl[ty + (i << 3)][tx] = W[(size_t)(k0 + ty + (i << 3)) * Nc + n0 + tx];
  __syncthreads();
#pragma unroll
  for (int i = 0; i < 4; ++i)
    Wt[(size_t)(ro + n0 + ty + (i << 3)) * K + k0 + tx] = f2bf(tl[tx][ty + (i << 3)]);
}

// ---------------------------------------------------------------- MFMA GEMM narrow (FF2)
__global__ __launch_bounds__(256) void mgemm_res(const u16* __restrict__ A,
                                                 const u16* __restrict__ Bt,
                                                 const float* __restrict__ bias,
                                                 const float* __restrict__ res,
                                                 float* __restrict__ Cf,
                                                 int K, int Nc) {
  __shared__ u16 s_all[16384];
  u16* sA = s_all;
  u16* sB = s_all + 8192;
  const int t = threadIdx.x;
  const int row0 = blockIdx.x << 7;
  const int col0 = blockIdx.y << 7;
  const int lane = t & 63, w = t >> 6;
  const int ql = lane & 15, u = lane >> 4;
  const int wr = w >> 1, wc = w & 1;

  f32x4 acc[4][4];
#pragma unroll
  for (int i = 0; i < 4; ++i)
#pragma unroll
    for (int j = 0; j < 4; ++j) acc[i][j] = (f32x4){0.f, 0.f, 0.f, 0.f};

  const u16* Ab = A + (size_t)row0 * K;
  const u16* Bb = Bt + (size_t)col0 * K;

  for (int k0 = 0; k0 < K; k0 += 64) {
    __syncthreads();
#pragma unroll
    for (int it = 0; it < 4; ++it) {
      const int idx = (it << 8) + t;
      const int row = idx >> 3;
      const int gcs = (idx & 7) ^ (row & 7);
      __builtin_amdgcn_global_load_lds(
          (const __attribute__((address_space(1))) u32*)(Ab + (size_t)row * K + k0 + (gcs << 3)),
          (__attribute__((address_space(3))) u32*)(sA + (idx << 3)), 16, 0, 0);
    }
#pragma unroll
    for (int it = 0; it < 4; ++it) {
      const int idx = (it << 8) + t;
      const int row = idx >> 3;
      const int gcs = (idx & 7) ^ (row & 7);
      __builtin_amdgcn_global_load_lds(
          (const __attribute__((address_space(1))) u32*)(Bb + (size_t)row * K + k0 + (gcs << 3)),
          (__attribute__((address_space(3))) u32*)(sB + (idx << 3)), 16, 0, 0);
    }
    __syncthreads();
#pragma unroll
    for (int ks = 0; ks < 2; ++ks) {
      const int gk = (ks << 2) + u;
      s16x8 aF[4], bF[4];
#pragma unroll
      for (int i = 0; i < 4; ++i) {
        const int ra = (wr << 6) + (i << 4) + ql;
        aF[i] = *reinterpret_cast<const s16x8*>(sA + ra * 64 + ((gk ^ (ra & 7)) << 3));
        const int rb = (wc << 6) + (i << 4) + ql;
        bF[i] = *reinterpret_cast<const s16x8*>(sB + rb * 64 + ((gk ^ (rb & 7)) << 3));
      }
#pragma unroll
      for (int i = 0; i < 4; ++i)
#pragma unroll
        for (int j = 0; j < 4; ++j)
          acc[i][j] = __builtin_amdgcn_mfma_f32_16x16x32_bf16(aF[i], bF[j], acc[i][j], 0, 0, 0);
    }
  }

  float b_[4];
#pragma unroll
  for (int j = 0; j < 4; ++j) b_[j] = bias[col0 + (wc << 6) + (j << 4) + ql];
#pragma unroll
  for (int i = 0; i < 4; ++i)
#pragma unroll
    for (int j = 0; j < 4; ++j)
#pragma unroll
      for (int r = 0; r < 4; ++r) {
        const int row = row0 + (wr << 6) + (i << 4) + (u << 2) + r;
        const int col = col0 + (wc << 6) + (j << 4) + ql;
        Cf[(size_t)row * Nc + col] = acc[i][j][r] + b_[j] + res[(size_t)row * Nc + col];
      }
}

// ---------------------------------------------------------------- MFMA GEMM wide (QKV, FF1)
template <int ACT, int OUTM>
__global__ __launch_bounds__(512) void mgemm_w(const u16* __restrict__ A,
                                               const u16* __restrict__ Bt,
                                               const float* __restrict__ bias,
                                               u16* __restrict__ Cb,
                                               u16* __restrict__ Vt,
                                               int K, int Nc) {
  __shared__ u16 s_all[24576];  // sA[128][64] | sB[256][64]; sC[128][136] alias
  u16* sA = s_all;
  u16* sB = s_all + 8192;
  const int t = threadIdx.x;
  const int row0 = blockIdx.x << 7;
  const int col0 = blockIdx.y << 8;
  const int lane = t & 63, w = t >> 6;
  const int ql = lane & 15, u = lane >> 4;
  const int wr = w >> 2, wc = w & 3;

  f32x4 acc[4][4];
#pragma unroll
  for (int i = 0; i < 4; ++i)
#pragma unroll
    for (int j = 0; j < 4; ++j) acc[i][j] = (f32x4){0.f, 0.f, 0.f, 0.f};

  const u16* Ab = A + (size_t)row0 * K;
  const u16* Bb = Bt + (size_t)col0 * K;

  for (int k0 = 0; k0 < K; k0 += 64) {
    __syncthreads();
#pragma unroll
    for (int it = 0; it < 2; ++it) {
      const int idx = (it << 9) + t;
      const int row = idx >> 3;
      const int gcs = (idx & 7) ^ (row & 7);
      __builtin_amdgcn_global_load_lds(
          (const __attribute__((address_space(1))) u32*)(Ab + (size_t)row * K + k0 + (gcs << 3)),
          (__attribute__((address_space(3))) u32*)(sA + (idx << 3)), 16, 0, 0);
    }
#pragma unroll
    for (int it = 0; it < 4; ++it) {
      const int idx = (it << 9) + t;
      const int row = idx >> 3;
      const int gcs = (idx & 7) ^ (row & 7);
      __builtin_amdgcn_global_load_lds(
          (const __attribute__((address_space(1))) u32*)(Bb + (size_t)row * K + k0 + (gcs << 3)),
          (__attribute__((address_space(3))) u32*)(sB + (idx << 3)), 16, 0, 0);
    }
    __syncthreads();
#pragma unroll
    for (int ks = 0; ks < 2; ++ks) {
      const int gk = (ks << 2) + u;
      s16x8 aF[4], bF[4];
#pragma unroll
      for (int i = 0; i < 4; ++i) {
        const int ra = (wr << 6) + (i << 4) + ql;
        aF[i] = *reinterpret_cast<const s16x8*>(sA + ra * 64 + ((gk ^ (ra & 7)) << 3));
        const int rb = (wc << 6) + (i << 4) + ql;
        bF[i] = *reinterpret_cast<const s16x8*>(sB + rb * 64 + ((gk ^ (rb & 7)) << 3));
      }
#pragma unroll
      for (int i = 0; i < 4; ++i)
#pragma unroll
        for (int j = 0; j < 4; ++j)
          acc[i][j] = __builtin_amdgcn_mfma_f32_16x16x32_bf16(aF[i], bF[j], acc[i][j], 0, 0, 0);
    }
  }

  float b_[4];
#pragma unroll
  for (int j = 0; j < 4; ++j) b_[j] = bias[col0 + (wc << 6) + (j << 4) + ql];

  if (OUTM == 2 && col0 >= 512) {  // V -> transposed vt[(g*8+h)][d][node]
    const int g = row0 >> 9;
    const int key0 = (row0 & 511) + (wr << 6);
#pragma unroll
    for (int i = 0; i < 4; ++i)
#pragma unroll
      for (int j = 0; j < 4; ++j) {
        const int c = (wc << 6) + (j << 4) + ql;
        const int hh = c >> 5, d = c & 31;
        ushort4 pk;
        pk.x = f2bf(acc[i][j][0] + b_[j]);
        pk.y = f2bf(acc[i][j][1] + b_[j]);
        pk.z = f2bf(acc[i][j][2] + b_[j]);
        pk.w = f2bf(acc[i][j][3] + b_[j]);
        *reinterpret_cast<ushort4*>(Vt + ((((size_t)g << 3) + hh) << 14) + d * 512 +
                                    key0 + (i << 4) + (u << 2)) = pk;
      }
    return;
  }

  const int ncb = (OUTM == 2) ? 512 : Nc;
  u16* sC = s_all;
#pragma unroll
  for (int halfc = 0; halfc < 2; ++halfc) {
    __syncthreads();
    if ((wc >> 1) == halfc) {
      const int wcl = wc & 1;
#pragma unroll
      for (int i = 0; i < 4; ++i)
#pragma unroll
        for (int j = 0; j < 4; ++j)
#pragma unroll
          for (int r = 0; r < 4; ++r) {
            float v = acc[i][j][r] + b_[j];
            if (ACT) v = fmaxf(v, 0.f);
            const int row = (wr << 6) + (i << 4) + (u << 2) + r;
            const int col = (wcl << 6) + (j << 4) + ql;
            sC[row * 136 + col] = f2bf(v);
          }
    }
    __syncthreads();
#pragma unroll
    for (int it = 0; it < 4; ++it) {
      const int idx = (it << 9) + t;
      const int row = idx >> 4, gc = idx & 15;
      *reinterpret_cast<s16x8*>(Cb + (size_t)(row0 + row) * ncb + col0 + (halfc << 7) + (gc << 3)) =
          *reinterpret_cast<const s16x8*>(sC + row * 136 + (gc << 3));
    }
  }
}

// ---------------------------------------------------------------- Attention v9
// Multiplicative bias (round 10) + 3 barriers + prefetched records/x + per-wave sums.
// LDS dwords: P[32][512]bf16 = 8192 | s_ds[32] | s_ws[4][32]=128 | s_ot[32][36]=1152
//   = 9504 dw = 38,016 B -> 4 WG/CU.
__global__ __launch_bounds__(256) void attn_kernel(
    const u16* __restrict__ qk, const u16* __restrict__ vt,
    const u32* __restrict__ rec_id, const uint4* __restrict__ rec_ew,
    const u32* __restrict__ cnt, const u32* __restrict__ amask,
    const float* __restrict__ relpos,
    const float* __restrict__ x, float* __restrict__ x1) {
  extern __shared__ u32 smem_u[];
  u16* s_p = (u16*)smem_u;                    // [32][512] bf16 (swizzled)
  float* s_ds = (float*)(smem_u + 8192);      // [32] scatter delta sums
  float* s_ws = (float*)(smem_u + 8224);      // [4][2][16] per-wave base sums
  float* s_ot = (float*)(smem_u + 8352);      // [32][36]

  const int braw = blockIdx.x;
  const int b = ((braw & 7) << 9) + (braw >> 3);  // XCD swizzle (4096 % 8 == 0)
  const int qt = b & 15, h = (b >> 4) & 7, g = b >> 7;
  const int t = threadIdx.x;
  const int n0 = (g << 9) + (qt << 5);
  const int lane = t & 63, w = t >> 6;
  const int ql = lane & 15, u = lane >> 4;

  if (t < 32) s_ds[t] = 0.0f;  // first used after barrier #1

  // ---- prefetch scatter records (avg 2/lane; overflow handled in-loop)
  const int bkt = (g << 4) | qt;
  const u32 cn = cnt[(bkt << 2) + w];
  const int nrec = cn > 256u ? 256 : (int)cn;
  const u32* ridb = rec_id + (bkt << 10) + (w << 8);
  const u32* rewb = (const u32*)(rec_ew + ((size_t)bkt << 10) + (w << 8)) + (h >> 1);
  u32 pid0 = 0, pwd0 = 0, pid1 = 0, pwd1 = 0;
  if (lane < nrec)      { pid0 = ridb[lane];      pwd0 = rewb[(size_t)lane << 2]; }
  if (lane + 64 < nrec) { pid1 = ridb[lane + 64]; pwd1 = rewb[(size_t)(lane + 64) << 2]; }

  // ---- prefetch epilogue residual
  const int qe = t >> 3, d4e = (t & 7) << 2;
  const size_t oie = (size_t)(n0 + qe) * D_ + (h << 5) + d4e;
  const f32x4 xve = *reinterpret_cast<const f32x4*>(x + oie);

  // ---- prefetch Q (2) + K (8) fragments
  s16x8 qf8[2], kf8[8];
#pragma unroll
  for (int qf = 0; qf < 2; ++qf)
    qf8[qf] = *reinterpret_cast<const s16x8*>(
        qk + (size_t)(n0 + (qf << 4) + ql) * 512 + (h << 5) + (u << 3));
#pragma unroll
  for (int kf = 0; kf < 8; ++kf)
    kf8[kf] = *reinterpret_cast<const s16x8*>(
        qk + (size_t)((g << 9) + (w << 7) + (kf << 4) + ql) * 512 + 256 + (h << 5) + (u << 3));

  // ---- QK^T (swapped): S^T[key][q]; 16 MFMAs register-only
  f32x4 acc[8][2];
#pragma unroll
  for (int kf = 0; kf < 8; ++kf)
#pragma unroll
    for (int qf = 0; qf < 2; ++qf) acc[kf][qf] = (f32x4){0.f, 0.f, 0.f, 0.f};
  __builtin_amdgcn_s_setprio(1);
#pragma unroll
  for (int kf = 0; kf < 8; ++kf)
#pragma unroll
    for (int qf = 0; qf < 2; ++qf)
      acc[kf][qf] = __builtin_amdgcn_mfma_f32_16x16x32_bf16(kf8[kf], qf8[qf], acc[kf][qf], 0, 0, 0);
  __builtin_amdgcn_s_setprio(0);

  {  // ---- exp (no max) + P write (bf16, swizzled) + per-wave base sums (no barrier needed)
    const float scale = 0.17677669529663687f;  // 1/sqrt(32)
    float sum[2] = {0.f, 0.f};
#pragma unroll
    for (int kf = 0; kf < 8; ++kf) {
#pragma unroll
      for (int qf = 0; qf < 2; ++qf) {
        const int q = (qf << 4) + ql;
        float e[4];
#pragma unroll
        for (int r = 0; r < 4; ++r) {
          e[r] = __expf(acc[kf][qf][r] * scale);
          sum[qf] += e[r];
        }
        const int kl0 = (w << 7) + (kf << 4) + (u << 2);
        const int gran = kl0 >> 3;
        uint2 pw;
        pw.x = (u32)f2bf(e[0]) | ((u32)f2bf(e[1]) << 16);
        pw.y = (u32)f2bf(e[2]) | ((u32)f2bf(e[3]) << 16);
        *reinterpret_cast<uint2*>(s_p + (q << 9) + ((gran ^ (q & 7)) << 3) + (kl0 & 7)) = pw;
      }
    }
#pragma unroll
    for (int qf = 0; qf < 2; ++qf) {
      sum[qf] += __shfl_xor(sum[qf], 16);
      sum[qf] += __shfl_xor(sum[qf], 32);
      if (lane < 16) s_ws[(w << 5) + (qf << 4) + ql] = sum[qf];
    }
  }
  __syncthreads();  // #1: P + s_ws + s_ds-zero visible

  {  // ---- sparse edge pass: P[q][k] *= f, s_ds[q] += P_old*(f-1). Wave w = shard w.
#pragma unroll
    for (int pi = 0; pi < 2; ++pi) {
      const bool valid = (pi == 0) ? (lane < nrec) : (lane + 64 < nrec);
      if (valid) {
        const u32 id = (pi == 0) ? pid0 : pid1;
        const u32 wrd = (pi == 0) ? pwd0 : pwd1;
        const float f = h2f((h & 1) ? (wrd >> 16) : (wrd & 0xffffu));
        const int q = id & 31, k = (int)(id >> 5);
        const int idx16 = (q << 9) + (((k >> 3) ^ (q & 7)) << 3) + (k & 7);
        u32* addr = smem_u + (idx16 >> 1);
        const int sh = (idx16 & 1) << 4;
        u32 old = *addr;
        float pv;
        while (true) {
          pv = bf2f((old >> sh) & 0xffffu);
          const u32 nw = (old & ~(0xffffu << sh)) | ((u32)f2bf(pv * f) << sh);
          const u32 got = atomicCAS(addr, old, nw);
          if (got == old) break;
          old = got;
        }
        atomicAdd(&s_ds[q], pv * (f - 1.0f));
      }
    }
    for (int i = lane + 128; i < nrec; i += 64) {  // rare overflow tail
      const u32 id = ridb[i];
      const u32 wrd = rewb[(size_t)i << 2];
      const float f = h2f((h & 1) ? (wrd >> 16) : (wrd & 0xffffu));
      const int q = id & 31, k = (int)(id >> 5);
      const int idx16 = (q << 9) + (((k >> 3) ^ (q & 7)) << 3) + (k & 7);
      u32* addr = smem_u + (idx16 >> 1);
      const int sh = (idx16 & 1) << 4;
      u32 old = *addr;
      float pv;
      while (true) {
        pv = bf2f((old >> sh) & 0xffffu);
        const u32 nw = (old & ~(0xffffu << sh)) | ((u32)f2bf(pv * f) << sh);
        const u32 got = atomicCAS(addr, old, nw);
        if (got == old) break;
        old = got;
      }
      atomicAdd(&s_ds[q], pv * (f - 1.0f));
    }
    if (g == 0) {  // rel_pos: P *= exp(rp) over deduped adjacency bits
      const float frp = __expf(relpos[h]);
      const float fm1 = frp - 1.0f;
#pragma unroll
      for (int wi = 0; wi < 2; ++wi) {
        const int widx = t + (wi << 8);
        const int q = widx >> 4, w16 = widx & 15;
        u32 m = amask[(((qt << 5) + q) << 4) + w16];
        while (m) {
          const int bit = __ffs(m) - 1;
          m &= m - 1;
          const int k = (w16 << 5) + bit;
          const int idx16 = (q << 9) + (((k >> 3) ^ (q & 7)) << 3) + (k & 7);
          u32* addr = smem_u + (idx16 >> 1);
          const int sh = (idx16 & 1) << 4;
          u32 old = *addr;
          float pv;
          while (true) {
            pv = bf2f((old >> sh) & 0xffffu);
            const u32 nw = (old & ~(0xffffu << sh)) | ((u32)f2bf(pv * frp) << sh);
            const u32 got = atomicCAS(addr, old, nw);
            if (got == old) break;
            old = got;
          }
          atomicAdd(&s_ds[q], pv * fm1);
        }
      }
    }
  }
  __syncthreads();  // #2: corrected P + delta sums visible

  {  // ---- PV: wave -> (wd dim-frag, wq q-frag); full 512 keys
    const int wq = w & 1, wd = w >> 1;
    const u16* vtb = vt + ((((size_t)g << 3) + h) << 14) + (size_t)((wd << 4) + ql) * 512;
    const int q = (wq << 4) + ql;
    f32x4 o = (f32x4){0.f, 0.f, 0.f, 0.f};
    __builtin_amdgcn_s_setprio(1);
#pragma unroll
    for (int ks = 0; ks < 16; ++ks) {
      const s16x8 va = *reinterpret_cast<const s16x8*>(vtb + (ks << 5) + (u << 3));
      const int gran = (ks << 2) + u;
      const s16x8 pb = *reinterpret_cast<const s16x8*>(s_p + (q << 9) + ((gran ^ (q & 7)) << 3));
      o = __builtin_amdgcn_mfma_f32_16x16x32_bf16(va, pb, o, 0, 0, 0);
    }
    __builtin_amdgcn_s_setprio(0);
    const float base = s_ws[q] + s_ws[32 + q] + s_ws[64 + q] + s_ws[96 + q];
    const float invS = 1.0f / (base + s_ds[q & 31]);
#pragma unroll
    for (int r = 0; r < 4; ++r)
      s_ot[q * 36 + (wd << 4) + (u << 2) + r] = o[r] * invS;
  }
  __syncthreads();  // #3

  {  // ---- epilogue: + prefetched x residual
    const f32x4 ov = *reinterpret_cast<const f32x4*>(s_ot + qe * 36 + d4e);
    f32x4 o;
#pragma unroll
    for (int j = 0; j < 4; ++j) o[j] = ov[j] + xve[j];
    *reinterpret_cast<f32x4*>(x1 + oie) = o;
  }
}

// ---------------------------------------------------------------- launch
extern "C" void kernel_launch(void* const* d_in, const int* in_sizes, int n_in,
                              void* d_out, int out_size, void* d_ws, size_t ws_size,
                              hipStream_t stream) {
  const float* x    = (const float*)d_in[0];
  const int*   ei   = (const int*)d_in[1];
  const float* ea   = (const float*)d_in[2];
  const float* ln1g = (const float*)d_in[3];
  const float* ln1b = (const float*)d_in[4];
  const float* wq   = (const float*)d_in[5];
  const float* bq   = (const float*)d_in[6];
  const float* wk   = (const float*)d_in[7];
  const float* bk   = (const float*)d_in[8];
  const float* wv   = (const float*)d_in[9];
  const float* bv   = (const float*)d_in[10];
  const float* wep  = (const float*)d_in[11];
  const float* bep  = (const float*)d_in[12];
  const float* weg  = (const float*)d_in[13];
  const float* beg  = (const float*)d_in[14];
  const float* rp   = (const float*)d_in[15];
  const float* w1   = (const float*)d_in[16];
  const float* b1   = (const float*)d_in[17];
  const float* w2   = (const float*)d_in[18];
  const float* b2   = (const float*)d_in[19];
  const float* ln2g = (const float*)d_in[20];
  const float* ln2b = (const float*)d_in[21];
  float* out = (float*)d_out;

  float* ws = (float*)d_ws;
  const size_t M1 = 1048576;
  u16* xn   = (u16*)ws;                       // [16384][256] bf16
  u16* qk   = (u16*)(ws + 2 * M1);            // [16384][512] bf16 (Q|K)
  u16* vt   = (u16*)(ws + 6 * M1);            // [256][32][512] bf16
  u16* f1   = (u16*)ws;                       // [16384][1024] bf16 (alias, post-attn)
  float* x1 = ws + 8 * M1;                    // f32
  u16* h2   = (u16*)(ws + 12 * M1);           // bf16
  u16* wqkvt = (u16*)(ws + 14 * M1);          // [768][256] bf16
  u16* w1t  = (u16*)(ws + 14 * M1 + 262144);  // [1024][256] bf16
  u16* w2t  = (u16*)(ws + 14 * M1 + 524288);  // [256][1024] bf16
  float* bqkv = ws + 14 * M1 + 786432;        // [768] f32
  u32* cnt  = (u32*)(ws + 14 * M1 + 787456);  // [2048] u32
  u32* amask = cnt + 2048;                    // [512][16] u32 (32KB)
  u32* rec_id = (u32*)(ws + 15 * M1);         // [512*1024] u32 (2MB)
  uint4* rec_ew = (uint4*)(ws + 16 * M1);     // [512*1024] uint4 (8MB)

  // 0. zero cnt+amask, then fused prep (weights | bqkv | edge prep | LN1)
  hipMemsetAsync(cnt, 0, (2048 + 8192) * sizeof(u32), stream);
  prep_all<<<dim3(5825), dim3(256), 0, stream>>>(
      wq, wk, wv, w1, w2, wqkvt, w1t, w2t, bq, bk, bv, bqkv,
      ei, ea, wep, bep, weg, beg, cnt, rec_id, rec_ew, amask, x, ln1g, ln1b, xn);
  // 1. fused QKV GEMM (wide): Q,K -> qk row-major; V -> vt transposed
  mgemm_w<0, 2><<<dim3(128, 3), 512, 0, stream>>>(xn, wqkvt, bqkv, qk, vt, 256, 768);
  // 2. attention (+x residual) -> x1 f32
  const int smem_attn = 9504 * 4;  // 38,016 B -> 4 WG/CU
  (void)hipFuncSetAttribute(reinterpret_cast<const void*>(attn_kernel),
                            hipFuncAttributeMaxDynamicSharedMemorySize, smem_attn);
  attn_kernel<<<dim3(G_ * H_ * 16), 256, smem_attn, stream>>>(qk, vt, rec_id, rec_ew, cnt,
                                                              amask, rp, x, x1);
  // 3. LN2 -> bf16
  ln_kernel<<<dim3(N_ / 4), dim3(256), 0, stream>>>(x1, ln2g, ln2b, h2);
  // 4. FF1 (relu, wide) -> f1 bf16
  mgemm_w<1, 0><<<dim3(128, 4), 512, 0, stream>>>(h2, w1t, b1, f1, nullptr, 256, 1024);
  // 5. FF2 (+bias +x1 residual, narrow) -> out f32
  mgemm_res<<<dim3(128, 2), 256, 0, stream>>>(f1, w2t, b2, x1, out, 1024, 256);
}

// Round 12
// 174.213 us; speedup vs baseline: 1.4360x; 1.0062x over previous
//
#include <hip/hip_runtime.h>
#include <math.h>

#define G_   32
#define NPG_ 512
#define N_   16384
#define E_   262144
#define D_   256
#define H_   8
#define FF_  1024

typedef unsigned int u32;
typedef unsigned short u16;
typedef __attribute__((ext_vector_type(8))) short s16x8;   // 8 x bf16
typedef __attribute__((ext_vector_type(4))) float f32x4;

__device__ inline u16 f2bf(float f) {
  u32 u = __float_as_uint(f);
  u += 0x7fffu + ((u >> 16) & 1u);
  return (u16)(u >> 16);
}
__device__ inline float bf2f(u32 hi16) { return __uint_as_float(hi16 << 16); }
__device__ inline u16 f2h(float f) {
  union { _Float16 h; u16 u; } c; c.h = (_Float16)f; return c.u;
}
__device__ inline float h2f(u32 bits) {
  union { u16 u; _Float16 h; } c; c.u = (u16)bits; return (float)c.h;
}

// ---------------------------------------------------------------- LayerNorm (f32 in, bf16 out)
__device__ inline void ln_row(const float* __restrict__ in, const float* __restrict__ gw,
                              const float* __restrict__ bw, u16* __restrict__ out,
                              int row, int lane) {
  const float4 v = reinterpret_cast<const float4*>(in + (size_t)row * D_)[lane];
  float s = v.x + v.y + v.z + v.w;
#pragma unroll
  for (int off = 32; off > 0; off >>= 1) s += __shfl_xor(s, off);
  const float m = s * (1.0f / D_);
  const float dx = v.x - m, dy = v.y - m, dz = v.z - m, dw = v.w - m;
  float s2 = dx * dx + dy * dy + dz * dz + dw * dw;
#pragma unroll
  for (int off = 32; off > 0; off >>= 1) s2 += __shfl_xor(s2, off);
  const float inv = rsqrtf(s2 * (1.0f / D_) + 1e-5f);
  const float4 g4 = reinterpret_cast<const float4*>(gw)[lane];
  const float4 b4 = reinterpret_cast<const float4*>(bw)[lane];
  ushort4 o;
  o.x = f2bf(dx * inv * g4.x + b4.x);
  o.y = f2bf(dy * inv * g4.y + b4.y);
  o.z = f2bf(dz * inv * g4.z + b4.z);
  o.w = f2bf(dw * inv * g4.w + b4.w);
  *reinterpret_cast<ushort4*>(out + (size_t)row * D_ + (lane << 2)) = o;
}

// ---------------------------------------------------------------- LayerNorm (bf16 in, bf16 out)
__global__ __launch_bounds__(256) void ln_kernel_b(const u16* __restrict__ in,
                                                   const float* __restrict__ gw,
                                                   const float* __restrict__ bw,
                                                   u16* __restrict__ out) {
  const int lane = threadIdx.x & 63;
  const int row = (blockIdx.x << 2) + (threadIdx.x >> 6);
  const ushort4 v4 = *reinterpret_cast<const ushort4*>(in + (size_t)row * D_ + (lane << 2));
  const float vx = bf2f(v4.x), vy = bf2f(v4.y), vz = bf2f(v4.z), vw = bf2f(v4.w);
  float s = vx + vy + vz + vw;
#pragma unroll
  for (int off = 32; off > 0; off >>= 1) s += __shfl_xor(s, off);
  const float m = s * (1.0f / D_);
  const float dx = vx - m, dy = vy - m, dz = vz - m, dw = vw - m;
  float s2 = dx * dx + dy * dy + dz * dz + dw * dw;
#pragma unroll
  for (int off = 32; off > 0; off >>= 1) s2 += __shfl_xor(s2, off);
  const float inv = rsqrtf(s2 * (1.0f / D_) + 1e-5f);
  const float4 g4 = reinterpret_cast<const float4*>(gw)[lane];
  const float4 b4 = reinterpret_cast<const float4*>(bw)[lane];
  ushort4 o;
  o.x = f2bf(dx * inv * g4.x + b4.x);
  o.y = f2bf(dy * inv * g4.y + b4.y);
  o.z = f2bf(dz * inv * g4.z + b4.z);
  o.w = f2bf(dw * inv * g4.w + b4.w);
  *reinterpret_cast<ushort4*>(out + (size_t)row * D_ + (lane << 2)) = o;
}

// ---------------------------------------------------------------- fused prep
__global__ __launch_bounds__(256) void prep_all(
    const float* __restrict__ wq, const float* __restrict__ wk,
    const float* __restrict__ wv, const float* __restrict__ w1,
    const float* __restrict__ w2,
    u16* __restrict__ wqkvt, u16* __restrict__ w1t, u16* __restrict__ w2t,
    const float* __restrict__ bq, const float* __restrict__ bk,
    const float* __restrict__ bv, float* __restrict__ bqkv,
    const int* __restrict__ ei, const float* __restrict__ ea,
    const float* __restrict__ wep, const float* __restrict__ bep,
    const float* __restrict__ weg, const float* __restrict__ beg,
    u32* __restrict__ cnt, u32* __restrict__ rec_id, uint4* __restrict__ rec_ew,
    u32* __restrict__ amask,
    const float* __restrict__ x, const float* __restrict__ ln1g,
    const float* __restrict__ ln1b, u16* __restrict__ xn) {
  const int bid = blockIdx.x;
  const int t = threadIdx.x;
  if (bid >= 1729) {  // LN1
    ln_row(x, ln1g, ln1b, xn, ((bid - 1729) << 2) + (t >> 6), t & 63);
    return;
  }
  if (bid >= 705) {  // edge prep
    const int e = (bid - 705) * 256 + t;
    const int ls = ei[e] & 511;
    const int ld = ei[E_ + e] & 511;
    if (e < 8192)  // graph 0 adjacency (deduped by OR)
      atomicOr(&amask[(ls << 4) + (ld >> 5)], 1u << (ld & 31));
    const int bk = ((e >> 13) << 4) | (ls >> 5);
    const int sh = t & 3;
    const u32 pos = atomicAdd(&cnt[(bk << 2) + sh], 1u);
    if (pos < 256u) {
      const float2 a2 = reinterpret_cast<const float2*>(ea)[e];
      u32 wds[4];
#pragma unroll
      for (int hp = 0; hp < 4; ++hp) {
        float f2[2];
#pragma unroll
        for (int s = 0; s < 2; ++s) {
          const int h = hp * 2 + s;
          const float pre = a2.x * wep[h] + a2.y * wep[H_ + h] + bep[h];
          const float gat = a2.x * weg[h] + a2.y * weg[H_ + h] + beg[h];
          f2[s] = __expf(pre / (1.0f + __expf(-gat)));  // exp(ew): multiplicative factor
        }
        wds[hp] = (u32)f2h(f2[0]) | ((u32)f2h(f2[1]) << 16);
      }
      const int slot = (bk << 10) + (sh << 8) + (int)pos;
      rec_id[slot] = (u32)((ls & 31) | (ld << 5));
      rec_ew[slot] = make_uint4(wds[0], wds[1], wds[2], wds[3]);
    }
    return;
  }
  if (bid == 704) {  // bias pack
    for (int i = t; i < 768; i += 256)
      bqkv[i] = (i < 256) ? bq[i] : (i < 512 ? bk[i - 256] : bv[i - 512]);
    return;
  }
  // weight transpose
  const float* W; u16* Wt; int K, Nc, ro, local;
  if (bid < 64)       { W = wq; Wt = wqkvt; K = 256;  Nc = 256;  ro = 0;   local = bid; }
  else if (bid < 128) { W = wk; Wt = wqkvt; K = 256;  Nc = 256;  ro = 256; local = bid - 64; }
  else if (bid < 192) { W = wv; Wt = wqkvt; K = 256;  Nc = 256;  ro = 512; local = bid - 128; }
  else if (bid < 448) { W = w1; Wt = w1t;   K = 256;  Nc = 1024; ro = 0;   local = bid - 192; }
  else                { W = w2; Wt = w2t;   K = 1024; Nc = 256;  ro = 0;   local = bid - 448; }
  const int tx = t & 31, ty = t >> 5;
  const int tn = Nc >> 5;
  const int n0 = (local % tn) << 5, k0 = (local / tn) << 5;
  __shared__ float tl[32][33];
#pragma unroll
  for (int i = 0; i < 4; ++i)
    tl[ty + (i << 3)][tx] = W[(size_t)(k0 + ty + (i << 3)) * Nc + n0 + tx];
  __syncthreads();
#pragma unroll
  for (int i = 0; i < 4; ++i)
    Wt[(size_t)(ro + n0 + ty + (i << 3)) * K + k0 + tx] = f2bf(tl[tx][ty + (i << 3)]);
}

// ---------------------------------------------------------------- MFMA GEMM narrow (FF2)
__global__ __launch_bounds__(256) void mgemm_res(const u16* __restrict__ A,
                                                 const u16* __restrict__ Bt,
                                                 const float* __restrict__ bias,
                                                 const u16* __restrict__ res,
                                                 float* __restrict__ Cf,
                                                 int K, int Nc) {
  __shared__ u16 s_all[16384];
  u16* sA = s_all;
  u16* sB = s_all + 8192;
  const int t = threadIdx.x;
  const int row0 = blockIdx.x << 7;
  const int col0 = blockIdx.y << 7;
  const int lane = t & 63, w = t >> 6;
  const int ql = lane & 15, u = lane >> 4;
  const int wr = w >> 1, wc = w & 1;

  f32x4 acc[4][4];
#pragma unroll
  for (int i = 0; i < 4; ++i)
#pragma unroll
    for (int j = 0; j < 4; ++j) acc[i][j] = (f32x4){0.f, 0.f, 0.f, 0.f};

  const u16* Ab = A + (size_t)row0 * K;
  const u16* Bb = Bt + (size_t)col0 * K;

  for (int k0 = 0; k0 < K; k0 += 64) {
    __syncthreads();
#pragma unroll
    for (int it = 0; it < 4; ++it) {
      const int idx = (it << 8) + t;
      const int row = idx >> 3;
      const int gcs = (idx & 7) ^ (row & 7);
      __builtin_amdgcn_global_load_lds(
          (const __attribute__((address_space(1))) u32*)(Ab + (size_t)row * K + k0 + (gcs << 3)),
          (__attribute__((address_space(3))) u32*)(sA + (idx << 3)), 16, 0, 0);
    }
#pragma unroll
    for (int it = 0; it < 4; ++it) {
      const int idx = (it << 8) + t;
      const int row = idx >> 3;
      const int gcs = (idx & 7) ^ (row & 7);
      __builtin_amdgcn_global_load_lds(
          (const __attribute__((address_space(1))) u32*)(Bb + (size_t)row * K + k0 + (gcs << 3)),
          (__attribute__((address_space(3))) u32*)(sB + (idx << 3)), 16, 0, 0);
    }
    __syncthreads();
#pragma unroll
    for (int ks = 0; ks < 2; ++ks) {
      const int gk = (ks << 2) + u;
      s16x8 aF[4], bF[4];
#pragma unroll
      for (int i = 0; i < 4; ++i) {
        const int ra = (wr << 6) + (i << 4) + ql;
        aF[i] = *reinterpret_cast<const s16x8*>(sA + ra * 64 + ((gk ^ (ra & 7)) << 3));
        const int rb = (wc << 6) + (i << 4) + ql;
        bF[i] = *reinterpret_cast<const s16x8*>(sB + rb * 64 + ((gk ^ (rb & 7)) << 3));
      }
#pragma unroll
      for (int i = 0; i < 4; ++i)
#pragma unroll
        for (int j = 0; j < 4; ++j)
          acc[i][j] = __builtin_amdgcn_mfma_f32_16x16x32_bf16(aF[i], bF[j], acc[i][j], 0, 0, 0);
    }
  }

  float b_[4];
#pragma unroll
  for (int j = 0; j < 4; ++j) b_[j] = bias[col0 + (wc << 6) + (j << 4) + ql];
#pragma unroll
  for (int i = 0; i < 4; ++i)
#pragma unroll
    for (int j = 0; j < 4; ++j)
#pragma unroll
      for (int r = 0; r < 4; ++r) {
        const int row = row0 + (wr << 6) + (i << 4) + (u << 2) + r;
        const int col = col0 + (wc << 6) + (j << 4) + ql;
        Cf[(size_t)row * Nc + col] =
            acc[i][j][r] + b_[j] + bf2f(res[(size_t)row * Nc + col]);
      }
}

// ---------------------------------------------------------------- MFMA GEMM wide (QKV, FF1)
template <int ACT, int OUTM>
__global__ __launch_bounds__(512) void mgemm_w(const u16* __restrict__ A,
                                               const u16* __restrict__ Bt,
                                               const float* __restrict__ bias,
                                               u16* __restrict__ Cb,
                                               u16* __restrict__ Vt,
                                               int K, int Nc) {
  __shared__ u16 s_all[24576];  // sA[128][64] | sB[256][64]; sC[128][136] alias
  u16* sA = s_all;
  u16* sB = s_all + 8192;
  const int t = threadIdx.x;
  const int row0 = blockIdx.x << 7;
  const int col0 = blockIdx.y << 8;
  const int lane = t & 63, w = t >> 6;
  const int ql = lane & 15, u = lane >> 4;
  const int wr = w >> 2, wc = w & 3;

  f32x4 acc[4][4];
#pragma unroll
  for (int i = 0; i < 4; ++i)
#pragma unroll
    for (int j = 0; j < 4; ++j) acc[i][j] = (f32x4){0.f, 0.f, 0.f, 0.f};

  const u16* Ab = A + (size_t)row0 * K;
  const u16* Bb = Bt + (size_t)col0 * K;

  for (int k0 = 0; k0 < K; k0 += 64) {
    __syncthreads();
#pragma unroll
    for (int it = 0; it < 2; ++it) {
      const int idx = (it << 9) + t;
      const int row = idx >> 3;
      const int gcs = (idx & 7) ^ (row & 7);
      __builtin_amdgcn_global_load_lds(
          (const __attribute__((address_space(1))) u32*)(Ab + (size_t)row * K + k0 + (gcs << 3)),
          (__attribute__((address_space(3))) u32*)(sA + (idx << 3)), 16, 0, 0);
    }
#pragma unroll
    for (int it = 0; it < 4; ++it) {
      const int idx = (it << 9) + t;
      const int row = idx >> 3;
      const int gcs = (idx & 7) ^ (row & 7);
      __builtin_amdgcn_global_load_lds(
          (const __attribute__((address_space(1))) u32*)(Bb + (size_t)row * K + k0 + (gcs << 3)),
          (__attribute__((address_space(3))) u32*)(sB + (idx << 3)), 16, 0, 0);
    }
    __syncthreads();
#pragma unroll
    for (int ks = 0; ks < 2; ++ks) {
      const int gk = (ks << 2) + u;
      s16x8 aF[4], bF[4];
#pragma unroll
      for (int i = 0; i < 4; ++i) {
        const int ra = (wr << 6) + (i << 4) + ql;
        aF[i] = *reinterpret_cast<const s16x8*>(sA + ra * 64 + ((gk ^ (ra & 7)) << 3));
        const int rb = (wc << 6) + (i << 4) + ql;
        bF[i] = *reinterpret_cast<const s16x8*>(sB + rb * 64 + ((gk ^ (rb & 7)) << 3));
      }
#pragma unroll
      for (int i = 0; i < 4; ++i)
#pragma unroll
        for (int j = 0; j < 4; ++j)
          acc[i][j] = __builtin_amdgcn_mfma_f32_16x16x32_bf16(aF[i], bF[j], acc[i][j], 0, 0, 0);
    }
  }

  float b_[4];
#pragma unroll
  for (int j = 0; j < 4; ++j) b_[j] = bias[col0 + (wc << 6) + (j << 4) + ql];

  if (OUTM == 2 && col0 >= 512) {  // V -> transposed vt[(g*8+h)][d][node]
    const int g = row0 >> 9;
    const int key0 = (row0 & 511) + (wr << 6);
#pragma unroll
    for (int i = 0; i < 4; ++i)
#pragma unroll
      for (int j = 0; j < 4; ++j) {
        const int c = (wc << 6) + (j << 4) + ql;
        const int hh = c >> 5, d = c & 31;
        ushort4 pk;
        pk.x = f2bf(acc[i][j][0] + b_[j]);
        pk.y = f2bf(acc[i][j][1] + b_[j]);
        pk.z = f2bf(acc[i][j][2] + b_[j]);
        pk.w = f2bf(acc[i][j][3] + b_[j]);
        *reinterpret_cast<ushort4*>(Vt + ((((size_t)g << 3) + hh) << 14) + d * 512 +
                                    key0 + (i << 4) + (u << 2)) = pk;
      }
    return;
  }

  const int ncb = (OUTM == 2) ? 512 : Nc;
  u16* sC = s_all;
#pragma unroll
  for (int halfc = 0; halfc < 2; ++halfc) {
    __syncthreads();
    if ((wc >> 1) == halfc) {
      const int wcl = wc & 1;
#pragma unroll
      for (int i = 0; i < 4; ++i)
#pragma unroll
        for (int j = 0; j < 4; ++j)
#pragma unroll
          for (int r = 0; r < 4; ++r) {
            float v = acc[i][j][r] + b_[j];
            if (ACT) v = fmaxf(v, 0.f);
            const int row = (wr << 6) + (i << 4) + (u << 2) + r;
            const int col = (wcl << 6) + (j << 4) + ql;
            sC[row * 136 + col] = f2bf(v);
          }
    }
    __syncthreads();
#pragma unroll
    for (int it = 0; it < 4; ++it) {
      const int idx = (it << 9) + t;
      const int row = idx >> 4, gc = idx & 15;
      *reinterpret_cast<s16x8*>(Cb + (size_t)(row0 + row) * ncb + col0 + (halfc << 7) + (gc << 3)) =
          *reinterpret_cast<const s16x8*>(sC + row * 136 + (gc << 3));
    }
  }
}

// ---------------------------------------------------------------- Attention v10
// Multiplicative bias; 2 barriers; PV writes x1 (bf16) directly from registers.
// LDS dwords: P[32][512]bf16 = 8192 | s_ds[32] | s_ws[4][32]=128 = 8352 dw = 33,408 B.
__global__ __launch_bounds__(256) void attn_kernel(
    const u16* __restrict__ qk, const u16* __restrict__ vt,
    const u32* __restrict__ rec_id, const uint4* __restrict__ rec_ew,
    const u32* __restrict__ cnt, const u32* __restrict__ amask,
    const float* __restrict__ relpos,
    const float* __restrict__ x, u16* __restrict__ x1b) {
  extern __shared__ u32 smem_u[];
  u16* s_p = (u16*)smem_u;                    // [32][512] bf16 (swizzled)
  float* s_ds = (float*)(smem_u + 8192);      // [32] scatter delta sums
  float* s_ws = (float*)(smem_u + 8224);      // [4][2][16] per-wave base sums

  const int braw = blockIdx.x;
  const int b = ((braw & 7) << 9) + (braw >> 3);  // XCD swizzle (4096 % 8 == 0)
  const int qt = b & 15, h = (b >> 4) & 7, g = b >> 7;
  const int t = threadIdx.x;
  const int n0 = (g << 9) + (qt << 5);
  const int lane = t & 63, w = t >> 6;
  const int ql = lane & 15, u = lane >> 4;

  if (t < 32) s_ds[t] = 0.0f;  // first used after barrier #1

  // ---- prefetch scatter records (avg 2/lane; overflow handled in-loop)
  const int bkt = (g << 4) | qt;
  const u32 cn = cnt[(bkt << 2) + w];
  const int nrec = cn > 256u ? 256 : (int)cn;
  const u32* ridb = rec_id + (bkt << 10) + (w << 8);
  const u32* rewb = (const u32*)(rec_ew + ((size_t)bkt << 10) + (w << 8)) + (h >> 1);
  u32 pid0 = 0, pwd0 = 0, pid1 = 0, pwd1 = 0;
  if (lane < nrec)      { pid0 = ridb[lane];      pwd0 = rewb[(size_t)lane << 2]; }
  if (lane + 64 < nrec) { pid1 = ridb[lane + 64]; pwd1 = rewb[(size_t)(lane + 64) << 2]; }

  // ---- PV-role residual prefetch (epilogue fused into PV)
  const int wqv = w & 1, wdv = w >> 1;
  const int qv = (wqv << 4) + ql;
  const size_t oiv = (size_t)(n0 + qv) * D_ + (h << 5) + (wdv << 4) + (u << 2);
  const f32x4 xvv = *reinterpret_cast<const f32x4*>(x + oiv);

  // ---- prefetch Q (2) + K (8) fragments
  s16x8 qf8[2], kf8[8];
#pragma unroll
  for (int qf = 0; qf < 2; ++qf)
    qf8[qf] = *reinterpret_cast<const s16x8*>(
        qk + (size_t)(n0 + (qf << 4) + ql) * 512 + (h << 5) + (u << 3));
#pragma unroll
  for (int kf = 0; kf < 8; ++kf)
    kf8[kf] = *reinterpret_cast<const s16x8*>(
        qk + (size_t)((g << 9) + (w << 7) + (kf << 4) + ql) * 512 + 256 + (h << 5) + (u << 3));

  // ---- QK^T (swapped): S^T[key][q]; 16 MFMAs register-only
  f32x4 acc[8][2];
#pragma unroll
  for (int kf = 0; kf < 8; ++kf)
#pragma unroll
    for (int qf = 0; qf < 2; ++qf) acc[kf][qf] = (f32x4){0.f, 0.f, 0.f, 0.f};
  __builtin_amdgcn_s_setprio(1);
#pragma unroll
  for (int kf = 0; kf < 8; ++kf)
#pragma unroll
    for (int qf = 0; qf < 2; ++qf)
      acc[kf][qf] = __builtin_amdgcn_mfma_f32_16x16x32_bf16(kf8[kf], qf8[qf], acc[kf][qf], 0, 0, 0);
  __builtin_amdgcn_s_setprio(0);

  {  // ---- exp (no max; v_exp with folded scale*log2e) + P pack (cvt_pk) + per-wave sums
    const float CF = 0.25503531490029224f;  // (1/sqrt(32)) * log2(e)
    float sum[2] = {0.f, 0.f};
#pragma unroll
    for (int kf = 0; kf < 8; ++kf) {
#pragma unroll
      for (int qf = 0; qf < 2; ++qf) {
        const int q = (qf << 4) + ql;
        float e[4];
#pragma unroll
        for (int r = 0; r < 4; ++r) {
          const float xx = acc[kf][qf][r] * CF;
          asm("v_exp_f32 %0, %1" : "=v"(e[r]) : "v"(xx));
          sum[qf] += e[r];
        }
        uint2 pw;
        asm("v_cvt_pk_bf16_f32 %0, %1, %2" : "=v"(pw.x) : "v"(e[0]), "v"(e[1]));
        asm("v_cvt_pk_bf16_f32 %0, %1, %2" : "=v"(pw.y) : "v"(e[2]), "v"(e[3]));
        const int kl0 = (w << 7) + (kf << 4) + (u << 2);
        const int gran = kl0 >> 3;
        *reinterpret_cast<uint2*>(s_p + (q << 9) + ((gran ^ (q & 7)) << 3) + (kl0 & 7)) = pw;
      }
    }
#pragma unroll
    for (int qf = 0; qf < 2; ++qf) {
      sum[qf] += __shfl_xor(sum[qf], 16);
      sum[qf] += __shfl_xor(sum[qf], 32);
      if (lane < 16) s_ws[(w << 5) + (qf << 4) + ql] = sum[qf];
    }
  }
  __syncthreads();  // #1: P + s_ws + s_ds-zero visible

  {  // ---- sparse edge pass: P[q][k] *= f, s_ds[q] += P_old*(f-1). Wave w = shard w.
#pragma unroll
    for (int pi = 0; pi < 2; ++pi) {
      const bool valid = (pi == 0) ? (lane < nrec) : (lane + 64 < nrec);
      if (valid) {
        const u32 id = (pi == 0) ? pid0 : pid1;
        const u32 wrd = (pi == 0) ? pwd0 : pwd1;
        const float f = h2f((h & 1) ? (wrd >> 16) : (wrd & 0xffffu));
        const int q = id & 31, k = (int)(id >> 5);
        const int idx16 = (q << 9) + (((k >> 3) ^ (q & 7)) << 3) + (k & 7);
        u32* addr = smem_u + (idx16 >> 1);
        const int sh = (idx16 & 1) << 4;
        u32 old = *addr;
        float pv;
        while (true) {
          pv = bf2f((old >> sh) & 0xffffu);
          const u32 nw = (old & ~(0xffffu << sh)) | ((u32)f2bf(pv * f) << sh);
          const u32 got = atomicCAS(addr, old, nw);
          if (got == old) break;
          old = got;
        }
        atomicAdd(&s_ds[q], pv * (f - 1.0f));
      }
    }
    for (int i = lane + 128; i < nrec; i += 64) {  // rare overflow tail
      const u32 id = ridb[i];
      const u32 wrd = rewb[(size_t)i << 2];
      const float f = h2f((h & 1) ? (wrd >> 16) : (wrd & 0xffffu));
      const int q = id & 31, k = (int)(id >> 5);
      const int idx16 = (q << 9) + (((k >> 3) ^ (q & 7)) << 3) + (k & 7);
      u32* addr = smem_u + (idx16 >> 1);
      const int sh = (idx16 & 1) << 4;
      u32 old = *addr;
      float pv;
      while (true) {
        pv = bf2f((old >> sh) & 0xffffu);
        const u32 nw = (old & ~(0xffffu << sh)) | ((u32)f2bf(pv * f) << sh);
        const u32 got = atomicCAS(addr, old, nw);
        if (got == old) break;
        old = got;
      }
      atomicAdd(&s_ds[q], pv * (f - 1.0f));
    }
    if (g == 0) {  // rel_pos: P *= exp(rp) over deduped adjacency bits
      const float frp = __expf(relpos[h]);
      const float fm1 = frp - 1.0f;
#pragma unroll
      for (int wi = 0; wi < 2; ++wi) {
        const int widx = t + (wi << 8);
        const int q = widx >> 4, w16 = widx & 15;
        u32 m = amask[(((qt << 5) + q) << 4) + w16];
        while (m) {
          const int bit = __ffs(m) - 1;
          m &= m - 1;
          const int k = (w16 << 5) + bit;
          const int idx16 = (q << 9) + (((k >> 3) ^ (q & 7)) << 3) + (k & 7);
          u32* addr = smem_u + (idx16 >> 1);
          const int sh = (idx16 & 1) << 4;
          u32 old = *addr;
          float pv;
          while (true) {
            pv = bf2f((old >> sh) & 0xffffu);
            const u32 nw = (old & ~(0xffffu << sh)) | ((u32)f2bf(pv * frp) << sh);
            const u32 got = atomicCAS(addr, old, nw);
            if (got == old) break;
            old = got;
          }
          atomicAdd(&s_ds[q], pv * fm1);
        }
      }
    }
  }
  __syncthreads();  // #2: corrected P + delta sums visible

  {  // ---- PV + fused epilogue: direct bf16 store of x1 from registers
    const u16* vtb = vt + ((((size_t)g << 3) + h) << 14) + (size_t)((wdv << 4) + ql) * 512;
    f32x4 o = (f32x4){0.f, 0.f, 0.f, 0.f};
    __builtin_amdgcn_s_setprio(1);
#pragma unroll
    for (int ks = 0; ks < 16; ++ks) {
      const s16x8 va = *reinterpret_cast<const s16x8*>(vtb + (ks << 5) + (u << 3));
      const int gran = (ks << 2) + u;
      const s16x8 pb = *reinterpret_cast<const s16x8*>(s_p + (qv << 9) + ((gran ^ (qv & 7)) << 3));
      o = __builtin_amdgcn_mfma_f32_16x16x32_bf16(va, pb, o, 0, 0, 0);
    }
    __builtin_amdgcn_s_setprio(0);
    const float base = s_ws[qv] + s_ws[32 + qv] + s_ws[64 + qv] + s_ws[96 + qv];
    const float invS = 1.0f / (base + s_ds[qv]);
    ushort4 st;
    st.x = f2bf(o[0] * invS + xvv[0]);
    st.y = f2bf(o[1] * invS + xvv[1]);
    st.z = f2bf(o[2] * invS + xvv[2]);
    st.w = f2bf(o[3] * invS + xvv[3]);
    *reinterpret_cast<ushort4*>(x1b + oiv) = st;
  }
}

// ---------------------------------------------------------------- launch
extern "C" void kernel_launch(void* const* d_in, const int* in_sizes, int n_in,
                              void* d_out, int out_size, void* d_ws, size_t ws_size,
                              hipStream_t stream) {
  const float* x    = (const float*)d_in[0];
  const int*   ei   = (const int*)d_in[1];
  const float* ea   = (const float*)d_in[2];
  const float* ln1g = (const float*)d_in[3];
  const float* ln1b = (const float*)d_in[4];
  const float* wq   = (const float*)d_in[5];
  const float* bq   = (const float*)d_in[6];
  const float* wk   = (const float*)d_in[7];
  const float* bk   = (const float*)d_in[8];
  const float* wv   = (const float*)d_in[9];
  const float* bv   = (const float*)d_in[10];
  const float* wep  = (const float*)d_in[11];
  const float* bep  = (const float*)d_in[12];
  const float* weg  = (const float*)d_in[13];
  const float* beg  = (const float*)d_in[14];
  const float* rp   = (const float*)d_in[15];
  const float* w1   = (const float*)d_in[16];
  const float* b1   = (const float*)d_in[17];
  const float* w2   = (const float*)d_in[18];
  const float* b2   = (const float*)d_in[19];
  const float* ln2g = (const float*)d_in[20];
  const float* ln2b = (const float*)d_in[21];
  float* out = (float*)d_out;

  float* ws = (float*)d_ws;
  const size_t M1 = 1048576;
  u16* xn   = (u16*)ws;                       // [16384][256] bf16
  u16* qk   = (u16*)(ws + 2 * M1);            // [16384][512] bf16 (Q|K)
  u16* vt   = (u16*)(ws + 6 * M1);            // [256][32][512] bf16
  u16* f1   = (u16*)ws;                       // [16384][1024] bf16 (alias, post-attn)
  u16* x1b  = (u16*)(ws + 8 * M1);            // [16384][256] bf16
  u16* h2   = (u16*)(ws + 12 * M1);           // bf16
  u16* wqkvt = (u16*)(ws + 14 * M1);          // [768][256] bf16
  u16* w1t  = (u16*)(ws + 14 * M1 + 262144);  // [1024][256] bf16
  u16* w2t  = (u16*)(ws + 14 * M1 + 524288);  // [256][1024] bf16
  float* bqkv = ws + 14 * M1 + 786432;        // [768] f32
  u32* cnt  = (u32*)(ws + 14 * M1 + 787456);  // [2048] u32
  u32* amask = cnt + 2048;                    // [512][16] u32 (32KB)
  u32* rec_id = (u32*)(ws + 15 * M1);         // [512*1024] u32 (2MB)
  uint4* rec_ew = (uint4*)(ws + 16 * M1);     // [512*1024] uint4 (8MB)

  // 0. zero cnt+amask, then fused prep (weights | bqkv | edge prep | LN1)
  hipMemsetAsync(cnt, 0, (2048 + 8192) * sizeof(u32), stream);
  prep_all<<<dim3(5825), dim3(256), 0, stream>>>(
      wq, wk, wv, w1, w2, wqkvt, w1t, w2t, bq, bk, bv, bqkv,
      ei, ea, wep, bep, weg, beg, cnt, rec_id, rec_ew, amask, x, ln1g, ln1b, xn);
  // 1. fused QKV GEMM (wide): Q,K -> qk row-major; V -> vt transposed
  mgemm_w<0, 2><<<dim3(128, 3), 512, 0, stream>>>(xn, wqkvt, bqkv, qk, vt, 256, 768);
  // 2. attention (+x residual) -> x1b bf16
  const int smem_attn = 8352 * 4;  // 33,408 B -> 4 WG/CU
  (void)hipFuncSetAttribute(reinterpret_cast<const void*>(attn_kernel),
                            hipFuncAttributeMaxDynamicSharedMemorySize, smem_attn);
  attn_kernel<<<dim3(G_ * H_ * 16), 256, smem_attn, stream>>>(qk, vt, rec_id, rec_ew, cnt,
                                                              amask, rp, x, x1b);
  // 3. LN2 (bf16 in) -> bf16
  ln_kernel_b<<<dim3(N_ / 4), dim3(256), 0, stream>>>(x1b, ln2g, ln2b, h2);
  // 4. FF1 (relu, wide) -> f1 bf16
  mgemm_w<1, 0><<<dim3(128, 4), 512, 0, stream>>>(h2, w1t, b1, f1, nullptr, 256, 1024);
  // 5. FF2 (+bias +x1b residual, narrow) -> out f32
  mgemm_res<<<dim3(128, 2), 256, 0, stream>>>(f1, w2t, b2, x1b, out, 1024, 256);
}

// Round 14
// 168.778 us; speedup vs baseline: 1.4823x; 1.0322x over previous
//
#include <hip/hip_runtime.h>
#include <math.h>

#define G_   32
#define NPG_ 512
#define N_   16384
#define E_   262144
#define D_   256
#define H_   8
#define FF_  1024

typedef unsigned int u32;
typedef unsigned short u16;
typedef __attribute__((ext_vector_type(8))) short s16x8;   // 8 x bf16
typedef __attribute__((ext_vector_type(4))) float f32x4;

#define AS1 __attribute__((address_space(1)))
#define AS3 __attribute__((address_space(3)))
#define VMCNT0() asm volatile("s_waitcnt vmcnt(0)" ::: "memory")

__device__ inline u16 f2bf(float f) {
  u32 u = __float_as_uint(f);
  u += 0x7fffu + ((u >> 16) & 1u);
  return (u16)(u >> 16);
}
__device__ inline float bf2f(u32 hi16) { return __uint_as_float(hi16 << 16); }
__device__ inline u16 f2h(float f) {
  union { _Float16 h; u16 u; } c; c.h = (_Float16)f; return c.u;
}
__device__ inline float h2f(u32 bits) {
  union { u16 u; _Float16 h; } c; c.u = (u16)bits; return (float)c.h;
}

// ---------------------------------------------------------------- LayerNorm (f32 in, bf16 out)
__device__ inline void ln_row(const float* __restrict__ in, const float* __restrict__ gw,
                              const float* __restrict__ bw, u16* __restrict__ out,
                              int row, int lane) {
  const float4 v = reinterpret_cast<const float4*>(in + (size_t)row * D_)[lane];
  float s = v.x + v.y + v.z + v.w;
#pragma unroll
  for (int off = 32; off > 0; off >>= 1) s += __shfl_xor(s, off);
  const float m = s * (1.0f / D_);
  const float dx = v.x - m, dy = v.y - m, dz = v.z - m, dw = v.w - m;
  float s2 = dx * dx + dy * dy + dz * dz + dw * dw;
#pragma unroll
  for (int off = 32; off > 0; off >>= 1) s2 += __shfl_xor(s2, off);
  const float inv = rsqrtf(s2 * (1.0f / D_) + 1e-5f);
  const float4 g4 = reinterpret_cast<const float4*>(gw)[lane];
  const float4 b4 = reinterpret_cast<const float4*>(bw)[lane];
  ushort4 o;
  o.x = f2bf(dx * inv * g4.x + b4.x);
  o.y = f2bf(dy * inv * g4.y + b4.y);
  o.z = f2bf(dz * inv * g4.z + b4.z);
  o.w = f2bf(dw * inv * g4.w + b4.w);
  *reinterpret_cast<ushort4*>(out + (size_t)row * D_ + (lane << 2)) = o;
}

// ---------------------------------------------------------------- LayerNorm (bf16 in, bf16 out)
__global__ __launch_bounds__(256) void ln_kernel_b(const u16* __restrict__ in,
                                                   const float* __restrict__ gw,
                                                   const float* __restrict__ bw,
                                                   u16* __restrict__ out) {
  const int lane = threadIdx.x & 63;
  const int row = (blockIdx.x << 2) + (threadIdx.x >> 6);
  const ushort4 v4 = *reinterpret_cast<const ushort4*>(in + (size_t)row * D_ + (lane << 2));
  const float vx = bf2f(v4.x), vy = bf2f(v4.y), vz = bf2f(v4.z), vw = bf2f(v4.w);
  float s = vx + vy + vz + vw;
#pragma unroll
  for (int off = 32; off > 0; off >>= 1) s += __shfl_xor(s, off);
  const float m = s * (1.0f / D_);
  const float dx = vx - m, dy = vy - m, dz = vz - m, dw = vw - m;
  float s2 = dx * dx + dy * dy + dz * dz + dw * dw;
#pragma unroll
  for (int off = 32; off > 0; off >>= 1) s2 += __shfl_xor(s2, off);
  const float inv = rsqrtf(s2 * (1.0f / D_) + 1e-5f);
  const float4 g4 = reinterpret_cast<const float4*>(gw)[lane];
  const float4 b4 = reinterpret_cast<const float4*>(bw)[lane];
  ushort4 o;
  o.x = f2bf(dx * inv * g4.x + b4.x);
  o.y = f2bf(dy * inv * g4.y + b4.y);
  o.z = f2bf(dz * inv * g4.z + b4.z);
  o.w = f2bf(dw * inv * g4.w + b4.w);
  *reinterpret_cast<ushort4*>(out + (size_t)row * D_ + (lane << 2)) = o;
}

// ---------------------------------------------------------------- fused prep
__global__ __launch_bounds__(256) void prep_all(
    const float* __restrict__ wq, const float* __restrict__ wk,
    const float* __restrict__ wv, const float* __restrict__ w1,
    const float* __restrict__ w2,
    u16* __restrict__ wqkvt, u16* __restrict__ w1t, u16* __restrict__ w2t,
    const float* __restrict__ bq, const float* __restrict__ bk,
    const float* __restrict__ bv, float* __restrict__ bqkv,
    const int* __restrict__ ei, const float* __restrict__ ea,
    const float* __restrict__ wep, const float* __restrict__ bep,
    const float* __restrict__ weg, const float* __restrict__ beg,
    u32* __restrict__ cnt, u32* __restrict__ rec_id, uint4* __restrict__ rec_ew,
    u32* __restrict__ amask,
    const float* __restrict__ x, const float* __restrict__ ln1g,
    const float* __restrict__ ln1b, u16* __restrict__ xn) {
  const int bid = blockIdx.x;
  const int t = threadIdx.x;
  if (bid >= 1729) {  // LN1
    ln_row(x, ln1g, ln1b, xn, ((bid - 1729) << 2) + (t >> 6), t & 63);
    return;
  }
  if (bid >= 705) {  // edge prep
    const int e = (bid - 705) * 256 + t;
    const int ls = ei[e] & 511;
    const int ld = ei[E_ + e] & 511;
    if (e < 8192)  // graph 0 adjacency (deduped by OR)
      atomicOr(&amask[(ls << 4) + (ld >> 5)], 1u << (ld & 31));
    const int bk = ((e >> 13) << 4) | (ls >> 5);
    const int sh = t & 3;
    const u32 pos = atomicAdd(&cnt[(bk << 2) + sh], 1u);
    if (pos < 256u) {
      const float2 a2 = reinterpret_cast<const float2*>(ea)[e];
      u32 wds[4];
#pragma unroll
      for (int hp = 0; hp < 4; ++hp) {
        float f2[2];
#pragma unroll
        for (int s = 0; s < 2; ++s) {
          const int h = hp * 2 + s;
          const float pre = a2.x * wep[h] + a2.y * wep[H_ + h] + bep[h];
          const float gat = a2.x * weg[h] + a2.y * weg[H_ + h] + beg[h];
          f2[s] = __expf(pre / (1.0f + __expf(-gat)));  // exp(ew): multiplicative factor
        }
        wds[hp] = (u32)f2h(f2[0]) | ((u32)f2h(f2[1]) << 16);
      }
      const int slot = (bk << 10) + (sh << 8) + (int)pos;
      rec_id[slot] = (u32)((ls & 31) | (ld << 5));
      rec_ew[slot] = make_uint4(wds[0], wds[1], wds[2], wds[3]);
    }
    return;
  }
  if (bid == 704) {  // bias pack
    for (int i = t; i < 768; i += 256)
      bqkv[i] = (i < 256) ? bq[i] : (i < 512 ? bk[i - 256] : bv[i - 512]);
    return;
  }
  // weight transpose
  const float* W; u16* Wt; int K, Nc, ro, local;
  if (bid < 64)       { W = wq; Wt = wqkvt; K = 256;  Nc = 256;  ro = 0;   local = bid; }
  else if (bid < 128) { W = wk; Wt = wqkvt; K = 256;  Nc = 256;  ro = 256; local = bid - 64; }
  else if (bid < 192) { W = wv; Wt = wqkvt; K = 256;  Nc = 256;  ro = 512; local = bid - 128; }
  else if (bid < 448) { W = w1; Wt = w1t;   K = 256;  Nc = 1024; ro = 0;   local = bid - 192; }
  else                { W = w2; Wt = w2t;   K = 1024; Nc = 256;  ro = 0;   local = bid - 448; }
  const int tx = t & 31, ty = t >> 5;
  const int tn = Nc >> 5;
  const int n0 = (local % tn) << 5, k0 = (local / tn) << 5;
  __shared__ float tl[32][33];
#pragma unroll
  for (int i = 0; i < 4; ++i)
    tl[ty + (i << 3)][tx] = W[(size_t)(k0 + ty + (i << 3)) * Nc + n0 + tx];
  __syncthreads();
#pragma unroll
  for (int i = 0; i < 4; ++i)
    Wt[(size_t)(ro + n0 + ty + (i << 3)) * K + k0 + tx] = f2bf(tl[tx][ty + (i << 3)]);
}

// ---------------------------------------------------------------- MFMA GEMM narrow (FF2)
// BM=BN=128, 256 thr; BK=64 double-buffered with EXPLICIT vmcnt(0) before barriers.
__global__ __launch_bounds__(256) void mgemm_res(const u16* __restrict__ A,
                                                 const u16* __restrict__ Bt,
                                                 const float* __restrict__ bias,
                                                 const u16* __restrict__ res,
                                                 float* __restrict__ Cf,
                                                 int K, int Nc) {
  __shared__ u16 s_all[32768];  // [2][ A 8192 | B 8192 ]
  const int t = threadIdx.x;
  const int row0 = blockIdx.x << 7;
  const int col0 = blockIdx.y << 7;
  const int lane = t & 63, w = t >> 6;
  const int ql = lane & 15, u = lane >> 4;
  const int wr = w >> 1, wc = w & 1;

  f32x4 acc[4][4];
#pragma unroll
  for (int i = 0; i < 4; ++i)
#pragma unroll
    for (int j = 0; j < 4; ++j) acc[i][j] = (f32x4){0.f, 0.f, 0.f, 0.f};

  const u16* Ab = A + (size_t)row0 * K;
  const u16* Bb = Bt + (size_t)col0 * K;

  auto stage = [&](int c, int k0) {
    u16* bufA = s_all + c * 16384;
    u16* bufB = bufA + 8192;
#pragma unroll
    for (int it = 0; it < 4; ++it) {
      const int idx = (it << 8) + t;
      const int row = idx >> 3;
      const int gcs = (idx & 7) ^ (row & 7);
      __builtin_amdgcn_global_load_lds(
          (const AS1 u32*)(Ab + (size_t)row * K + k0 + (gcs << 3)),
          (AS3 u32*)(bufA + (idx << 3)), 16, 0, 0);
    }
#pragma unroll
    for (int it = 0; it < 4; ++it) {
      const int idx = (it << 8) + t;
      const int row = idx >> 3;
      const int gcs = (idx & 7) ^ (row & 7);
      __builtin_amdgcn_global_load_lds(
          (const AS1 u32*)(Bb + (size_t)row * K + k0 + (gcs << 3)),
          (AS3 u32*)(bufB + (idx << 3)), 16, 0, 0);
    }
  };

  stage(0, 0);
  VMCNT0();
  __syncthreads();
  int cur = 0;
  for (int k0 = 0; k0 < K; k0 += 64, cur ^= 1) {
    if (k0 + 64 < K) stage(cur ^ 1, k0 + 64);
    const u16* sA = s_all + cur * 16384;
    const u16* sB = sA + 8192;
#pragma unroll
    for (int ks = 0; ks < 2; ++ks) {
      const int gk = (ks << 2) + u;
      s16x8 aF[4], bF[4];
#pragma unroll
      for (int i = 0; i < 4; ++i) {
        const int ra = (wr << 6) + (i << 4) + ql;
        aF[i] = *reinterpret_cast<const s16x8*>(sA + ra * 64 + ((gk ^ (ra & 7)) << 3));
        const int rb = (wc << 6) + (i << 4) + ql;
        bF[i] = *reinterpret_cast<const s16x8*>(sB + rb * 64 + ((gk ^ (rb & 7)) << 3));
      }
#pragma unroll
      for (int i = 0; i < 4; ++i)
#pragma unroll
        for (int j = 0; j < 4; ++j)
          acc[i][j] = __builtin_amdgcn_mfma_f32_16x16x32_bf16(aF[i], bF[j], acc[i][j], 0, 0, 0);
    }
    VMCNT0();        // prefetch landed before any wave crosses the barrier
    __syncthreads();
  }

  float b_[4];
#pragma unroll
  for (int j = 0; j < 4; ++j) b_[j] = bias[col0 + (wc << 6) + (j << 4) + ql];
#pragma unroll
  for (int i = 0; i < 4; ++i)
#pragma unroll
    for (int j = 0; j < 4; ++j)
#pragma unroll
      for (int r = 0; r < 4; ++r) {
        const int row = row0 + (wr << 6) + (i << 4) + (u << 2) + r;
        const int col = col0 + (wc << 6) + (j << 4) + ql;
        Cf[(size_t)row * Nc + col] =
            acc[i][j][r] + b_[j] + bf2f(res[(size_t)row * Nc + col]);
      }
}

// ---------------------------------------------------------------- MFMA GEMM wide (QKV, FF1)
// BM=128, BN=256, 512 thr; BK=32 double-buffered with EXPLICIT vmcnt(0) before barriers.
template <int ACT, int OUTM>
__global__ __launch_bounds__(512) void mgemm_w(const u16* __restrict__ A,
                                               const u16* __restrict__ Bt,
                                               const float* __restrict__ bias,
                                               u16* __restrict__ Cb,
                                               u16* __restrict__ Vt,
                                               int K, int Nc) {
  __shared__ u16 s_all[24576];  // [2][ A 4096 | B 8192 ]; sC[128][136] alias
  const int t = threadIdx.x;
  const int row0 = blockIdx.x << 7;
  const int col0 = blockIdx.y << 8;
  const int lane = t & 63, w = t >> 6;
  const int ql = lane & 15, u = lane >> 4;
  const int wr = w >> 2, wc = w & 3;

  f32x4 acc[4][4];
#pragma unroll
  for (int i = 0; i < 4; ++i)
#pragma unroll
    for (int j = 0; j < 4; ++j) acc[i][j] = (f32x4){0.f, 0.f, 0.f, 0.f};

  const u16* Ab = A + (size_t)row0 * K;
  const u16* Bb = Bt + (size_t)col0 * K;

  auto stage = [&](int c, int k0) {
    u16* bufA = s_all + c * 12288;
    u16* bufB = bufA + 4096;
    {  // A: 512 granules, 1/thread
      const int row = t >> 2;
      const int cs = (t & 3) ^ (row & 3);
      __builtin_amdgcn_global_load_lds(
          (const AS1 u32*)(Ab + (size_t)row * K + k0 + (cs << 3)),
          (AS3 u32*)(bufA + (t << 3)), 16, 0, 0);
    }
#pragma unroll
    for (int it = 0; it < 2; ++it) {  // B: 1024 granules, 2/thread
      const int idx = (it << 9) + t;
      const int row = idx >> 2;
      const int cs = (idx & 3) ^ (row & 3);
      __builtin_amdgcn_global_load_lds(
          (const AS1 u32*)(Bb + (size_t)row * K + k0 + (cs << 3)),
          (AS3 u32*)(bufB + (idx << 3)), 16, 0, 0);
    }
  };

  stage(0, 0);
  VMCNT0();
  __syncthreads();
  int cur = 0;
  for (int k0 = 0; k0 < K; k0 += 32, cur ^= 1) {
    if (k0 + 32 < K) stage(cur ^ 1, k0 + 32);
    const u16* sA = s_all + cur * 12288;
    const u16* sB = sA + 4096;
    s16x8 aF[4], bF[4];
#pragma unroll
    for (int i = 0; i < 4; ++i) {
      const int ra = (wr << 6) + (i << 4) + ql;
      aF[i] = *reinterpret_cast<const s16x8*>(sA + (ra << 5) + ((u ^ (ra & 3)) << 3));
      const int rb = (wc << 6) + (i << 4) + ql;
      bF[i] = *reinterpret_cast<const s16x8*>(sB + (rb << 5) + ((u ^ (rb & 3)) << 3));
    }
#pragma unroll
    for (int i = 0; i < 4; ++i)
#pragma unroll
      for (int j = 0; j < 4; ++j)
        acc[i][j] = __builtin_amdgcn_mfma_f32_16x16x32_bf16(aF[i], bF[j], acc[i][j], 0, 0, 0);
    VMCNT0();        // prefetch landed before any wave crosses the barrier
    __syncthreads();
  }

  float b_[4];
#pragma unroll
  for (int j = 0; j < 4; ++j) b_[j] = bias[col0 + (wc << 6) + (j << 4) + ql];

  if (OUTM == 2 && col0 >= 512) {  // V -> transposed vt[(g*8+h)][d][node]
    const int g = row0 >> 9;
    const int key0 = (row0 & 511) + (wr << 6);
#pragma unroll
    for (int i = 0; i < 4; ++i)
#pragma unroll
      for (int j = 0; j < 4; ++j) {
        const int c = (wc << 6) + (j << 4) + ql;
        const int hh = c >> 5, d = c & 31;
        ushort4 pk;
        pk.x = f2bf(acc[i][j][0] + b_[j]);
        pk.y = f2bf(acc[i][j][1] + b_[j]);
        pk.z = f2bf(acc[i][j][2] + b_[j]);
        pk.w = f2bf(acc[i][j][3] + b_[j]);
        *reinterpret_cast<ushort4*>(Vt + ((((size_t)g << 3) + hh) << 14) + d * 512 +
                                    key0 + (i << 4) + (u << 2)) = pk;
      }
    return;
  }

  const int ncb = (OUTM == 2) ? 512 : Nc;
  u16* sC = s_all;
#pragma unroll
  for (int halfc = 0; halfc < 2; ++halfc) {
    __syncthreads();
    if ((wc >> 1) == halfc) {
      const int wcl = wc & 1;
#pragma unroll
      for (int i = 0; i < 4; ++i)
#pragma unroll
        for (int j = 0; j < 4; ++j)
#pragma unroll
          for (int r = 0; r < 4; ++r) {
            float v = acc[i][j][r] + b_[j];
            if (ACT) v = fmaxf(v, 0.f);
            const int row = (wr << 6) + (i << 4) + (u << 2) + r;
            const int col = (wcl << 6) + (j << 4) + ql;
            sC[row * 136 + col] = f2bf(v);
          }
    }
    __syncthreads();
#pragma unroll
    for (int it = 0; it < 4; ++it) {
      const int idx = (it << 9) + t;
      const int row = idx >> 4, gc = idx & 15;
      *reinterpret_cast<s16x8*>(Cb + (size_t)(row0 + row) * ncb + col0 + (halfc << 7) + (gc << 3)) =
          *reinterpret_cast<const s16x8*>(sC + row * 136 + (gc << 3));
    }
  }
}

// ---------------------------------------------------------------- Attention v10b
// Multiplicative bias; 2 barriers; PV dual accumulation chains; direct bf16 x1 store.
__global__ __launch_bounds__(256) void attn_kernel(
    const u16* __restrict__ qk, const u16* __restrict__ vt,
    const u32* __restrict__ rec_id, const uint4* __restrict__ rec_ew,
    const u32* __restrict__ cnt, const u32* __restrict__ amask,
    const float* __restrict__ relpos,
    const float* __restrict__ x, u16* __restrict__ x1b) {
  extern __shared__ u32 smem_u[];
  u16* s_p = (u16*)smem_u;                    // [32][512] bf16 (swizzled)
  float* s_ds = (float*)(smem_u + 8192);      // [32] scatter delta sums
  float* s_ws = (float*)(smem_u + 8224);      // [4][2][16] per-wave base sums

  const int braw = blockIdx.x;
  const int b = ((braw & 7) << 9) + (braw >> 3);  // XCD swizzle (4096 % 8 == 0)
  const int qt = b & 15, h = (b >> 4) & 7, g = b >> 7;
  const int t = threadIdx.x;
  const int n0 = (g << 9) + (qt << 5);
  const int lane = t & 63, w = t >> 6;
  const int ql = lane & 15, u = lane >> 4;

  if (t < 32) s_ds[t] = 0.0f;  // first used after barrier #1

  // ---- prefetch scatter records (avg 2/lane; overflow handled in-loop)
  const int bkt = (g << 4) | qt;
  const u32 cn = cnt[(bkt << 2) + w];
  const int nrec = cn > 256u ? 256 : (int)cn;
  const u32* ridb = rec_id + (bkt << 10) + (w << 8);
  const u32* rewb = (const u32*)(rec_ew + ((size_t)bkt << 10) + (w << 8)) + (h >> 1);
  u32 pid0 = 0, pwd0 = 0, pid1 = 0, pwd1 = 0;
  if (lane < nrec)      { pid0 = ridb[lane];      pwd0 = rewb[(size_t)lane << 2]; }
  if (lane + 64 < nrec) { pid1 = ridb[lane + 64]; pwd1 = rewb[(size_t)(lane + 64) << 2]; }

  // ---- PV-role residual prefetch (epilogue fused into PV)
  const int wqv = w & 1, wdv = w >> 1;
  const int qv = (wqv << 4) + ql;
  const size_t oiv = (size_t)(n0 + qv) * D_ + (h << 5) + (wdv << 4) + (u << 2);
  const f32x4 xvv = *reinterpret_cast<const f32x4*>(x + oiv);

  // ---- prefetch Q (2) + K (8) fragments
  s16x8 qf8[2], kf8[8];
#pragma unroll
  for (int qf = 0; qf < 2; ++qf)
    qf8[qf] = *reinterpret_cast<const s16x8*>(
        qk + (size_t)(n0 + (qf << 4) + ql) * 512 + (h << 5) + (u << 3));
#pragma unroll
  for (int kf = 0; kf < 8; ++kf)
    kf8[kf] = *reinterpret_cast<const s16x8*>(
        qk + (size_t)((g << 9) + (w << 7) + (kf << 4) + ql) * 512 + 256 + (h << 5) + (u << 3));

  // ---- QK^T (swapped): S^T[key][q]; 16 MFMAs register-only
  f32x4 acc[8][2];
#pragma unroll
  for (int kf = 0; kf < 8; ++kf)
#pragma unroll
    for (int qf = 0; qf < 2; ++qf) acc[kf][qf] = (f32x4){0.f, 0.f, 0.f, 0.f};
  __builtin_amdgcn_s_setprio(1);
#pragma unroll
  for (int kf = 0; kf < 8; ++kf)
#pragma unroll
    for (int qf = 0; qf < 2; ++qf)
      acc[kf][qf] = __builtin_amdgcn_mfma_f32_16x16x32_bf16(kf8[kf], qf8[qf], acc[kf][qf], 0, 0, 0);
  __builtin_amdgcn_s_setprio(0);

  {  // ---- exp (no max; v_exp with folded scale*log2e) + P pack (cvt_pk) + per-wave sums
    const float CF = 0.25503531490029224f;  // (1/sqrt(32)) * log2(e)
    float sum[2] = {0.f, 0.f};
#pragma unroll
    for (int kf = 0; kf < 8; ++kf) {
#pragma unroll
      for (int qf = 0; qf < 2; ++qf) {
        const int q = (qf << 4) + ql;
        float e[4];
#pragma unroll
        for (int r = 0; r < 4; ++r) {
          const float xx = acc[kf][qf][r] * CF;
          asm("v_exp_f32 %0, %1" : "=v"(e[r]) : "v"(xx));
          sum[qf] += e[r];
        }
        uint2 pw;
        asm("v_cvt_pk_bf16_f32 %0, %1, %2" : "=v"(pw.x) : "v"(e[0]), "v"(e[1]));
        asm("v_cvt_pk_bf16_f32 %0, %1, %2" : "=v"(pw.y) : "v"(e[2]), "v"(e[3]));
        const int kl0 = (w << 7) + (kf << 4) + (u << 2);
        const int gran = kl0 >> 3;
        *reinterpret_cast<uint2*>(s_p + (q << 9) + ((gran ^ (q & 7)) << 3) + (kl0 & 7)) = pw;
      }
    }
#pragma unroll
    for (int qf = 0; qf < 2; ++qf) {
      sum[qf] += __shfl_xor(sum[qf], 16);
      sum[qf] += __shfl_xor(sum[qf], 32);
      if (lane < 16) s_ws[(w << 5) + (qf << 4) + ql] = sum[qf];
    }
  }
  __syncthreads();  // #1: P + s_ws + s_ds-zero visible

  {  // ---- sparse edge pass: P[q][k] *= f, s_ds[q] += P_old*(f-1). Wave w = shard w.
#pragma unroll
    for (int pi = 0; pi < 2; ++pi) {
      const bool valid = (pi == 0) ? (lane < nrec) : (lane + 64 < nrec);
      if (valid) {
        const u32 id = (pi == 0) ? pid0 : pid1;
        const u32 wrd = (pi == 0) ? pwd0 : pwd1;
        const float f = h2f((h & 1) ? (wrd >> 16) : (wrd & 0xffffu));
        const int q = id & 31, k = (int)(id >> 5);
        const int idx16 = (q << 9) + (((k >> 3) ^ (q & 7)) << 3) + (k & 7);
        u32* addr = smem_u + (idx16 >> 1);
        const int sh = (idx16 & 1) << 4;
        u32 old = *addr;
        float pv;
        while (true) {
          pv = bf2f((old >> sh) & 0xffffu);
          const u32 nw = (old & ~(0xffffu << sh)) | ((u32)f2bf(pv * f) << sh);
          const u32 got = atomicCAS(addr, old, nw);
          if (got == old) break;
          old = got;
        }
        atomicAdd(&s_ds[q], pv * (f - 1.0f));
      }
    }
    for (int i = lane + 128; i < nrec; i += 64) {  // rare overflow tail
      const u32 id = ridb[i];
      const u32 wrd = rewb[(size_t)i << 2];
      const float f = h2f((h & 1) ? (wrd >> 16) : (wrd & 0xffffu));
      const int q = id & 31, k = (int)(id >> 5);
      const int idx16 = (q << 9) + (((k >> 3) ^ (q & 7)) << 3) + (k & 7);
      u32* addr = smem_u + (idx16 >> 1);
      const int sh = (idx16 & 1) << 4;
      u32 old = *addr;
      float pv;
      while (true) {
        pv = bf2f((old >> sh) & 0xffffu);
        const u32 nw = (old & ~(0xffffu << sh)) | ((u32)f2bf(pv * f) << sh);
        const u32 got = atomicCAS(addr, old, nw);
        if (got == old) break;
        old = got;
      }
      atomicAdd(&s_ds[q], pv * (f - 1.0f));
    }
    if (g == 0) {  // rel_pos: P *= exp(rp) over deduped adjacency bits
      const float frp = __expf(relpos[h]);
      const float fm1 = frp - 1.0f;
#pragma unroll
      for (int wi = 0; wi < 2; ++wi) {
        const int widx = t + (wi << 8);
        const int q = widx >> 4, w16 = widx & 15;
        u32 m = amask[(((qt << 5) + q) << 4) + w16];
        while (m) {
          const int bit = __ffs(m) - 1;
          m &= m - 1;
          const int k = (w16 << 5) + bit;
          const int idx16 = (q << 9) + (((k >> 3) ^ (q & 7)) << 3) + (k & 7);
          u32* addr = smem_u + (idx16 >> 1);
          const int sh = (idx16 & 1) << 4;
          u32 old = *addr;
          float pv;
          while (true) {
            pv = bf2f((old >> sh) & 0xffffu);
            const u32 nw = (old & ~(0xffffu << sh)) | ((u32)f2bf(pv * frp) << sh);
            const u32 got = atomicCAS(addr, old, nw);
            if (got == old) break;
            old = got;
          }
          atomicAdd(&s_ds[q], pv * fm1);
        }
      }
    }
  }
  __syncthreads();  // #2: corrected P + delta sums visible

  {  // ---- PV (dual chains) + fused epilogue: direct bf16 store of x1
    const u16* vtb = vt + ((((size_t)g << 3) + h) << 14) + (size_t)((wdv << 4) + ql) * 512;
    f32x4 o0 = (f32x4){0.f, 0.f, 0.f, 0.f};
    f32x4 o1 = (f32x4){0.f, 0.f, 0.f, 0.f};
    __builtin_amdgcn_s_setprio(1);
#pragma unroll
    for (int ks = 0; ks < 16; ks += 2) {
      const s16x8 va0 = *reinterpret_cast<const s16x8*>(vtb + (ks << 5) + (u << 3));
      const int g0 = (ks << 2) + u;
      const s16x8 pb0 = *reinterpret_cast<const s16x8*>(s_p + (qv << 9) + ((g0 ^ (qv & 7)) << 3));
      o0 = __builtin_amdgcn_mfma_f32_16x16x32_bf16(va0, pb0, o0, 0, 0, 0);
      const s16x8 va1 = *reinterpret_cast<const s16x8*>(vtb + ((ks + 1) << 5) + (u << 3));
      const int g1 = ((ks + 1) << 2) + u;
      const s16x8 pb1 = *reinterpret_cast<const s16x8*>(s_p + (qv << 9) + ((g1 ^ (qv & 7)) << 3));
      o1 = __builtin_amdgcn_mfma_f32_16x16x32_bf16(va1, pb1, o1, 0, 0, 0);
    }
    __builtin_amdgcn_s_setprio(0);
    const float base = s_ws[qv] + s_ws[32 + qv] + s_ws[64 + qv] + s_ws[96 + qv];
    const float invS = 1.0f / (base + s_ds[qv]);
    ushort4 st;
    st.x = f2bf((o0[0] + o1[0]) * invS + xvv[0]);
    st.y = f2bf((o0[1] + o1[1]) * invS + xvv[1]);
    st.z = f2bf((o0[2] + o1[2]) * invS + xvv[2]);
    st.w = f2bf((o0[3] + o1[3]) * invS + xvv[3]);
    *reinterpret_cast<ushort4*>(x1b + oiv) = st;
  }
}

// ---------------------------------------------------------------- launch
extern "C" void kernel_launch(void* const* d_in, const int* in_sizes, int n_in,
                              void* d_out, int out_size, void* d_ws, size_t ws_size,
                              hipStream_t stream) {
  const float* x    = (const float*)d_in[0];
  const int*   ei   = (const int*)d_in[1];
  const float* ea   = (const float*)d_in[2];
  const float* ln1g = (const float*)d_in[3];
  const float* ln1b = (const float*)d_in[4];
  const float* wq   = (const float*)d_in[5];
  const float* bq   = (const float*)d_in[6];
  const float* wk   = (const float*)d_in[7];
  const float* bk   = (const float*)d_in[8];
  const float* wv   = (const float*)d_in[9];
  const float* bv   = (const float*)d_in[10];
  const float* wep  = (const float*)d_in[11];
  const float* bep  = (const float*)d_in[12];
  const float* weg  = (const float*)d_in[13];
  const float* beg  = (const float*)d_in[14];
  const float* rp   = (const float*)d_in[15];
  const float* w1   = (const float*)d_in[16];
  const float* b1   = (const float*)d_in[17];
  const float* w2   = (const float*)d_in[18];
  const float* b2   = (const float*)d_in[19];
  const float* ln2g = (const float*)d_in[20];
  const float* ln2b = (const float*)d_in[21];
  float* out = (float*)d_out;

  float* ws = (float*)d_ws;
  const size_t M1 = 1048576;
  u16* xn   = (u16*)ws;                       // [16384][256] bf16
  u16* qk   = (u16*)(ws + 2 * M1);            // [16384][512] bf16 (Q|K)
  u16* vt   = (u16*)(ws + 6 * M1);            // [256][32][512] bf16
  u16* f1   = (u16*)ws;                       // [16384][1024] bf16 (alias, post-attn)
  u16* x1b  = (u16*)(ws + 8 * M1);            // [16384][256] bf16
  u16* h2   = (u16*)(ws + 12 * M1);           // bf16
  u16* wqkvt = (u16*)(ws + 14 * M1);          // [768][256] bf16
  u16* w1t  = (u16*)(ws + 14 * M1 + 262144);  // [1024][256] bf16
  u16* w2t  = (u16*)(ws + 14 * M1 + 524288);  // [256][1024] bf16
  float* bqkv = ws + 14 * M1 + 786432;        // [768] f32
  u32* cnt  = (u32*)(ws + 14 * M1 + 787456);  // [2048] u32
  u32* amask = cnt + 2048;                    // [512][16] u32 (32KB)
  u32* rec_id = (u32*)(ws + 15 * M1);         // [512*1024] u32 (2MB)
  uint4* rec_ew = (uint4*)(ws + 16 * M1);     // [512*1024] uint4 (8MB)

  // 0. zero cnt+amask, then fused prep (weights | bqkv | edge prep | LN1)
  hipMemsetAsync(cnt, 0, (2048 + 8192) * sizeof(u32), stream);
  prep_all<<<dim3(5825), dim3(256), 0, stream>>>(
      wq, wk, wv, w1, w2, wqkvt, w1t, w2t, bq, bk, bv, bqkv,
      ei, ea, wep, bep, weg, beg, cnt, rec_id, rec_ew, amask, x, ln1g, ln1b, xn);
  // 1. fused QKV GEMM (wide, dbuf): Q,K -> qk row-major; V -> vt transposed
  mgemm_w<0, 2><<<dim3(128, 3), 512, 0, stream>>>(xn, wqkvt, bqkv, qk, vt, 256, 768);
  // 2. attention (+x residual) -> x1b bf16
  const int smem_attn = 8352 * 4;  // 33,408 B -> 4 WG/CU
  (void)hipFuncSetAttribute(reinterpret_cast<const void*>(attn_kernel),
                            hipFuncAttributeMaxDynamicSharedMemorySize, smem_attn);
  attn_kernel<<<dim3(G_ * H_ * 16), 256, smem_attn, stream>>>(qk, vt, rec_id, rec_ew, cnt,
                                                              amask, rp, x, x1b);
  // 3. LN2 (bf16 in) -> bf16
  ln_kernel_b<<<dim3(N_ / 4), dim3(256), 0, stream>>>(x1b, ln2g, ln2b, h2);
  // 4. FF1 (relu, wide, dbuf) -> f1 bf16
  mgemm_w<1, 0><<<dim3(128, 4), 512, 0, stream>>>(h2, w1t, b1, f1, nullptr, 256, 1024);
  // 5. FF2 (+bias +x1b residual, narrow, dbuf) -> out f32
  mgemm_res<<<dim3(128, 2), 256, 0, stream>>>(f1, w2t, b2, x1b, out, 1024, 256);
}

// Round 15
// 154.880 us; speedup vs baseline: 1.6153x; 1.0897x over previous
//
#include <hip/hip_runtime.h>
#include <math.h>

#define G_   32
#define NPG_ 512
#define N_   16384
#define E_   262144
#define D_   256
#define H_   8
#define FF_  1024

typedef unsigned int u32;
typedef unsigned short u16;
typedef __attribute__((ext_vector_type(8))) short s16x8;   // 8 x bf16
typedef __attribute__((ext_vector_type(4))) float f32x4;

#define AS1 __attribute__((address_space(1)))
#define AS3 __attribute__((address_space(3)))
#define VMCNT0() asm volatile("s_waitcnt vmcnt(0)" ::: "memory")

__device__ inline u16 f2bf(float f) {
  u32 u = __float_as_uint(f);
  u += 0x7fffu + ((u >> 16) & 1u);
  return (u16)(u >> 16);
}
__device__ inline float bf2f(u32 hi16) { return __uint_as_float(hi16 << 16); }
__device__ inline u16 f2h(float f) {
  union { _Float16 h; u16 u; } c; c.h = (_Float16)f; return c.u;
}
__device__ inline float h2f(u32 bits) {
  union { u16 u; _Float16 h; } c; c.u = (u16)bits; return (float)c.h;
}

// ---------------------------------------------------------------- LayerNorm (f32 in, bf16 out)
__device__ inline void ln_row(const float* __restrict__ in, const float* __restrict__ gw,
                              const float* __restrict__ bw, u16* __restrict__ out,
                              int row, int lane) {
  const float4 v = reinterpret_cast<const float4*>(in + (size_t)row * D_)[lane];
  float s = v.x + v.y + v.z + v.w;
#pragma unroll
  for (int off = 32; off > 0; off >>= 1) s += __shfl_xor(s, off);
  const float m = s * (1.0f / D_);
  const float dx = v.x - m, dy = v.y - m, dz = v.z - m, dw = v.w - m;
  float s2 = dx * dx + dy * dy + dz * dz + dw * dw;
#pragma unroll
  for (int off = 32; off > 0; off >>= 1) s2 += __shfl_xor(s2, off);
  const float inv = rsqrtf(s2 * (1.0f / D_) + 1e-5f);
  const float4 g4 = reinterpret_cast<const float4*>(gw)[lane];
  const float4 b4 = reinterpret_cast<const float4*>(bw)[lane];
  ushort4 o;
  o.x = f2bf(dx * inv * g4.x + b4.x);
  o.y = f2bf(dy * inv * g4.y + b4.y);
  o.z = f2bf(dz * inv * g4.z + b4.z);
  o.w = f2bf(dw * inv * g4.w + b4.w);
  *reinterpret_cast<ushort4*>(out + (size_t)row * D_ + (lane << 2)) = o;
}

// ---------------------------------------------------------------- LayerNorm (bf16 in, bf16 out)
__global__ __launch_bounds__(256) void ln_kernel_b(const u16* __restrict__ in,
                                                   const float* __restrict__ gw,
                                                   const float* __restrict__ bw,
                                                   u16* __restrict__ out) {
  const int lane = threadIdx.x & 63;
  const int row = (blockIdx.x << 2) + (threadIdx.x >> 6);
  const ushort4 v4 = *reinterpret_cast<const ushort4*>(in + (size_t)row * D_ + (lane << 2));
  const float vx = bf2f(v4.x), vy = bf2f(v4.y), vz = bf2f(v4.z), vw = bf2f(v4.w);
  float s = vx + vy + vz + vw;
#pragma unroll
  for (int off = 32; off > 0; off >>= 1) s += __shfl_xor(s, off);
  const float m = s * (1.0f / D_);
  const float dx = vx - m, dy = vy - m, dz = vz - m, dw = vw - m;
  float s2 = dx * dx + dy * dy + dz * dz + dw * dw;
#pragma unroll
  for (int off = 32; off > 0; off >>= 1) s2 += __shfl_xor(s2, off);
  const float inv = rsqrtf(s2 * (1.0f / D_) + 1e-5f);
  const float4 g4 = reinterpret_cast<const float4*>(gw)[lane];
  const float4 b4 = reinterpret_cast<const float4*>(bw)[lane];
  ushort4 o;
  o.x = f2bf(dx * inv * g4.x + b4.x);
  o.y = f2bf(dy * inv * g4.y + b4.y);
  o.z = f2bf(dz * inv * g4.z + b4.z);
  o.w = f2bf(dw * inv * g4.w + b4.w);
  *reinterpret_cast<ushort4*>(out + (size_t)row * D_ + (lane << 2)) = o;
}

// ---------------------------------------------------------------- fused prep
__global__ __launch_bounds__(256) void prep_all(
    const float* __restrict__ wq, const float* __restrict__ wk,
    const float* __restrict__ wv, const float* __restrict__ w1,
    const float* __restrict__ w2,
    u16* __restrict__ wqkvt, u16* __restrict__ w1t, u16* __restrict__ w2t,
    const float* __restrict__ bq, const float* __restrict__ bk,
    const float* __restrict__ bv, float* __restrict__ bqkv,
    const int* __restrict__ ei, const float* __restrict__ ea,
    const float* __restrict__ wep, const float* __restrict__ bep,
    const float* __restrict__ weg, const float* __restrict__ beg,
    u32* __restrict__ cnt, u32* __restrict__ rec_id, uint4* __restrict__ rec_ew,
    u32* __restrict__ amask,
    const float* __restrict__ x, const float* __restrict__ ln1g,
    const float* __restrict__ ln1b, u16* __restrict__ xn) {
  const int bid = blockIdx.x;
  const int t = threadIdx.x;
  if (bid >= 1729) {  // LN1
    ln_row(x, ln1g, ln1b, xn, ((bid - 1729) << 2) + (t >> 6), t & 63);
    return;
  }
  if (bid >= 705) {  // edge prep
    const int e = (bid - 705) * 256 + t;
    const int ls = ei[e] & 511;
    const int ld = ei[E_ + e] & 511;
    if (e < 8192)  // graph 0 adjacency (deduped by OR)
      atomicOr(&amask[(ls << 4) + (ld >> 5)], 1u << (ld & 31));
    const int bk = ((e >> 13) << 4) | (ls >> 5);
    const int sh = t & 3;
    const u32 pos = atomicAdd(&cnt[(bk << 2) + sh], 1u);
    if (pos < 256u) {
      const float2 a2 = reinterpret_cast<const float2*>(ea)[e];
      u32 wds[4];
#pragma unroll
      for (int hp = 0; hp < 4; ++hp) {
        float f2[2];
#pragma unroll
        for (int s = 0; s < 2; ++s) {
          const int h = hp * 2 + s;
          const float pre = a2.x * wep[h] + a2.y * wep[H_ + h] + bep[h];
          const float gat = a2.x * weg[h] + a2.y * weg[H_ + h] + beg[h];
          f2[s] = __expf(pre / (1.0f + __expf(-gat)));  // exp(ew): multiplicative factor
        }
        wds[hp] = (u32)f2h(f2[0]) | ((u32)f2h(f2[1]) << 16);
      }
      const int slot = (bk << 10) + (sh << 8) + (int)pos;
      rec_id[slot] = (u32)((ls & 31) | (ld << 5));
      rec_ew[slot] = make_uint4(wds[0], wds[1], wds[2], wds[3]);
    }
    return;
  }
  if (bid == 704) {  // bias pack
    for (int i = t; i < 768; i += 256)
      bqkv[i] = (i < 256) ? bq[i] : (i < 512 ? bk[i - 256] : bv[i - 512]);
    return;
  }
  // weight transpose
  const float* W; u16* Wt; int K, Nc, ro, local;
  if (bid < 64)       { W = wq; Wt = wqkvt; K = 256;  Nc = 256;  ro = 0;   local = bid; }
  else if (bid < 128) { W = wk; Wt = wqkvt; K = 256;  Nc = 256;  ro = 256; local = bid - 64; }
  else if (bid < 192) { W = wv; Wt = wqkvt; K = 256;  Nc = 256;  ro = 512; local = bid - 128; }
  else if (bid < 448) { W = w1; Wt = w1t;   K = 256;  Nc = 1024; ro = 0;   local = bid - 192; }
  else                { W = w2; Wt = w2t;   K = 1024; Nc = 256;  ro = 0;   local = bid - 448; }
  const int tx = t & 31, ty = t >> 5;
  const int tn = Nc >> 5;
  const int n0 = (local % tn) << 5, k0 = (local / tn) << 5;
  __shared__ float tl[32][33];
#pragma unroll
  for (int i = 0; i < 4; ++i)
    tl[ty + (i << 3)][tx] = W[(size_t)(k0 + ty + (i << 3)) * Nc + n0 + tx];
  __syncthreads();
#pragma unroll
  for (int i = 0; i < 4; ++i)
    Wt[(size_t)(ro + n0 + ty + (i << 3)) * K + k0 + tx] = f2bf(tl[tx][ty + (i << 3)]);
}

// ---------------------------------------------------------------- MFMA GEMM narrow (FF2)
__global__ __launch_bounds__(256) void mgemm_res(const u16* __restrict__ A,
                                                 const u16* __restrict__ Bt,
                                                 const float* __restrict__ bias,
                                                 const u16* __restrict__ res,
                                                 float* __restrict__ Cf,
                                                 int K, int Nc) {
  __shared__ u16 s_all[32768];  // [2][ A 8192 | B 8192 ]
  const int t = threadIdx.x;
  const int row0 = blockIdx.x << 7;
  const int col0 = blockIdx.y << 7;
  const int lane = t & 63, w = t >> 6;
  const int ql = lane & 15, u = lane >> 4;
  const int wr = w >> 1, wc = w & 1;

  f32x4 acc[4][4];
#pragma unroll
  for (int i = 0; i < 4; ++i)
#pragma unroll
    for (int j = 0; j < 4; ++j) acc[i][j] = (f32x4){0.f, 0.f, 0.f, 0.f};

  const u16* Ab = A + (size_t)row0 * K;
  const u16* Bb = Bt + (size_t)col0 * K;

  auto stage = [&](int c, int k0) {
    u16* bufA = s_all + c * 16384;
    u16* bufB = bufA + 8192;
#pragma unroll
    for (int it = 0; it < 4; ++it) {
      const int idx = (it << 8) + t;
      const int row = idx >> 3;
      const int gcs = (idx & 7) ^ (row & 7);
      __builtin_amdgcn_global_load_lds(
          (const AS1 u32*)(Ab + (size_t)row * K + k0 + (gcs << 3)),
          (AS3 u32*)(bufA + (idx << 3)), 16, 0, 0);
    }
#pragma unroll
    for (int it = 0; it < 4; ++it) {
      const int idx = (it << 8) + t;
      const int row = idx >> 3;
      const int gcs = (idx & 7) ^ (row & 7);
      __builtin_amdgcn_global_load_lds(
          (const AS1 u32*)(Bb + (size_t)row * K + k0 + (gcs << 3)),
          (AS3 u32*)(bufB + (idx << 3)), 16, 0, 0);
    }
  };

  stage(0, 0);
  VMCNT0();
  __syncthreads();
  int cur = 0;
  for (int k0 = 0; k0 < K; k0 += 64, cur ^= 1) {
    if (k0 + 64 < K) stage(cur ^ 1, k0 + 64);
    const u16* sA = s_all + cur * 16384;
    const u16* sB = sA + 8192;
#pragma unroll
    for (int ks = 0; ks < 2; ++ks) {
      const int gk = (ks << 2) + u;
      s16x8 aF[4], bF[4];
#pragma unroll
      for (int i = 0; i < 4; ++i) {
        const int ra = (wr << 6) + (i << 4) + ql;
        aF[i] = *reinterpret_cast<const s16x8*>(sA + ra * 64 + ((gk ^ (ra & 7)) << 3));
        const int rb = (wc << 6) + (i << 4) + ql;
        bF[i] = *reinterpret_cast<const s16x8*>(sB + rb * 64 + ((gk ^ (rb & 7)) << 3));
      }
#pragma unroll
      for (int i = 0; i < 4; ++i)
#pragma unroll
        for (int j = 0; j < 4; ++j)
          acc[i][j] = __builtin_amdgcn_mfma_f32_16x16x32_bf16(aF[i], bF[j], acc[i][j], 0, 0, 0);
    }
    VMCNT0();        // prefetch landed before any wave crosses the barrier
    __syncthreads();
  }

  float b_[4];
#pragma unroll
  for (int j = 0; j < 4; ++j) b_[j] = bias[col0 + (wc << 6) + (j << 4) + ql];
#pragma unroll
  for (int i = 0; i < 4; ++i)
#pragma unroll
    for (int j = 0; j < 4; ++j)
#pragma unroll
      for (int r = 0; r < 4; ++r) {
        const int row = row0 + (wr << 6) + (i << 4) + (u << 2) + r;
        const int col = col0 + (wc << 6) + (j << 4) + ql;
        Cf[(size_t)row * Nc + col] =
            acc[i][j][r] + b_[j] + bf2f(res[(size_t)row * Nc + col]);
      }
}

// ---------------------------------------------------------------- MFMA GEMM wide (QKV, FF1)
template <int ACT, int OUTM>
__global__ __launch_bounds__(512) void mgemm_w(const u16* __restrict__ A,
                                               const u16* __restrict__ Bt,
                                               const float* __restrict__ bias,
                                               u16* __restrict__ Cb,
                                               u16* __restrict__ Vt,
                                               int K, int Nc) {
  __shared__ u16 s_all[24576];  // [2][ A 4096 | B 8192 ]; sC[128][136] alias
  const int t = threadIdx.x;
  const int row0 = blockIdx.x << 7;
  const int col0 = blockIdx.y << 8;
  const int lane = t & 63, w = t >> 6;
  const int ql = lane & 15, u = lane >> 4;
  const int wr = w >> 2, wc = w & 3;

  f32x4 acc[4][4];
#pragma unroll
  for (int i = 0; i < 4; ++i)
#pragma unroll
    for (int j = 0; j < 4; ++j) acc[i][j] = (f32x4){0.f, 0.f, 0.f, 0.f};

  const u16* Ab = A + (size_t)row0 * K;
  const u16* Bb = Bt + (size_t)col0 * K;

  auto stage = [&](int c, int k0) {
    u16* bufA = s_all + c * 12288;
    u16* bufB = bufA + 4096;
    {  // A: 512 granules, 1/thread
      const int row = t >> 2;
      const int cs = (t & 3) ^ (row & 3);
      __builtin_amdgcn_global_load_lds(
          (const AS1 u32*)(Ab + (size_t)row * K + k0 + (cs << 3)),
          (AS3 u32*)(bufA + (t << 3)), 16, 0, 0);
    }
#pragma unroll
    for (int it = 0; it < 2; ++it) {  // B: 1024 granules, 2/thread
      const int idx = (it << 9) + t;
      const int row = idx >> 2;
      const int cs = (idx & 3) ^ (row & 3);
      __builtin_amdgcn_global_load_lds(
          (const AS1 u32*)(Bb + (size_t)row * K + k0 + (cs << 3)),
          (AS3 u32*)(bufB + (idx << 3)), 16, 0, 0);
    }
  };

  stage(0, 0);
  VMCNT0();
  __syncthreads();
  int cur = 0;
  for (int k0 = 0; k0 < K; k0 += 32, cur ^= 1) {
    if (k0 + 32 < K) stage(cur ^ 1, k0 + 32);
    const u16* sA = s_all + cur * 12288;
    const u16* sB = sA + 4096;
    s16x8 aF[4], bF[4];
#pragma unroll
    for (int i = 0; i < 4; ++i) {
      const int ra = (wr << 6) + (i << 4) + ql;
      aF[i] = *reinterpret_cast<const s16x8*>(sA + (ra << 5) + ((u ^ (ra & 3)) << 3));
      const int rb = (wc << 6) + (i << 4) + ql;
      bF[i] = *reinterpret_cast<const s16x8*>(sB + (rb << 5) + ((u ^ (rb & 3)) << 3));
    }
#pragma unroll
    for (int i = 0; i < 4; ++i)
#pragma unroll
      for (int j = 0; j < 4; ++j)
        acc[i][j] = __builtin_amdgcn_mfma_f32_16x16x32_bf16(aF[i], bF[j], acc[i][j], 0, 0, 0);
    VMCNT0();        // prefetch landed before any wave crosses the barrier
    __syncthreads();
  }

  float b_[4];
#pragma unroll
  for (int j = 0; j < 4; ++j) b_[j] = bias[col0 + (wc << 6) + (j << 4) + ql];

  if (OUTM == 2 && col0 >= 512) {  // V -> transposed vt[(g*8+h)][d][node]
    const int g = row0 >> 9;
    const int key0 = (row0 & 511) + (wr << 6);
#pragma unroll
    for (int i = 0; i < 4; ++i)
#pragma unroll
      for (int j = 0; j < 4; ++j) {
        const int c = (wc << 6) + (j << 4) + ql;
        const int hh = c >> 5, d = c & 31;
        ushort4 pk;
        pk.x = f2bf(acc[i][j][0] + b_[j]);
        pk.y = f2bf(acc[i][j][1] + b_[j]);
        pk.z = f2bf(acc[i][j][2] + b_[j]);
        pk.w = f2bf(acc[i][j][3] + b_[j]);
        *reinterpret_cast<ushort4*>(Vt + ((((size_t)g << 3) + hh) << 14) + d * 512 +
                                    key0 + (i << 4) + (u << 2)) = pk;
      }
    return;
  }

  const int ncb = (OUTM == 2) ? 512 : Nc;
  u16* sC = s_all;
#pragma unroll
  for (int halfc = 0; halfc < 2; ++halfc) {
    __syncthreads();
    if ((wc >> 1) == halfc) {
      const int wcl = wc & 1;
#pragma unroll
      for (int i = 0; i < 4; ++i)
#pragma unroll
        for (int j = 0; j < 4; ++j)
#pragma unroll
          for (int r = 0; r < 4; ++r) {
            float v = acc[i][j][r] + b_[j];
            if (ACT) v = fmaxf(v, 0.f);
            const int row = (wr << 6) + (i << 4) + (u << 2) + r;
            const int col = (wcl << 6) + (j << 4) + ql;
            sC[row * 136 + col] = f2bf(v);
          }
    }
    __syncthreads();
#pragma unroll
    for (int it = 0; it < 4; ++it) {
      const int idx = (it << 9) + t;
      const int row = idx >> 4, gc = idx & 15;
      *reinterpret_cast<s16x8*>(Cb + (size_t)(row0 + row) * ncb + col0 + (halfc << 7) + (gc << 3)) =
          *reinterpret_cast<const s16x8*>(sC + row * 136 + (gc << 3));
    }
  }
}

// ---------------------------------------------------------------- Attention v11
// Multiplicative bias; 2 barriers; row sums via ones-MFMA over FINAL P (no LDS stats).
// LDS = P[32][512] bf16 = EXACTLY 32,768 B (granule hypothesis: <=32KB -> more WG/CU).
__global__ __launch_bounds__(256, 4) void attn_kernel(
    const u16* __restrict__ qk, const u16* __restrict__ vt,
    const u32* __restrict__ rec_id, const uint4* __restrict__ rec_ew,
    const u32* __restrict__ cnt, const u32* __restrict__ amask,
    const float* __restrict__ relpos,
    const float* __restrict__ x, u16* __restrict__ x1b) {
  extern __shared__ u32 smem_u[];
  u16* s_p = (u16*)smem_u;                    // [32][512] bf16 (swizzled)

  const int braw = blockIdx.x;
  const int b = ((braw & 7) << 9) + (braw >> 3);  // XCD swizzle (4096 % 8 == 0)
  const int qt = b & 15, h = (b >> 4) & 7, g = b >> 7;
  const int t = threadIdx.x;
  const int n0 = (g << 9) + (qt << 5);
  const int lane = t & 63, w = t >> 6;
  const int ql = lane & 15, u = lane >> 4;

  // ---- prefetch scatter records (avg 2/lane; overflow handled in-loop)
  const int bkt = (g << 4) | qt;
  const u32 cn = cnt[(bkt << 2) + w];
  const int nrec = cn > 256u ? 256 : (int)cn;
  const u32* ridb = rec_id + (bkt << 10) + (w << 8);
  const u32* rewb = (const u32*)(rec_ew + ((size_t)bkt << 10) + (w << 8)) + (h >> 1);
  u32 pid0 = 0, pwd0 = 0, pid1 = 0, pwd1 = 0;
  if (lane < nrec)      { pid0 = ridb[lane];      pwd0 = rewb[(size_t)lane << 2]; }
  if (lane + 64 < nrec) { pid1 = ridb[lane + 64]; pwd1 = rewb[(size_t)(lane + 64) << 2]; }

  // ---- PV-role residual prefetch (epilogue fused into PV)
  const int wqv = w & 1, wdv = w >> 1;
  const int qv = (wqv << 4) + ql;
  const size_t oiv = (size_t)(n0 + qv) * D_ + (h << 5) + (wdv << 4) + (u << 2);
  const f32x4 xvv = *reinterpret_cast<const f32x4*>(x + oiv);

  // ---- prefetch Q (2) + K (8) fragments
  s16x8 qf8[2], kf8[8];
#pragma unroll
  for (int qf = 0; qf < 2; ++qf)
    qf8[qf] = *reinterpret_cast<const s16x8*>(
        qk + (size_t)(n0 + (qf << 4) + ql) * 512 + (h << 5) + (u << 3));
#pragma unroll
  for (int kf = 0; kf < 8; ++kf)
    kf8[kf] = *reinterpret_cast<const s16x8*>(
        qk + (size_t)((g << 9) + (w << 7) + (kf << 4) + ql) * 512 + 256 + (h << 5) + (u << 3));

  // ---- QK^T (swapped): S^T[key][q]; 16 MFMAs register-only
  f32x4 acc[8][2];
#pragma unroll
  for (int kf = 0; kf < 8; ++kf)
#pragma unroll
    for (int qf = 0; qf < 2; ++qf) acc[kf][qf] = (f32x4){0.f, 0.f, 0.f, 0.f};
  __builtin_amdgcn_s_setprio(1);
#pragma unroll
  for (int kf = 0; kf < 8; ++kf)
#pragma unroll
    for (int qf = 0; qf < 2; ++qf)
      acc[kf][qf] = __builtin_amdgcn_mfma_f32_16x16x32_bf16(kf8[kf], qf8[qf], acc[kf][qf], 0, 0, 0);
  __builtin_amdgcn_s_setprio(0);

  {  // ---- exp (no max; v_exp with folded scale*log2e) + P pack (cvt_pk); NO sum tracking
    const float CF = 0.25503531490029224f;  // (1/sqrt(32)) * log2(e)
#pragma unroll
    for (int kf = 0; kf < 8; ++kf) {
#pragma unroll
      for (int qf = 0; qf < 2; ++qf) {
        const int q = (qf << 4) + ql;
        float e[4];
#pragma unroll
        for (int r = 0; r < 4; ++r) {
          const float xx = acc[kf][qf][r] * CF;
          asm("v_exp_f32 %0, %1" : "=v"(e[r]) : "v"(xx));
        }
        uint2 pw;
        asm("v_cvt_pk_bf16_f32 %0, %1, %2" : "=v"(pw.x) : "v"(e[0]), "v"(e[1]));
        asm("v_cvt_pk_bf16_f32 %0, %1, %2" : "=v"(pw.y) : "v"(e[2]), "v"(e[3]));
        const int kl0 = (w << 7) + (kf << 4) + (u << 2);
        const int gran = kl0 >> 3;
        *reinterpret_cast<uint2*>(s_p + (q << 9) + ((gran ^ (q & 7)) << 3) + (kl0 & 7)) = pw;
      }
    }
  }
  __syncthreads();  // #1: P fully written, visible to all waves

  {  // ---- sparse edge pass: P[q][k] *= f (pure CAS, no delta tracking). Wave w = shard w.
#pragma unroll
    for (int pi = 0; pi < 2; ++pi) {
      const bool valid = (pi == 0) ? (lane < nrec) : (lane + 64 < nrec);
      if (valid) {
        const u32 id = (pi == 0) ? pid0 : pid1;
        const u32 wrd = (pi == 0) ? pwd0 : pwd1;
        const float f = h2f((h & 1) ? (wrd >> 16) : (wrd & 0xffffu));
        const int q = id & 31, k = (int)(id >> 5);
        const int idx16 = (q << 9) + (((k >> 3) ^ (q & 7)) << 3) + (k & 7);
        u32* addr = smem_u + (idx16 >> 1);
        const int sh = (idx16 & 1) << 4;
        u32 old = *addr;
        while (true) {
          const float pv = bf2f((old >> sh) & 0xffffu);
          const u32 nw = (old & ~(0xffffu << sh)) | ((u32)f2bf(pv * f) << sh);
          const u32 got = atomicCAS(addr, old, nw);
          if (got == old) break;
          old = got;
        }
      }
    }
    for (int i = lane + 128; i < nrec; i += 64) {  // rare overflow tail
      const u32 id = ridb[i];
      const u32 wrd = rewb[(size_t)i << 2];
      const float f = h2f((h & 1) ? (wrd >> 16) : (wrd & 0xffffu));
      const int q = id & 31, k = (int)(id >> 5);
      const int idx16 = (q << 9) + (((k >> 3) ^ (q & 7)) << 3) + (k & 7);
      u32* addr = smem_u + (idx16 >> 1);
      const int sh = (idx16 & 1) << 4;
      u32 old = *addr;
      while (true) {
        const float pv = bf2f((old >> sh) & 0xffffu);
        const u32 nw = (old & ~(0xffffu << sh)) | ((u32)f2bf(pv * f) << sh);
        const u32 got = atomicCAS(addr, old, nw);
        if (got == old) break;
        old = got;
      }
    }
    if (g == 0) {  // rel_pos: P *= exp(rp) over deduped adjacency bits
      const float frp = __expf(relpos[h]);
#pragma unroll
      for (int wi = 0; wi < 2; ++wi) {
        const int widx = t + (wi << 8);
        const int q = widx >> 4, w16 = widx & 15;
        u32 m = amask[(((qt << 5) + q) << 4) + w16];
        while (m) {
          const int bit = __ffs(m) - 1;
          m &= m - 1;
          const int k = (w16 << 5) + bit;
          const int idx16 = (q << 9) + (((k >> 3) ^ (q & 7)) << 3) + (k & 7);
          u32* addr = smem_u + (idx16 >> 1);
          const int sh = (idx16 & 1) << 4;
          u32 old = *addr;
          while (true) {
            const float pv = bf2f((old >> sh) & 0xffffu);
            const u32 nw = (old & ~(0xffffu << sh)) | ((u32)f2bf(pv * frp) << sh);
            const u32 got = atomicCAS(addr, old, nw);
            if (got == old) break;
            old = got;
          }
        }
      }
    }
  }
  __syncthreads();  // #2: corrected P visible

  {  // ---- PV (dual chains) + ones-MFMA row sums + fused epilogue (bf16 x1 store)
    const u16* vtb = vt + ((((size_t)g << 3) + h) << 14) + (size_t)((wdv << 4) + ql) * 512;
    union { s16x8 v; u32 uu[4]; } onu;
    onu.uu[0] = 0x3F803F80u; onu.uu[1] = 0x3F803F80u;
    onu.uu[2] = 0x3F803F80u; onu.uu[3] = 0x3F803F80u;
    const s16x8 vones = onu.v;
    f32x4 o0 = (f32x4){0.f, 0.f, 0.f, 0.f};
    f32x4 o1 = (f32x4){0.f, 0.f, 0.f, 0.f};
    f32x4 os0 = (f32x4){0.f, 0.f, 0.f, 0.f};
    f32x4 os1 = (f32x4){0.f, 0.f, 0.f, 0.f};
    __builtin_amdgcn_s_setprio(1);
#pragma unroll
    for (int ks = 0; ks < 16; ks += 2) {
      const s16x8 va0 = *reinterpret_cast<const s16x8*>(vtb + (ks << 5) + (u << 3));
      const int g0 = (ks << 2) + u;
      const s16x8 pb0 = *reinterpret_cast<const s16x8*>(s_p + (qv << 9) + ((g0 ^ (qv & 7)) << 3));
      o0 = __builtin_amdgcn_mfma_f32_16x16x32_bf16(va0, pb0, o0, 0, 0, 0);
      os0 = __builtin_amdgcn_mfma_f32_16x16x32_bf16(vones, pb0, os0, 0, 0, 0);
      const s16x8 va1 = *reinterpret_cast<const s16x8*>(vtb + ((ks + 1) << 5) + (u << 3));
      const int g1 = ((ks + 1) << 2) + u;
      const s16x8 pb1 = *reinterpret_cast<const s16x8*>(s_p + (qv << 9) + ((g1 ^ (qv & 7)) << 3));
      o1 = __builtin_amdgcn_mfma_f32_16x16x32_bf16(va1, pb1, o1, 0, 0, 0);
      os1 = __builtin_amdgcn_mfma_f32_16x16x32_bf16(vones, pb1, os1, 0, 0, 0);
    }
    __builtin_amdgcn_s_setprio(0);
    const float invS = 1.0f / (os0[0] + os1[0]);  // all rows of os identical = row sum of qv
    ushort4 st;
    st.x = f2bf((o0[0] + o1[0]) * invS + xvv[0]);
    st.y = f2bf((o0[1] + o1[1]) * invS + xvv[1]);
    st.z = f2bf((o0[2] + o1[2]) * invS + xvv[2]);
    st.w = f2bf((o0[3] + o1[3]) * invS + xvv[3]);
    *reinterpret_cast<ushort4*>(x1b + oiv) = st;
  }
}

// ---------------------------------------------------------------- launch
extern "C" void kernel_launch(void* const* d_in, const int* in_sizes, int n_in,
                              void* d_out, int out_size, void* d_ws, size_t ws_size,
                              hipStream_t stream) {
  const float* x    = (const float*)d_in[0];
  const int*   ei   = (const int*)d_in[1];
  const float* ea   = (const float*)d_in[2];
  const float* ln1g = (const float*)d_in[3];
  const float* ln1b = (const float*)d_in[4];
  const float* wq   = (const float*)d_in[5];
  const float* bq   = (const float*)d_in[6];
  const float* wk   = (const float*)d_in[7];
  const float* bk   = (const float*)d_in[8];
  const float* wv   = (const float*)d_in[9];
  const float* bv   = (const float*)d_in[10];
  const float* wep  = (const float*)d_in[11];
  const float* bep  = (const float*)d_in[12];
  const float* weg  = (const float*)d_in[13];
  const float* beg  = (const float*)d_in[14];
  const float* rp   = (const float*)d_in[15];
  const float* w1   = (const float*)d_in[16];
  const float* b1   = (const float*)d_in[17];
  const float* w2   = (const float*)d_in[18];
  const float* b2   = (const float*)d_in[19];
  const float* ln2g = (const float*)d_in[20];
  const float* ln2b = (const float*)d_in[21];
  float* out = (float*)d_out;

  float* ws = (float*)d_ws;
  const size_t M1 = 1048576;
  u16* xn   = (u16*)ws;                       // [16384][256] bf16
  u16* qk   = (u16*)(ws + 2 * M1);            // [16384][512] bf16 (Q|K)
  u16* vt   = (u16*)(ws + 6 * M1);            // [256][32][512] bf16
  u16* f1   = (u16*)ws;                       // [16384][1024] bf16 (alias, post-attn)
  u16* x1b  = (u16*)(ws + 8 * M1);            // [16384][256] bf16
  u16* h2   = (u16*)(ws + 12 * M1);           // bf16
  u16* wqkvt = (u16*)(ws + 14 * M1);          // [768][256] bf16
  u16* w1t  = (u16*)(ws + 14 * M1 + 262144);  // [1024][256] bf16
  u16* w2t  = (u16*)(ws + 14 * M1 + 524288);  // [256][1024] bf16
  float* bqkv = ws + 14 * M1 + 786432;        // [768] f32
  u32* cnt  = (u32*)(ws + 14 * M1 + 787456);  // [2048] u32
  u32* amask = cnt + 2048;                    // [512][16] u32 (32KB)
  u32* rec_id = (u32*)(ws + 15 * M1);         // [512*1024] u32 (2MB)
  uint4* rec_ew = (uint4*)(ws + 16 * M1);     // [512*1024] uint4 (8MB)

  // 0. zero cnt+amask, then fused prep (weights | bqkv | edge prep | LN1)
  hipMemsetAsync(cnt, 0, (2048 + 8192) * sizeof(u32), stream);
  prep_all<<<dim3(5825), dim3(256), 0, stream>>>(
      wq, wk, wv, w1, w2, wqkvt, w1t, w2t, bq, bk, bv, bqkv,
      ei, ea, wep, bep, weg, beg, cnt, rec_id, rec_ew, amask, x, ln1g, ln1b, xn);
  // 1. fused QKV GEMM (wide, dbuf): Q,K -> qk row-major; V -> vt transposed
  mgemm_w<0, 2><<<dim3(128, 3), 512, 0, stream>>>(xn, wqkvt, bqkv, qk, vt, 256, 768);
  // 2. attention (+x residual) -> x1b bf16; LDS exactly 32 KB
  const int smem_attn = 32768;
  (void)hipFuncSetAttribute(reinterpret_cast<const void*>(attn_kernel),
                            hipFuncAttributeMaxDynamicSharedMemorySize, smem_attn);
  attn_kernel<<<dim3(G_ * H_ * 16), 256, smem_attn, stream>>>(qk, vt, rec_id, rec_ew, cnt,
                                                              amask, rp, x, x1b);
  // 3. LN2 (bf16 in) -> bf16
  ln_kernel_b<<<dim3(N_ / 4), dim3(256), 0, stream>>>(x1b, ln2g, ln2b, h2);
  // 4. FF1 (relu, wide, dbuf) -> f1 bf16
  mgemm_w<1, 0><<<dim3(128, 4), 512, 0, stream>>>(h2, w1t, b1, f1, nullptr, 256, 1024);
  // 5. FF2 (+bias +x1b residual, narrow, dbuf) -> out f32
  mgemm_res<<<dim3(128, 2), 256, 0, stream>>>(f1, w2t, b2, x1b, out, 1024, 256);
}